// Round 3
// baseline (1188.953 us; speedup 1.0000x reference)
//
#include <hip/hip_runtime.h>
#include <hip/hip_bf16.h>
#include <math.h>

// MEFL forward, fp32. B=4, D=49, C=512, N=27, C2=256.
// R2 (resubmit; R2 bench timed out before running): (a) ARM edge attention
// restructured: S_all = Qa@Ka^T (one GEMM/batch), segmented softmax,
// mean_d(h) = Pbar@VW/49, BN var via tr(P G P^T) trick. (b) 64x64/128-thread
// GEMM with 8x4 register tile, float4 staging, XOR-swizzled LDS.

namespace {

constexpr float SCALE_ = 0.0625f;   // 256^-0.5
constexpr float EPS_   = 1e-5f;

// ============ GEMM: C[M,N] = A[M,K] @ W[N,K]^T + bias, N mult of 64, K mult of 32 ============
__device__ __forceinline__
void gemm_nt_core(const float* __restrict__ A, const float* __restrict__ W,
                  const float* __restrict__ bias, float* __restrict__ C,
                  int M, int N, int K)
{
  __shared__ float As[64][36];   // row-major, quad-swizzled: col_quad ^= (row>>3)
  __shared__ float Bs[64][36];
  const int tid = threadIdx.x;              // 128 threads
  const int n0 = blockIdx.x * 64, m0 = blockIdx.y * 64;
  const int tx = tid & 15, ty = tid >> 4;   // tx: n-quad 0..15, ty: m-group 0..7
  float acc[8][4];
#pragma unroll
  for (int i = 0; i < 8; ++i)
#pragma unroll
    for (int j = 0; j < 4; ++j) acc[i][j] = 0.f;

  for (int k0 = 0; k0 < K; k0 += 32) {
#pragma unroll
    for (int p = 0; p < 4; ++p) {
      int idx = tid + p * 128;
      int r = idx >> 3, kq = idx & 7;
      int sw = (kq ^ (r >> 3)) & 7;
      float4 va = make_float4(0.f, 0.f, 0.f, 0.f);
      if (m0 + r < M) va = *(const float4*)(A + (long)(m0 + r) * K + k0 + kq * 4);
      *(float4*)&As[r][sw * 4] = va;
      float4 vb = *(const float4*)(W + (long)(n0 + r) * K + k0 + kq * 4);
      *(float4*)&Bs[r][sw * 4] = vb;
    }
    __syncthreads();
#pragma unroll
    for (int kq = 0; kq < 8; ++kq) {
      float a8[8][4], b4[4][4];
#pragma unroll
      for (int i = 0; i < 8; ++i)
        *(float4*)a8[i] = *(const float4*)&As[ty*8 + i][((kq ^ ty) & 7) * 4];
#pragma unroll
      for (int j = 0; j < 4; ++j) {
        int r = tx*4 + j;
        *(float4*)b4[j] = *(const float4*)&Bs[r][((kq ^ (r >> 3)) & 7) * 4];
      }
#pragma unroll
      for (int kk = 0; kk < 4; ++kk)
#pragma unroll
        for (int i = 0; i < 8; ++i)
#pragma unroll
          for (int j = 0; j < 4; ++j)
            acc[i][j] = fmaf(a8[i][kk], b4[j][kk], acc[i][j]);
    }
    __syncthreads();
  }
  float4 bb = make_float4(0.f, 0.f, 0.f, 0.f);
  if (bias) bb = *(const float4*)(bias + n0 + tx*4);
#pragma unroll
  for (int i = 0; i < 8; ++i) {
    int m = m0 + ty*8 + i;
    if (m < M) {
      float4 o;
      o.x = acc[i][0]+bb.x; o.y = acc[i][1]+bb.y;
      o.z = acc[i][2]+bb.z; o.w = acc[i][3]+bb.w;
      *(float4*)(C + (long)m * N + n0 + tx*4) = o;
    }
  }
}

__global__ __launch_bounds__(128)
void gemm_nt(const float* __restrict__ A, const float* __restrict__ W,
             const float* __restrict__ bias, float* __restrict__ C,
             int M, int N, int K, long aBS, long wBS, long bBS, long cBS)
{
  int z = blockIdx.z;
  gemm_nt_core(A + (long)z * aBS, W + (long)z * wBS,
               bias ? bias + (long)z * bBS : nullptr,
               C + (long)z * cBS, M, N, K);
}

// 4 GEMMs sharing one A (GNN f_v projections)
__global__ __launch_bounds__(128)
void gemm4_nt(const float* __restrict__ A,
              const float* W0, const float* W1, const float* W2, const float* W3,
              float* C0, float* C1, float* C2, float* C3, int M, int N, int K)
{
  const float* W; float* C;
  switch (blockIdx.z) {
    case 0:  W = W0; C = C0; break;
    case 1:  W = W1; C = C1; break;
    case 2:  W = W2; C = C2; break;
    default: W = W3; C = C3; break;
  }
  gemm_nt_core(A, W, nullptr, C, M, N, K);
}

// ============ small NN GEMM (W is [K,N]) — only for Mpre = ep_W @ arm_vW ============
__global__ __launch_bounds__(256)
void gemm_nn_k(const float* __restrict__ A, const float* __restrict__ W,
               float* __restrict__ C, int M, int N, int K)
{
  __shared__ float As[32][68];
  __shared__ float Ws[32][68];
  const int tid = threadIdx.x;
  const int n0 = blockIdx.x * 64, m0 = blockIdx.y * 64;
  const int tx = tid & 15, ty = tid >> 4;
  float acc[4][4] = {};
  for (int k0 = 0; k0 < K; k0 += 32) {
#pragma unroll
    for (int p = 0; p < 2; ++p) {
      int idx = tid + p * 256;
      int row = idx >> 3, kq = idx & 7;
      float4 v = make_float4(0.f, 0.f, 0.f, 0.f);
      if (m0 + row < M)
        v = *(const float4*)(A + (long)(m0 + row) * K + k0 + kq * 4);
      As[kq*4+0][row] = v.x; As[kq*4+1][row] = v.y;
      As[kq*4+2][row] = v.z; As[kq*4+3][row] = v.w;
    }
#pragma unroll
    for (int p = 0; p < 2; ++p) {
      int idx = tid + p * 256;
      int row = idx >> 4, nq = idx & 15;
      float4 v = *(const float4*)(W + (long)(k0 + row) * N + n0 + nq * 4);
      *(float4*)&Ws[row][nq*4] = v;
    }
    __syncthreads();
#pragma unroll
    for (int k = 0; k < 32; ++k) {
      float4 a4 = *(const float4*)&As[k][ty*4];
      float4 b4 = *(const float4*)&Ws[k][tx*4];
      float av[4] = {a4.x, a4.y, a4.z, a4.w};
      float bv[4] = {b4.x, b4.y, b4.z, b4.w};
#pragma unroll
      for (int i2 = 0; i2 < 4; ++i2)
#pragma unroll
        for (int j2 = 0; j2 < 4; ++j2)
          acc[i2][j2] = fmaf(av[i2], bv[j2], acc[i2][j2]);
    }
    __syncthreads();
  }
#pragma unroll
  for (int i2 = 0; i2 < 4; ++i2) {
    int m = m0 + ty*4 + i2;
    if (m < M)
      *(float4*)(C + (long)m * N + n0 + tx*4) =
        make_float4(acc[i2][0], acc[i2][1], acc[i2][2], acc[i2][3]);
  }
}

// ============ node-block BN ============
__global__ __launch_bounds__(256)
void nb_stats(const float* __restrict__ H, float* __restrict__ mean, float* __restrict__ rs)
{
  int n = blockIdx.x;
  int c = blockIdx.y * 256 + threadIdx.x;
  const float* p = H + (long)n * 196 * 512 + c;
  float s = 0.f, q = 0.f;
  for (int r = 0; r < 196; ++r) { float v = p[(long)r * 512]; s += v; q = fmaf(v, v, q); }
  float m = s * (1.f / 196.f);
  float var = q * (1.f / 196.f) - m * m;
  mean[n * 512 + c] = m;
  rs[n * 512 + c] = rsqrtf(var + EPS_);
}

__global__ __launch_bounds__(256)
void nb_apply(const float* __restrict__ H, const float* __restrict__ mean,
              const float* __restrict__ rs, const float* __restrict__ bw,
              const float* __restrict__ bb, float* __restrict__ fu, float* __restrict__ fv)
{
  int n = blockIdx.x, b = blockIdx.y;
  int t = threadIdx.x;
#pragma unroll
  for (int cq = 0; cq < 2; ++cq) {
    int c = cq * 256 + t;
    float m = mean[n*512+c], r = rs[n*512+c];
    float w = bw[n*512+c], bias = bb[n*512+c];
    const float* hp = H + ((long)(n*4+b)*49) * 512 + c;
    float* fp = fu + ((long)(n*4+b)*49) * 512 + c;
    float s = 0.f;
    for (int d = 0; d < 49; ++d) {
      float v = hp[(long)d*512];
      float o = fmaxf(fmaf((v - m) * r, w, bias), 0.f);
      fp[(long)d*512] = o;
      s += o;
    }
    fv[((long)b*27+n)*512 + c] = s * (1.f / 49.f);
  }
}

// ============ FAM cross-attention (writes feat batch-major [b][n*49+d][c]) ============
__global__ __launch_bounds__(512)
void attn_fam(const float* __restrict__ Qg, const float* __restrict__ Kg,
              const float* __restrict__ Vg, float* __restrict__ outp)
{
  __shared__ float Qs[52][68];
  __shared__ float Ks[52][68];
  __shared__ float Ss[49][56];
  __shared__ float Vs[49][68];

  const int tid = threadIdx.x;
  const int bx = blockIdx.x, b = blockIdx.y;   // bx = node n
  const int qblk = bx*4 + b;                    // qfam is n-major
  const long obase = ((long)b*1323 + (long)bx*49) * 512;  // feat batch-major
  const float* qp = Qg + (long)qblk * (49 * 256);
  const float* kp = Kg + (long)b * (49 * 256);
  const float* vp = Vg + (long)b * (49 * 512);

  const int tx = tid & 15;
  const int ty4 = tid >> 4;

  float sacc[2][4] = {};
  const int d0 = ty4 * 2;
  const int e0 = tx * 4;
  const int eh0 = (e0+0)&7, eh1 = (e0+1)&7, eh2 = (e0+2)&7, eh3 = (e0+3)&7;
  const int er0 = (e0+0) > 51 ? 51 : (e0+0);
  const int er1 = (e0+1) > 51 ? 51 : (e0+1);
  const int er2 = (e0+2) > 51 ? 51 : (e0+2);
  const int er3 = (e0+3) > 51 ? 51 : (e0+3);
  for (int kc = 0; kc < 256; kc += 64) {
    for (int idx = tid; idx < 49 * 16; idx += 512) {
      int row = idx >> 4, kq = idx & 15;
      *(float4*)&Qs[row][kq*4] = *(const float4*)(qp + (long)row*256 + kc + kq*4);
      *(float4*)&Ks[row][(kq ^ (row & 7)) * 4] = *(const float4*)(kp + (long)row*256 + kc + kq*4);
    }
    __syncthreads();
    if (d0 < 49) {
      const float* q0 = &Qs[d0][0];
      const float* q1 = &Qs[d0 + 1][0];
      const float* k0 = &Ks[er0][0];
      const float* k1 = &Ks[er1][0];
      const float* k2 = &Ks[er2][0];
      const float* k3 = &Ks[er3][0];
#pragma unroll 4
      for (int kq = 0; kq < 16; ++kq) {
        float4 a0 = *(const float4*)(q0 + kq*4);
        float4 a1 = *(const float4*)(q1 + kq*4);
        float4 b0 = *(const float4*)(k0 + ((kq ^ eh0) * 4));
        float4 b1 = *(const float4*)(k1 + ((kq ^ eh1) * 4));
        float4 b2 = *(const float4*)(k2 + ((kq ^ eh2) * 4));
        float4 b3 = *(const float4*)(k3 + ((kq ^ eh3) * 4));
        float av0[4] = {a0.x, a0.y, a0.z, a0.w};
        float av1[4] = {a1.x, a1.y, a1.z, a1.w};
        float bv[4][4] = {{b0.x,b0.y,b0.z,b0.w},{b1.x,b1.y,b1.z,b1.w},
                          {b2.x,b2.y,b2.z,b2.w},{b3.x,b3.y,b3.z,b3.w}};
#pragma unroll
        for (int j2 = 0; j2 < 4; ++j2) {
#pragma unroll
          for (int qq = 0; qq < 4; ++qq) {
            sacc[0][j2] = fmaf(av0[qq], bv[j2][qq], sacc[0][j2]);
            sacc[1][j2] = fmaf(av1[qq], bv[j2][qq], sacc[1][j2]);
          }
        }
      }
    }
    __syncthreads();
  }
  if (d0 < 49) {
#pragma unroll
    for (int i2 = 0; i2 < 2; ++i2) {
      int d = d0 + i2;
      if (d < 49) {
#pragma unroll
        for (int j2 = 0; j2 < 4; ++j2) {
          int e = e0 + j2;
          if (e < 49) Ss[d][e] = sacc[i2][j2] * SCALE_;
        }
      }
    }
  }
  __syncthreads();

  if (tid < 49) {
    float mx = -1e30f;
    for (int e = 0; e < 49; ++e) mx = fmaxf(mx, Ss[tid][e]);
    float sum = 0.f;
    for (int e = 0; e < 49; ++e) { float ex = __expf(Ss[tid][e] - mx); Ss[tid][e] = ex; sum += ex; }
    float inv = 1.f / sum;
    for (int e = 0; e < 49; ++e) Ss[tid][e] *= inv;
  }
  __syncthreads();

  const int td = ty4;
  const bool has2 = (td + 32) < 49;
  for (int cc = 0; cc < 512; cc += 64) {
    for (int idx = tid; idx < 49 * 16; idx += 512) {
      int row = idx >> 4, cq = idx & 15;
      *(float4*)&Vs[row][cq*4] = *(const float4*)(vp + (long)row*512 + cc + cq*4);
    }
    __syncthreads();
    float pa[2][4] = {};
#pragma unroll 7
    for (int e = 0; e < 49; ++e) {
      float4 v4 = *(const float4*)&Vs[e][tx*4];
      float p0 = Ss[td][e];
      float p1 = has2 ? Ss[td + 32][e] : 0.f;
      pa[0][0] = fmaf(p0, v4.x, pa[0][0]); pa[0][1] = fmaf(p0, v4.y, pa[0][1]);
      pa[0][2] = fmaf(p0, v4.z, pa[0][2]); pa[0][3] = fmaf(p0, v4.w, pa[0][3]);
      pa[1][0] = fmaf(p1, v4.x, pa[1][0]); pa[1][1] = fmaf(p1, v4.y, pa[1][1]);
      pa[1][2] = fmaf(p1, v4.z, pa[1][2]); pa[1][3] = fmaf(p1, v4.w, pa[1][3]);
    }
    __syncthreads();
    *(float4*)(outp + obase + (long)td*512 + cc + tx*4) =
        make_float4(pa[0][0], pa[0][1], pa[0][2], pa[0][3]);
    if (has2)
      *(float4*)(outp + obase + (long)(td+32)*512 + cc + tx*4) =
          make_float4(pa[1][0], pa[1][1], pa[1][2], pa[1][3]);
  }
}

// ============ bias2 = ep_W @ arm_vb + ep_b, plus B1 = sum(b2), nb2 = sum(b2^2) ============
__global__ __launch_bounds__(512)
void bias2red_k(const float* __restrict__ epW, const float* __restrict__ vb,
                const float* __restrict__ epb, float* __restrict__ bias2,
                float* __restrict__ b2st)
{
  int c = threadIdx.x;
  float s = epb[c];
  const float* r = epW + (long)c * 512;
  for (int k = 0; k < 512; ++k) s = fmaf(r[k], vb[k], s);
  bias2[c] = s;
  __shared__ float red[16];
  float s1 = s, s2 = s * s;
#pragma unroll
  for (int off = 32; off; off >>= 1) { s1 += __shfl_down(s1, off); s2 += __shfl_down(s2, off); }
  int lane = c & 63, wid = c >> 6;
  if (lane == 0) { red[wid] = s1; red[8 + wid] = s2; }
  __syncthreads();
  if (c == 0) {
    float a = 0.f, qq = 0.f;
#pragma unroll
    for (int w = 0; w < 8; ++w) { a += red[w]; qq += red[8 + w]; }
    b2st[0] = a; b2st[1] = qq;
  }
}

// ============ G = VW VW^T per (b,i), plus row sums V1[e]=sum_c V, Vb2[e]=sum_c V*b2 ============
__constant__ unsigned char TI_c[28] = {0,1,1,2,2,2,3,3,3,3,4,4,4,4,4,5,5,5,5,5,5,6,6,6,6,6,6,6};
__constant__ unsigned char TJ_c[28] = {0,0,1,0,1,2,0,1,2,3,0,1,2,3,4,0,1,2,3,4,5,0,1,2,3,4,5,6};

__global__ __launch_bounds__(256)
void gmat_k(const float* __restrict__ VW, const float* __restrict__ b2,
            float* __restrict__ G, float* __restrict__ V1, float* __restrict__ Vb2)
{
  __shared__ float Vs[49][260];   // 50.9 KB, c-half staged
  const int i = blockIdx.x, b = blockIdx.y;
  const int tid = threadIdx.x;
  const int wave = tid >> 6, lane = tid & 63;
  const int di = lane >> 3, ej = lane & 7;
  const float* vp = VW + ((long)b*1323 + (long)i*49) * 512;
  float gacc[7];
#pragma unroll
  for (int t = 0; t < 7; ++t) gacc[t] = 0.f;
  float s1 = 0.f, s2 = 0.f;

  for (int half = 0; half < 2; ++half) {
    __syncthreads();
    for (int idx = tid; idx < 49 * 64; idx += 256) {
      int r = idx >> 6, q = idx & 63;
      *(float4*)&Vs[r][q*4] = *(const float4*)(vp + (long)r*512 + half*256 + q*4);
    }
    __syncthreads();
    int tt = 0;
    for (int t = wave; t < 28; t += 4, ++tt) {
      int d = TI_c[t]*8 + di, e = TJ_c[t]*8 + ej;
      int dc = d > 48 ? 48 : d, ec = e > 48 ? 48 : e;
      float g = gacc[tt];
      for (int q = 0; q < 64; ++q) {
        float4 a = *(const float4*)&Vs[dc][q*4];
        float4 bq = *(const float4*)&Vs[ec][q*4];
        g = fmaf(a.x, bq.x, fmaf(a.y, bq.y, fmaf(a.z, bq.z, fmaf(a.w, bq.w, g))));
      }
      gacc[tt] = g;
    }
    if (tid < 49) {
      for (int c = 0; c < 256; ++c) {
        float v = Vs[tid][c];
        s1 += v; s2 = fmaf(v, b2[half*256 + c], s2);
      }
    }
  }
  long gbase = ((long)b*27 + i) * 2401;
  int tt = 0;
  for (int t = wave; t < 28; t += 4, ++tt) {
    int ti = TI_c[t], tj = TJ_c[t];
    int d = ti*8 + di, e = tj*8 + ej;
    if (d < 49 && e < 49) {
      G[gbase + d*49 + e] = gacc[tt];
      if (ti != tj) G[gbase + e*49 + d] = gacc[tt];
    }
  }
  if (tid < 49) {
    long o = ((long)b*27 + i) * 49 + tid;
    V1[o] = s1; Vb2[o] = s2;
  }
}

// ============ per-edge: segmented softmax, Pbar, BN partial sums ============
__global__ __launch_bounds__(64)
void arm_post(const float* __restrict__ S, const float* __restrict__ G,
              const float* __restrict__ V1, const float* __restrict__ Vb2,
              float* __restrict__ Pbar, float* __restrict__ parts)
{
  __shared__ float TP[49 * 53];
  __shared__ float TG[49 * 53];
  const int tid = threadIdx.x;
  const int x = blockIdx.x, b = blockIdx.y;
  const int i = x / 27, j = x - i * 27;
  const float* Sp = S + (long)b*1323*1344 + (long)j*49*1344 + (long)i*49;
  for (int idx = tid; idx < 2401; idx += 64) {
    unsigned d = ((unsigned)idx * 1338u) >> 16;
    unsigned e = (unsigned)idx - d * 49u;
    TP[d*53 + e] = Sp[(long)d*1344 + e];
  }
  const float* Gp = G + ((long)b*27 + i) * 2401;
  for (int idx = tid; idx < 2401; idx += 64) {
    unsigned d = ((unsigned)idx * 1338u) >> 16;
    unsigned e = (unsigned)idx - d * 49u;
    TG[d*53 + e] = Gp[idx];
  }
  __syncthreads();
  if (tid < 49) {
    float* pr = &TP[tid * 53];
    float mx = -1e30f;
    for (int e = 0; e < 49; ++e) mx = fmaxf(mx, pr[e]);
    float sum = 0.f;
    for (int e = 0; e < 49; ++e) { float ex = __expf(pr[e] - mx); pr[e] = ex; sum += ex; }
    float inv = 1.f / sum;
    for (int e = 0; e < 49; ++e) pr[e] *= inv;
  }
  __syncthreads();
  float lin = 0.f, pvb = 0.f;
  if (tid < 49) {
    float pb = 0.f;
    for (int d = 0; d < 49; ++d) pb += TP[d*53 + tid];
    Pbar[(((long)b*27 + i)*27 + j)*49 + tid] = pb;
    long vo = ((long)b*27 + i)*49 + tid;
    lin = pb * V1[vo];
    pvb = pb * Vb2[vo];
  }
  float q2 = 0.f;
  if (tid < 49) {
    const float* pr = &TP[tid * 53];
#pragma unroll 1
    for (int e = 0; e < 49; e += 7) {
      float t0=0.f,t1=0.f,t2=0.f,t3=0.f,t4=0.f,t5=0.f,t6=0.f;
      for (int e2 = 0; e2 < 49; ++e2) {
        float pv = pr[e2];
        const float* g = &TG[e2*53 + e];
        t0 = fmaf(pv, g[0], t0); t1 = fmaf(pv, g[1], t1);
        t2 = fmaf(pv, g[2], t2); t3 = fmaf(pv, g[3], t3);
        t4 = fmaf(pv, g[4], t4); t5 = fmaf(pv, g[5], t5);
        t6 = fmaf(pv, g[6], t6);
      }
      q2 += t0*pr[e] + t1*pr[e+1] + t2*pr[e+2] + t3*pr[e+3]
          + t4*pr[e+4] + t5*pr[e+5] + t6*pr[e+6];
    }
  }
  float r1 = lin, r2 = q2 + 2.f * pvb;
#pragma unroll
  for (int off = 32; off; off >>= 1) { r1 += __shfl_down(r1, off); r2 += __shfl_down(r2, off); }
  if (tid == 0) {
    long o = ((long)b*729 + x) * 2;
    parts[o] = r1; parts[o + 1] = r2;
  }
}

// ============ per-edge BN stats over (b,d,c) ============
__global__ __launch_bounds__(256)
void edge_fin(const float* __restrict__ parts, const float* __restrict__ b2st,
              float* __restrict__ ems)
{
  int e = blockIdx.x * 256 + threadIdx.x;
  if (e < 729) {
    float B1 = b2st[0], nb2 = b2st[1];
    float s = 196.f * B1, q = 196.f * nb2;     // 4 batches * 49 rows
#pragma unroll
    for (int b = 0; b < 4; ++b) {
      s += parts[((long)b * 729 + e) * 2 + 0];
      q += parts[((long)b * 729 + e) * 2 + 1];
    }
    const float inv = 1.f / 100352.f;          // B*D*C
    float m = s * inv;
    float var = q * inv - m * m;
    ems[e*2]   = m;
    ems[e*2+1] = rsqrtf(var + EPS_);
  }
}

// ============ f_e[b,ij,c] = BN( Pbar@VW/49 + b2 ) ============
__global__ __launch_bounds__(256)
void fe_build(const float* __restrict__ Pbar, const float* __restrict__ VW,
              const float* __restrict__ b2, const float* __restrict__ ems,
              const float* __restrict__ gw, const float* __restrict__ gb,
              float* __restrict__ fe)
{
  __shared__ float Pb[27 * 49];
  const int i = blockIdx.x, b = blockIdx.y;
  const int tid = threadIdx.x;
  const float* pp = Pbar + ((long)b*27 + i) * 27 * 49;
  for (int idx = tid; idx < 1323; idx += 256) Pb[idx] = pp[idx];
  __syncthreads();
  const float* vp = VW + ((long)b*1323 + (long)i*49) * 512;
#pragma unroll 1
  for (int half = 0; half < 2; ++half) {
    int c = half * 256 + tid;
    float acc[27];
#pragma unroll
    for (int j = 0; j < 27; ++j) acc[j] = 0.f;
    for (int e = 0; e < 49; ++e) {
      float v = vp[(long)e*512 + c];
#pragma unroll
      for (int j = 0; j < 27; ++j) acc[j] = fmaf(Pb[j*49 + e], v, acc[j]);
    }
    float bz = b2[c];
#pragma unroll
    for (int j = 0; j < 27; ++j) {
      int ij = i*27 + j;
      float m = ems[ij*2], rs = ems[ij*2+1];
      float h = acc[j] * (1.f/49.f) + bz;
      fe[((long)b*729 + ij)*512 + c] = fmaf((h - m) * rs, gw[ij], gb[ij]);
    }
  }
}

// ============ GNN kernels ============
__global__ __launch_bounds__(256)
void gnn_edge_bn(const float* __restrict__ vi, const float* __restrict__ vj,
                 const float* __restrict__ el, const float* __restrict__ wv,
                 const float* __restrict__ bv, float* fe)
{
  int ij = blockIdx.x; int i = ij / 27, j = ij - i * 27;
  int t = threadIdx.x;
  __shared__ float red[18];
  float mv[8]; float s = 0.f, q = 0.f;
#pragma unroll
  for (int p = 0; p < 8; ++p) {
    int idx = p * 256 + t; int b = idx >> 9, c = idx & 511;
    float v = vi[((long)b*27+i)*512 + c] + vj[((long)b*27+j)*512 + c]
            + el[((long)b*729+ij)*512 + c];
    mv[p] = v; s += v; q = fmaf(v, v, q);
  }
  int lane = t & 63, wid = t >> 6;
#pragma unroll
  for (int off = 32; off; off >>= 1) { s += __shfl_down(s, off); q += __shfl_down(q, off); }
  if (lane == 0) { red[wid] = s; red[4 + wid] = q; }
  __syncthreads();
  if (t == 0) {
    float S = red[0]+red[1]+red[2]+red[3], Q = red[4]+red[5]+red[6]+red[7];
    float m = S * (1.f / 2048.f);
    red[16] = m;
    red[17] = rsqrtf(Q * (1.f / 2048.f) - m * m + EPS_);
  }
  __syncthreads();
  float m = red[16], rs = red[17];
  float w = wv[ij], bb = bv[ij];
#pragma unroll
  for (int p = 0; p < 8; ++p) {
    int idx = p * 256 + t; int b = idx >> 9, c = idx & 511;
    long o = ((long)b*729+ij)*512 + c;
    fe[o] += fmaxf(fmaf((mv[p] - m) * rs, w, bb), 0.f);
  }
}

__global__ __launch_bounds__(256)
void gnn_agg(const float* __restrict__ fe, const float* __restrict__ ui,
             const float* __restrict__ uj, float* __restrict__ agg)
{
  int i = blockIdx.x, b = blockIdx.y;
  int t = threadIdx.x;
#pragma unroll
  for (int cq = 0; cq < 2; ++cq) {
    int c = cq * 256 + t;
    float sg[27];
    float mx = -1e30f;
#pragma unroll
    for (int j = 0; j < 27; ++j) {
      float x = fe[((long)b*729 + i*27 + j)*512 + c];
      float sgm = 1.f / (1.f + __expf(-x));
      sg[j] = sgm; mx = fmaxf(mx, sgm);
    }
    float sum = 0.f;
#pragma unroll
    for (int j = 0; j < 27; ++j) { float e2 = __expf(sg[j] - mx); sg[j] = e2; sum += e2; }
    float acc = 0.f;
#pragma unroll
    for (int j = 0; j < 27; ++j)
      acc = fmaf(sg[j], uj[((long)b*27+j)*512 + c], acc);
    agg[((long)b*27+i)*512 + c] = ui[((long)b*27+i)*512 + c] + acc / (sum * 27.f);
  }
}

__global__ __launch_bounds__(256)
void gnn_node_bn(const float* __restrict__ agg, const float* __restrict__ wv,
                 const float* __restrict__ bv, float* fv)
{
  int i = blockIdx.x;
  int t = threadIdx.x;
  __shared__ float red[18];
  float mv[8]; float s = 0.f, q = 0.f;
#pragma unroll
  for (int p = 0; p < 8; ++p) {
    int idx = p * 256 + t; int b = idx >> 9, c = idx & 511;
    float v = agg[((long)b*27+i)*512 + c];
    mv[p] = v; s += v; q = fmaf(v, v, q);
  }
  int lane = t & 63, wid = t >> 6;
#pragma unroll
  for (int off = 32; off; off >>= 1) { s += __shfl_down(s, off); q += __shfl_down(q, off); }
  if (lane == 0) { red[wid] = s; red[4 + wid] = q; }
  __syncthreads();
  if (t == 0) {
    float S = red[0]+red[1]+red[2]+red[3], Q = red[4]+red[5]+red[6]+red[7];
    float m = S * (1.f / 2048.f);
    red[16] = m;
    red[17] = rsqrtf(Q * (1.f / 2048.f) - m * m + EPS_);
  }
  __syncthreads();
  float m = red[16], rs = red[17];
  float w = wv[i], bb = bv[i];
#pragma unroll
  for (int p = 0; p < 8; ++p) {
    int idx = p * 256 + t; int b = idx >> 9, c = idx & 511;
    long o = ((long)b*27+i)*512 + c;
    fv[o] += fmaxf(fmaf((mv[p] - m) * rs, w, bb), 0.f);
  }
}

__constant__ int SUB_IDX_c[14] = {0,0,1,1,2,2,4,4,7,7,8,8,11,11};

__global__ __launch_bounds__(64)
void sc_k(const float* __restrict__ fv, const float* __restrict__ mainsc,
          const float* __restrict__ subsc, float* __restrict__ out)
{
  int o = blockIdx.x, b = blockIdx.y;
  int lane = threadIdx.x;
  int r; const float* ap;
  if (o < 27) { r = o; ap = mainsc + (long)o * 512; }
  else        { int k = o - 27; r = SUB_IDX_c[k]; ap = subsc + (long)k * 512; }
  const float* fp = fv + ((long)b*27 + r) * 512;
  float sff = 0.f, saa = 0.f, sfa = 0.f;
  for (int c = lane; c < 512; c += 64) {
    float f = fp[c];
    float a = fmaxf(ap[c], 0.f);
    sff = fmaf(f, f, sff); saa = fmaf(a, a, saa); sfa = fmaf(f, a, sfa);
  }
#pragma unroll
  for (int off = 32; off; off >>= 1) {
    sff += __shfl_down(sff, off); saa += __shfl_down(saa, off); sfa += __shfl_down(sfa, off);
  }
  if (lane == 0)
    out[b * 41 + o] = sfa / (fmaxf(sqrtf(sff), 1e-12f) * fmaxf(sqrtf(saa), 1e-12f));
}

} // namespace

extern "C" void kernel_launch(void* const* d_in, const int* in_sizes, int n_in,
                              void* d_out, int out_size, void* d_ws, size_t ws_size,
                              hipStream_t stream)
{
  (void)in_sizes; (void)n_in; (void)out_size; (void)ws_size;
  const float* x       = (const float*)d_in[0];
  const float* nb_W    = (const float*)d_in[1];
  const float* nb_b    = (const float*)d_in[2];
  const float* nb_bnw  = (const float*)d_in[3];
  const float* nb_bnb  = (const float*)d_in[4];
  const float* fam_qW  = (const float*)d_in[5];
  const float* fam_qb  = (const float*)d_in[6];
  const float* fam_kW  = (const float*)d_in[7];
  const float* fam_kb  = (const float*)d_in[8];
  const float* fam_vW  = (const float*)d_in[9];
  const float* fam_vb  = (const float*)d_in[10];
  const float* arm_qW  = (const float*)d_in[11];
  const float* arm_qb  = (const float*)d_in[12];
  const float* arm_kW  = (const float*)d_in[13];
  const float* arm_kb  = (const float*)d_in[14];
  const float* arm_vW  = (const float*)d_in[15];
  const float* arm_vb  = (const float*)d_in[16];
  const float* ep_W    = (const float*)d_in[17];
  const float* ep_b    = (const float*)d_in[18];
  const float* gem_bnw = (const float*)d_in[19];
  const float* gem_bnb = (const float*)d_in[20];
  const float* gnn_uW  = (const float*)d_in[21];
  const float* gnn_vW  = (const float*)d_in[22];
  const float* gnn_aW  = (const float*)d_in[23];
  const float* gnn_bW  = (const float*)d_in[24];
  const float* gnn_eW  = (const float*)d_in[25];
  const float* gnn_bnvw = (const float*)d_in[26];
  const float* gnn_bnvb = (const float*)d_in[27];
  const float* gnn_bnew = (const float*)d_in[28];
  const float* gnn_bneb = (const float*)d_in[29];
  const float* main_sc  = (const float*)d_in[30];
  const float* sub_sc   = (const float*)d_in[31];
  float* out = (float*)d_out;

  // workspace (floats), ~71.8 MB total; aliases noted
  float* wsf = (float*)d_ws;
  float* Hnb   = wsf;  wsf += (long)27*196*512;   // 2709504; alias: feat (batch-major)
  float* fu    = wsf;  wsf += (long)27*196*512;   // 2709504; alias: VW, then el
  float* qfam  = wsf;  wsf += (long)5292*256;     // 1354752; alias: Qa
  float* Ka    = wsf;  wsf += (long)4*1344*256;   // 1376256 (rows 1323..1343/batch unused)
  float* S     = wsf;  wsf += (long)4*1323*1344;  // 7112448
  float* fe    = wsf;  wsf += (long)4*729*512;    // 1492992
  float* kf    = wsf;  wsf += 196*256;
  float* vf    = wsf;  wsf += 196*512;
  float* nbm   = wsf;  wsf += 27*512;
  float* nbr   = wsf;  wsf += 27*512;
  float* Mpre  = wsf;  wsf += 512*512;
  float* bias2 = wsf;  wsf += 512;
  float* b2st  = wsf;  wsf += 16;
  float* parts = wsf;  wsf += 4*729*2;
  float* ems   = wsf;  wsf += 1460;
  float* G     = wsf;  wsf += (long)108*2401;
  float* V1    = wsf;  wsf += 108*49 + 12;
  float* Vb2   = wsf;  wsf += 108*49 + 12;
  float* Pbar  = wsf;  wsf += (long)4*27*27*49;
  float* fv    = wsf;  wsf += 108*512;
  float* vi    = wsf;  wsf += 108*512;
  float* vj    = wsf;  wsf += 108*512;
  float* uj    = wsf;  wsf += 108*512;
  float* ui    = wsf;  wsf += 108*512;
  float* agg   = wsf;  wsf += 108*512;
  float* feat = Hnb;    // batch-major [4][1323][512]
  float* Qa   = qfam;   // batch-major [4][1323][256]
  float* VW   = fu;     // batch-major [4][1323][512]
  float* el   = fu;

  // 1) node-block GEMMs: H[n] = x @ nb_W[n]^T + nb_b[n]
  gemm_nt<<<dim3(8,4,27), 128, 0, stream>>>(x, nb_W, nb_b, Hnb,
      196, 512, 512, 0, (long)512*512, 512, (long)196*512);
  // 2-3) BN stats + apply -> f_u (n-major), f_v
  nb_stats<<<dim3(27,2), 256, 0, stream>>>(Hnb, nbm, nbr);
  nb_apply<<<dim3(27,4), 256, 0, stream>>>(Hnb, nbm, nbr, nb_bnw, nb_bnb, fu, fv);
  // 4-5) FAM k, v
  gemm_nt<<<dim3(4,4,1), 128, 0, stream>>>(x, fam_kW, fam_kb, kf, 196, 256, 512, 0,0,0,0);
  gemm_nt<<<dim3(8,4,1), 128, 0, stream>>>(x, fam_vW, fam_vb, vf, 196, 512, 512, 0,0,0,0);
  // 6) FAM q = f_u @ fam_qW^T (n-major)
  gemm_nt<<<dim3(4,83,1), 128, 0, stream>>>(fu, fam_qW, fam_qb, qfam, 5292, 256, 512, 0,0,0,0);
  // 7) FAM cross-attention -> feat (batch-major)
  attn_fam<<<dim3(27,4), 512, 0, stream>>>(qfam, kf, vf, feat);
  // 8) ARM Q (batch-major, flat M)
  gemm_nt<<<dim3(4,83,1), 128, 0, stream>>>(feat, arm_qW, arm_qb, Qa, 5292, 256, 512, 0,0,0,0);
  // 9) ARM K (per-batch, row-padded to 1344)
  gemm_nt<<<dim3(4,21,4), 128, 0, stream>>>(feat, arm_kW, arm_kb, Ka,
      1323, 256, 512, (long)1323*512, 0, 0, (long)1344*256);
  // 10) Mpre = ep_W @ arm_vW
  gemm_nn_k<<<dim3(8,8,1), 256, 0, stream>>>(ep_W, arm_vW, Mpre, 512, 512, 512);
  // 11) bias2 = ep_W @ arm_vb + ep_b, plus scalar sums
  bias2red_k<<<dim3(1), 512, 0, stream>>>(ep_W, arm_vb, ep_b, bias2, b2st);
  // 12) VW = feat @ Mpre^T
  gemm_nt<<<dim3(8,83,1), 128, 0, stream>>>(feat, Mpre, nullptr, VW, 5292, 512, 512, 0,0,0,0);
  // 13) S_all[b] = Qa_b @ Ka_b^T  (all pairwise dots)
  gemm_nt<<<dim3(21,21,4), 128, 0, stream>>>(Qa, Ka, nullptr, S,
      1323, 1344, 256, (long)1323*256, (long)1344*256, 0, (long)1323*1344);
  // 14) G = VW VW^T per (b,i) + V row sums
  gmat_k<<<dim3(27,4), 256, 0, stream>>>(VW, bias2, G, V1, Vb2);
  // 15) segmented softmax + Pbar + BN partials
  arm_post<<<dim3(729,4), 64, 0, stream>>>(S, G, V1, Vb2, Pbar, parts);
  // 16) per-edge BN stats
  edge_fin<<<dim3(3), 256, 0, stream>>>(parts, b2st, ems);
  // 17) f_e = BN(Pbar@VW/49 + b2)
  fe_build<<<dim3(27,4), 256, 0, stream>>>(Pbar, VW, bias2, ems, gem_bnw, gem_bnb, fe);
  // 18) 2 GatedGNN layers
  for (int l = 0; l < 2; ++l) {
    long wo = (long)l * 512 * 512;
    gemm4_nt<<<dim3(8,2,4), 128, 0, stream>>>(fv,
        gnn_aW + wo, gnn_bW + wo, gnn_vW + wo, gnn_uW + wo,
        vi, vj, uj, ui, 108, 512, 512);
    gemm_nt<<<dim3(8,46,1), 128, 0, stream>>>(fe, gnn_eW + wo, nullptr, el,
        2916, 512, 512, 0,0,0,0);
    gnn_edge_bn<<<dim3(729), 256, 0, stream>>>(vi, vj, el,
        gnn_bnew + (long)l*729, gnn_bneb + (long)l*729, fe);
    gnn_agg<<<dim3(27,4), 256, 0, stream>>>(fe, ui, uj, agg);
    gnn_node_bn<<<dim3(27), 256, 0, stream>>>(agg,
        gnn_bnvw + (long)l*27, gnn_bnvb + (long)l*27, fv);
  }
  // 19) cosine-similarity outputs [4,41]
  sc_k<<<dim3(41,4), 64, 0, stream>>>(fv, main_sc, sub_sc, out);
}

// Round 5
// 685.805 us; speedup vs baseline: 1.7337x; 1.7337x over previous
//
#include <hip/hip_runtime.h>
#include <hip/hip_bf16.h>
#include <math.h>

// MEFL forward. B=4, D=49, C=512, N=27, C2=256.
// R4 resubmit (R4 bench timed out before running): all GEMMs moved to MFMA
// (bf16x3 split: A*B ~ Ah*Bh + Ah*Bl + Al*Bh, fp32 acc). Operands pre-split
// into bf16 hi/lo planes once; producer kernels emit hi/lo in epilogues.
// Only change vs R4: workspace 109MB -> ~92MB via two statically-safe aliases
// (feat planes overlay dead fu planes; fe planes overlay dead Qa planes).

namespace {

constexpr float SCALE_ = 0.0625f;   // 256^-0.5
constexpr float EPS_   = 1e-5f;

typedef __attribute__((ext_vector_type(8))) short bf16x8;
typedef __attribute__((ext_vector_type(4))) short s16x4;
typedef __attribute__((ext_vector_type(4))) float f32x4;

__device__ __forceinline__ short f2bf(float f) {
  unsigned u = __float_as_uint(f);
  u += 0x7fffu + ((u >> 16) & 1u);
  return (short)(u >> 16);
}
__device__ __forceinline__ float bf2f(short h) {
  return __uint_as_float(((unsigned)(unsigned short)h) << 16);
}
__device__ __forceinline__ void split2(float f, short& h, short& l) {
  h = f2bf(f);
  l = f2bf(f - bf2f(h));
}

// ============ bf16x3 MFMA GEMM: C[M,N] = A[M,K] @ W[N,K]^T + bias ============
// A given as hi/lo bf16 planes. W as planes (CONVB=0) or fp32 converted on the
// fly (CONVB=1). Optional fp32 C and/or hi/lo plane outputs Ch/Cl.
// 256 threads = 4 waves; 64x64 tile; wave -> 32x32 quadrant via 2x2 fragments.
template<int CONVB>
__device__ __forceinline__
void gemm_bf3_core(const short* __restrict__ Ah, const short* __restrict__ Al,
                   const short* __restrict__ Wh, const short* __restrict__ Wl,
                   const float* __restrict__ Wf,
                   const float* __restrict__ bias, float* __restrict__ C,
                   short* __restrict__ Ch, short* __restrict__ Cl,
                   int M, int N, int K)
{
  __shared__ short sA[2][64][40];   // [hi/lo][row][k], 80B row stride (16B aligned)
  __shared__ short sB[2][64][40];
  const int tid  = threadIdx.x;
  const int n0   = blockIdx.x * 64, m0 = blockIdx.y * 64;
  const int wave = tid >> 6, lane = tid & 63;
  const int wr = (wave >> 1) * 32, wc = (wave & 1) * 32;
  const int lr = lane & 15, lk = (lane >> 4) * 8;
  const int sr = tid >> 2, sk = (tid & 3) * 8;
  const int arow = m0 + sr;

  f32x4 acc[2][2] = {};

  for (int k0 = 0; k0 < K; k0 += 32) {
    bf16x8 ah = {}, al = {};
    if (arow < M) {
      ah = *(const bf16x8*)(Ah + (long)arow * K + k0 + sk);
      al = *(const bf16x8*)(Al + (long)arow * K + k0 + sk);
    }
    bf16x8 bh, bl;
    if (CONVB) {
      f32x4 w0 = *(const f32x4*)(Wf + (long)(n0 + sr) * K + k0 + sk);
      f32x4 w1 = *(const f32x4*)(Wf + (long)(n0 + sr) * K + k0 + sk + 4);
#pragma unroll
      for (int j = 0; j < 4; ++j) {
        short h, l;
        split2(w0[j], h, l); bh[j] = h;     bl[j] = l;
        split2(w1[j], h, l); bh[4 + j] = h; bl[4 + j] = l;
      }
    } else {
      bh = *(const bf16x8*)(Wh + (long)(n0 + sr) * K + k0 + sk);
      bl = *(const bf16x8*)(Wl + (long)(n0 + sr) * K + k0 + sk);
    }
    __syncthreads();
    *(bf16x8*)&sA[0][sr][sk] = ah;
    *(bf16x8*)&sA[1][sr][sk] = al;
    *(bf16x8*)&sB[0][sr][sk] = bh;
    *(bf16x8*)&sB[1][sr][sk] = bl;
    __syncthreads();

    bf16x8 a0h = *(const bf16x8*)&sA[0][wr + lr][lk];
    bf16x8 a1h = *(const bf16x8*)&sA[0][wr + 16 + lr][lk];
    bf16x8 a0l = *(const bf16x8*)&sA[1][wr + lr][lk];
    bf16x8 a1l = *(const bf16x8*)&sA[1][wr + 16 + lr][lk];
    bf16x8 b0h = *(const bf16x8*)&sB[0][wc + lr][lk];
    bf16x8 b1h = *(const bf16x8*)&sB[0][wc + 16 + lr][lk];
    bf16x8 b0l = *(const bf16x8*)&sB[1][wc + lr][lk];
    bf16x8 b1l = *(const bf16x8*)&sB[1][wc + 16 + lr][lk];

    acc[0][0] = __builtin_amdgcn_mfma_f32_16x16x32_bf16(a0h, b0h, acc[0][0], 0, 0, 0);
    acc[0][1] = __builtin_amdgcn_mfma_f32_16x16x32_bf16(a0h, b1h, acc[0][1], 0, 0, 0);
    acc[1][0] = __builtin_amdgcn_mfma_f32_16x16x32_bf16(a1h, b0h, acc[1][0], 0, 0, 0);
    acc[1][1] = __builtin_amdgcn_mfma_f32_16x16x32_bf16(a1h, b1h, acc[1][1], 0, 0, 0);
    acc[0][0] = __builtin_amdgcn_mfma_f32_16x16x32_bf16(a0h, b0l, acc[0][0], 0, 0, 0);
    acc[0][1] = __builtin_amdgcn_mfma_f32_16x16x32_bf16(a0h, b1l, acc[0][1], 0, 0, 0);
    acc[1][0] = __builtin_amdgcn_mfma_f32_16x16x32_bf16(a1h, b0l, acc[1][0], 0, 0, 0);
    acc[1][1] = __builtin_amdgcn_mfma_f32_16x16x32_bf16(a1h, b1l, acc[1][1], 0, 0, 0);
    acc[0][0] = __builtin_amdgcn_mfma_f32_16x16x32_bf16(a0l, b0h, acc[0][0], 0, 0, 0);
    acc[0][1] = __builtin_amdgcn_mfma_f32_16x16x32_bf16(a0l, b1h, acc[0][1], 0, 0, 0);
    acc[1][0] = __builtin_amdgcn_mfma_f32_16x16x32_bf16(a1l, b0h, acc[1][0], 0, 0, 0);
    acc[1][1] = __builtin_amdgcn_mfma_f32_16x16x32_bf16(a1l, b1h, acc[1][1], 0, 0, 0);
  }

  const int rbase = m0 + wr + (lane >> 4) * 4;
  const int cb = n0 + wc + lr;
#pragma unroll
  for (int fj = 0; fj < 2; ++fj) {
    int col = cb + fj * 16;
    float bz = bias ? bias[col] : 0.f;
#pragma unroll
    for (int fi = 0; fi < 2; ++fi) {
#pragma unroll
      for (int r = 0; r < 4; ++r) {
        int row = rbase + fi * 16 + r;
        if (row < M) {
          float v = acc[fi][fj][r] + bz;
          long o = (long)row * N + col;
          if (C) C[o] = v;
          if (Ch) { short h, l; split2(v, h, l); Ch[o] = h; Cl[o] = l; }
        }
      }
    }
  }
}

template<int CONVB>
__global__ __launch_bounds__(256)
void gemm_bf3_k(const short* Ah, const short* Al, const short* Wh, const short* Wl,
                const float* Wf, const float* bias, float* C, short* Ch, short* Cl,
                int M, int N, int K, long aBS, long wBS, long bBS, long cBS)
{
  long z = blockIdx.z;
  gemm_bf3_core<CONVB>(Ah + z * aBS, Al + z * aBS,
                       Wh ? Wh + z * wBS : nullptr, Wl ? Wl + z * wBS : nullptr,
                       Wf ? Wf + z * wBS : nullptr,
                       bias ? bias + z * bBS : nullptr,
                       C ? C + z * cBS : nullptr,
                       Ch ? Ch + z * cBS : nullptr, Cl ? Cl + z * cBS : nullptr,
                       M, N, K);
}

struct G4 { const short* wh[4]; const short* wl[4]; float* c[4]; };

__global__ __launch_bounds__(256)
void gemm4_bf3_k(const short* Ah, const short* Al, G4 g, int M, int N, int K)
{
  int z = blockIdx.z;
  gemm_bf3_core<0>(Ah, Al, g.wh[z], g.wl[z], nullptr, nullptr, g.c[z],
                   nullptr, nullptr, M, N, K);
}

// ============ conversion kernels ============
__global__ __launch_bounds__(256)
void cvt1_k(const float* __restrict__ s, short* __restrict__ dh,
            short* __restrict__ dl, int n4)
{
  long i = (long)blockIdx.x * 256 + threadIdx.x;
  if (i >= n4) return;
  f32x4 v = *(const f32x4*)(s + i * 4);
  s16x4 h, l;
#pragma unroll
  for (int j = 0; j < 4; ++j) { short hh, ll; split2(v[j], hh, ll); h[j] = hh; l[j] = ll; }
  *(s16x4*)(dh + i * 4) = h;
  *(s16x4*)(dl + i * 4) = l;
}

struct P10 { const float* s[10]; };

// 26 chunks of 131072 elems: famq,famk,armq,armk @0-3; famv @4-5; gnn u,v,a,b,e @6..25
__global__ __launch_bounds__(256)
void cvt_w_k(P10 p, short* __restrict__ dh, short* __restrict__ dl)
{
  static const int tens[26] = {0,1,2,3,4,4,5,5,5,5,6,6,6,6,7,7,7,7,8,8,8,8,9,9,9,9};
  static const int coff[26] = {0,0,0,0,0,1,0,1,2,3,0,1,2,3,0,1,2,3,0,1,2,3,0,1,2,3};
  int c = blockIdx.y;
  const float* src = p.s[tens[c]] + (long)coff[c] * 131072;
  long dbase = (long)c * 131072;
  long i = ((long)blockIdx.x * 256 + threadIdx.x) * 8;
  f32x4 v0 = *(const f32x4*)(src + i);
  f32x4 v1 = *(const f32x4*)(src + i + 4);
  s16x4 h0, l0, h1, l1;
#pragma unroll
  for (int j = 0; j < 4; ++j) {
    short hh, ll;
    split2(v0[j], hh, ll); h0[j] = hh; l0[j] = ll;
    split2(v1[j], hh, ll); h1[j] = hh; l1[j] = ll;
  }
  *(s16x4*)(dh + dbase + i) = h0;     *(s16x4*)(dh + dbase + i + 4) = h1;
  *(s16x4*)(dl + dbase + i) = l0;     *(s16x4*)(dl + dbase + i + 4) = l1;
}

// ============ small NN GEMM (W is [K,N]) — only for Mpre = ep_W @ arm_vW ============
__global__ __launch_bounds__(256)
void gemm_nn_k(const float* __restrict__ A, const float* __restrict__ W,
               float* __restrict__ C, int M, int N, int K)
{
  __shared__ float As[32][68];
  __shared__ float Ws[32][68];
  const int tid = threadIdx.x;
  const int n0 = blockIdx.x * 64, m0 = blockIdx.y * 64;
  const int tx = tid & 15, ty = tid >> 4;
  float acc[4][4] = {};
  for (int k0 = 0; k0 < K; k0 += 32) {
#pragma unroll
    for (int p = 0; p < 2; ++p) {
      int idx = tid + p * 256;
      int row = idx >> 3, kq = idx & 7;
      float4 v = make_float4(0.f, 0.f, 0.f, 0.f);
      if (m0 + row < M)
        v = *(const float4*)(A + (long)(m0 + row) * K + k0 + kq * 4);
      As[kq*4+0][row] = v.x; As[kq*4+1][row] = v.y;
      As[kq*4+2][row] = v.z; As[kq*4+3][row] = v.w;
    }
#pragma unroll
    for (int p = 0; p < 2; ++p) {
      int idx = tid + p * 256;
      int row = idx >> 4, nq = idx & 15;
      float4 v = *(const float4*)(W + (long)(k0 + row) * N + n0 + nq * 4);
      *(float4*)&Ws[row][nq*4] = v;
    }
    __syncthreads();
#pragma unroll
    for (int k = 0; k < 32; ++k) {
      float4 a4 = *(const float4*)&As[k][ty*4];
      float4 b4 = *(const float4*)&Ws[k][tx*4];
      float av[4] = {a4.x, a4.y, a4.z, a4.w};
      float bv[4] = {b4.x, b4.y, b4.z, b4.w};
#pragma unroll
      for (int i2 = 0; i2 < 4; ++i2)
#pragma unroll
        for (int j2 = 0; j2 < 4; ++j2)
          acc[i2][j2] = fmaf(av[i2], bv[j2], acc[i2][j2]);
    }
    __syncthreads();
  }
#pragma unroll
  for (int i2 = 0; i2 < 4; ++i2) {
    int m = m0 + ty*4 + i2;
    if (m < M)
      *(float4*)(C + (long)m * N + n0 + tx*4) =
        make_float4(acc[i2][0], acc[i2][1], acc[i2][2], acc[i2][3]);
  }
}

// ============ node-block BN ============
__global__ __launch_bounds__(256)
void nb_stats(const float* __restrict__ H, float* __restrict__ mean, float* __restrict__ rs)
{
  int n = blockIdx.x;
  int c = blockIdx.y * 256 + threadIdx.x;
  const float* p = H + (long)n * 196 * 512 + c;
  float s = 0.f, q = 0.f;
  for (int r = 0; r < 196; ++r) { float v = p[(long)r * 512]; s += v; q = fmaf(v, v, q); }
  float m = s * (1.f / 196.f);
  float var = q * (1.f / 196.f) - m * m;
  mean[n * 512 + c] = m;
  rs[n * 512 + c] = rsqrtf(var + EPS_);
}

__global__ __launch_bounds__(256)
void nb_apply(const float* __restrict__ H, const float* __restrict__ mean,
              const float* __restrict__ rs, const float* __restrict__ bw,
              const float* __restrict__ bb,
              short* __restrict__ fuh, short* __restrict__ ful,
              float* __restrict__ fv, short* __restrict__ fvh, short* __restrict__ fvl)
{
  int n = blockIdx.x, b = blockIdx.y;
  int t = threadIdx.x;
#pragma unroll
  for (int cq = 0; cq < 2; ++cq) {
    int c = cq * 256 + t;
    float m = mean[n*512+c], r = rs[n*512+c];
    float w = bw[n*512+c], bias = bb[n*512+c];
    const float* hp = H + ((long)(n*4+b)*49) * 512 + c;
    long fo0 = ((long)(n*4+b)*49) * 512 + c;
    float s = 0.f;
    for (int d = 0; d < 49; ++d) {
      float v = hp[(long)d*512];
      float o = fmaxf(fmaf((v - m) * r, w, bias), 0.f);
      short hh, ll; split2(o, hh, ll);
      fuh[fo0 + (long)d*512] = hh;
      ful[fo0 + (long)d*512] = ll;
      s += o;
    }
    float fvv = s * (1.f / 49.f);
    long fo = ((long)b*27+n)*512 + c;
    fv[fo] = fvv;
    short hh, ll; split2(fvv, hh, ll);
    fvh[fo] = hh; fvl[fo] = ll;
  }
}

// ============ FAM cross-attention (emits feat hi/lo planes, batch-major) ============
__global__ __launch_bounds__(512)
void attn_fam(const float* __restrict__ Qg, const float* __restrict__ Kg,
              const float* __restrict__ Vg, short* __restrict__ feath,
              short* __restrict__ featl)
{
  __shared__ float Qs[52][68];
  __shared__ float Ks[52][68];
  __shared__ float Ss[49][56];
  __shared__ float Vs[49][68];

  const int tid = threadIdx.x;
  const int bx = blockIdx.x, b = blockIdx.y;   // bx = node n
  const int qblk = bx*4 + b;                    // qfam is n-major
  const long obase = ((long)b*1323 + (long)bx*49) * 512;  // feat batch-major
  const float* qp = Qg + (long)qblk * (49 * 256);
  const float* kp = Kg + (long)b * (49 * 256);
  const float* vp = Vg + (long)b * (49 * 512);

  const int tx = tid & 15;
  const int ty4 = tid >> 4;

  float sacc[2][4] = {};
  const int d0 = ty4 * 2;
  const int e0 = tx * 4;
  const int eh0 = (e0+0)&7, eh1 = (e0+1)&7, eh2 = (e0+2)&7, eh3 = (e0+3)&7;
  const int er0 = (e0+0) > 51 ? 51 : (e0+0);
  const int er1 = (e0+1) > 51 ? 51 : (e0+1);
  const int er2 = (e0+2) > 51 ? 51 : (e0+2);
  const int er3 = (e0+3) > 51 ? 51 : (e0+3);
  for (int kc = 0; kc < 256; kc += 64) {
    for (int idx = tid; idx < 49 * 16; idx += 512) {
      int row = idx >> 4, kq = idx & 15;
      *(float4*)&Qs[row][kq*4] = *(const float4*)(qp + (long)row*256 + kc + kq*4);
      *(float4*)&Ks[row][(kq ^ (row & 7)) * 4] = *(const float4*)(kp + (long)row*256 + kc + kq*4);
    }
    __syncthreads();
    if (d0 < 49) {
      const float* q0 = &Qs[d0][0];
      const float* q1 = &Qs[d0 + 1][0];
      const float* k0 = &Ks[er0][0];
      const float* k1 = &Ks[er1][0];
      const float* k2 = &Ks[er2][0];
      const float* k3 = &Ks[er3][0];
#pragma unroll 4
      for (int kq = 0; kq < 16; ++kq) {
        float4 a0 = *(const float4*)(q0 + kq*4);
        float4 a1 = *(const float4*)(q1 + kq*4);
        float4 b0 = *(const float4*)(k0 + ((kq ^ eh0) * 4));
        float4 b1 = *(const float4*)(k1 + ((kq ^ eh1) * 4));
        float4 b2 = *(const float4*)(k2 + ((kq ^ eh2) * 4));
        float4 b3 = *(const float4*)(k3 + ((kq ^ eh3) * 4));
        float av0[4] = {a0.x, a0.y, a0.z, a0.w};
        float av1[4] = {a1.x, a1.y, a1.z, a1.w};
        float bv[4][4] = {{b0.x,b0.y,b0.z,b0.w},{b1.x,b1.y,b1.z,b1.w},
                          {b2.x,b2.y,b2.z,b2.w},{b3.x,b3.y,b3.z,b3.w}};
#pragma unroll
        for (int j2 = 0; j2 < 4; ++j2) {
#pragma unroll
          for (int qq = 0; qq < 4; ++qq) {
            sacc[0][j2] = fmaf(av0[qq], bv[j2][qq], sacc[0][j2]);
            sacc[1][j2] = fmaf(av1[qq], bv[j2][qq], sacc[1][j2]);
          }
        }
      }
    }
    __syncthreads();
  }
  if (d0 < 49) {
#pragma unroll
    for (int i2 = 0; i2 < 2; ++i2) {
      int d = d0 + i2;
      if (d < 49) {
#pragma unroll
        for (int j2 = 0; j2 < 4; ++j2) {
          int e = e0 + j2;
          if (e < 49) Ss[d][e] = sacc[i2][j2] * SCALE_;
        }
      }
    }
  }
  __syncthreads();

  if (tid < 49) {
    float mx = -1e30f;
    for (int e = 0; e < 49; ++e) mx = fmaxf(mx, Ss[tid][e]);
    float sum = 0.f;
    for (int e = 0; e < 49; ++e) { float ex = __expf(Ss[tid][e] - mx); Ss[tid][e] = ex; sum += ex; }
    float inv = 1.f / sum;
    for (int e = 0; e < 49; ++e) Ss[tid][e] *= inv;
  }
  __syncthreads();

  const int td = ty4;
  const bool has2 = (td + 32) < 49;
  for (int cc = 0; cc < 512; cc += 64) {
    for (int idx = tid; idx < 49 * 16; idx += 512) {
      int row = idx >> 4, cq = idx & 15;
      *(float4*)&Vs[row][cq*4] = *(const float4*)(vp + (long)row*512 + cc + cq*4);
    }
    __syncthreads();
    float pa[2][4] = {};
#pragma unroll 7
    for (int e = 0; e < 49; ++e) {
      float4 v4 = *(const float4*)&Vs[e][tx*4];
      float p0 = Ss[td][e];
      float p1 = has2 ? Ss[td + 32][e] : 0.f;
      pa[0][0] = fmaf(p0, v4.x, pa[0][0]); pa[0][1] = fmaf(p0, v4.y, pa[0][1]);
      pa[0][2] = fmaf(p0, v4.z, pa[0][2]); pa[0][3] = fmaf(p0, v4.w, pa[0][3]);
      pa[1][0] = fmaf(p1, v4.x, pa[1][0]); pa[1][1] = fmaf(p1, v4.y, pa[1][1]);
      pa[1][2] = fmaf(p1, v4.z, pa[1][2]); pa[1][3] = fmaf(p1, v4.w, pa[1][3]);
    }
    __syncthreads();
    s16x4 hh, ll;
#pragma unroll
    for (int j = 0; j < 4; ++j) { short h, l; split2(pa[0][j], h, l); hh[j] = h; ll[j] = l; }
    *(s16x4*)(feath + obase + (long)td*512 + cc + tx*4) = hh;
    *(s16x4*)(featl + obase + (long)td*512 + cc + tx*4) = ll;
    if (has2) {
#pragma unroll
      for (int j = 0; j < 4; ++j) { short h, l; split2(pa[1][j], h, l); hh[j] = h; ll[j] = l; }
      *(s16x4*)(feath + obase + (long)(td+32)*512 + cc + tx*4) = hh;
      *(s16x4*)(featl + obase + (long)(td+32)*512 + cc + tx*4) = ll;
    }
  }
}

// ============ bias2 = ep_W @ arm_vb + ep_b, plus B1 = sum(b2), nb2 = sum(b2^2) ============
__global__ __launch_bounds__(512)
void bias2red_k(const float* __restrict__ epW, const float* __restrict__ vb,
                const float* __restrict__ epb, float* __restrict__ bias2,
                float* __restrict__ b2st)
{
  int c = threadIdx.x;
  float s = epb[c];
  const float* r = epW + (long)c * 512;
  for (int k = 0; k < 512; ++k) s = fmaf(r[k], vb[k], s);
  bias2[c] = s;
  __shared__ float red[16];
  float s1 = s, s2 = s * s;
#pragma unroll
  for (int off = 32; off; off >>= 1) { s1 += __shfl_down(s1, off); s2 += __shfl_down(s2, off); }
  int lane = c & 63, wid = c >> 6;
  if (lane == 0) { red[wid] = s1; red[8 + wid] = s2; }
  __syncthreads();
  if (c == 0) {
    float a = 0.f, qq = 0.f;
#pragma unroll
    for (int w = 0; w < 8; ++w) { a += red[w]; qq += red[8 + w]; }
    b2st[0] = a; b2st[1] = qq;
  }
}

// ============ G = VW VW^T per (b,i), plus row sums ============
__constant__ unsigned char TI_c[28] = {0,1,1,2,2,2,3,3,3,3,4,4,4,4,4,5,5,5,5,5,5,6,6,6,6,6,6,6};
__constant__ unsigned char TJ_c[28] = {0,0,1,0,1,2,0,1,2,3,0,1,2,3,4,0,1,2,3,4,5,0,1,2,3,4,5,6};

__global__ __launch_bounds__(256)
void gmat_k(const float* __restrict__ VW, const float* __restrict__ b2,
            float* __restrict__ G, float* __restrict__ V1, float* __restrict__ Vb2)
{
  __shared__ float Vs[49][260];
  const int i = blockIdx.x, b = blockIdx.y;
  const int tid = threadIdx.x;
  const int wave = tid >> 6, lane = tid & 63;
  const int di = lane >> 3, ej = lane & 7;
  const float* vp = VW + ((long)b*1323 + (long)i*49) * 512;
  float gacc[7];
#pragma unroll
  for (int t = 0; t < 7; ++t) gacc[t] = 0.f;
  float s1 = 0.f, s2 = 0.f;

  for (int half = 0; half < 2; ++half) {
    __syncthreads();
    for (int idx = tid; idx < 49 * 64; idx += 256) {
      int r = idx >> 6, q = idx & 63;
      *(float4*)&Vs[r][q*4] = *(const float4*)(vp + (long)r*512 + half*256 + q*4);
    }
    __syncthreads();
    int tt = 0;
    for (int t = wave; t < 28; t += 4, ++tt) {
      int d = TI_c[t]*8 + di, e = TJ_c[t]*8 + ej;
      int dc = d > 48 ? 48 : d, ec = e > 48 ? 48 : e;
      float g = gacc[tt];
      for (int q = 0; q < 64; ++q) {
        float4 a = *(const float4*)&Vs[dc][q*4];
        float4 bq = *(const float4*)&Vs[ec][q*4];
        g = fmaf(a.x, bq.x, fmaf(a.y, bq.y, fmaf(a.z, bq.z, fmaf(a.w, bq.w, g))));
      }
      gacc[tt] = g;
    }
    if (tid < 49) {
      for (int c = 0; c < 256; ++c) {
        float v = Vs[tid][c];
        s1 += v; s2 = fmaf(v, b2[half*256 + c], s2);
      }
    }
  }
  long gbase = ((long)b*27 + i) * 2401;
  int tt = 0;
  for (int t = wave; t < 28; t += 4, ++tt) {
    int ti = TI_c[t], tj = TJ_c[t];
    int d = ti*8 + di, e = tj*8 + ej;
    if (d < 49 && e < 49) {
      G[gbase + d*49 + e] = gacc[tt];
      if (ti != tj) G[gbase + e*49 + d] = gacc[tt];
    }
  }
  if (tid < 49) {
    long o = ((long)b*27 + i) * 49 + tid;
    V1[o] = s1; Vb2[o] = s2;
  }
}

// ============ per-edge: segmented softmax, Pbar, BN partial sums ============
__global__ __launch_bounds__(64)
void arm_post(const float* __restrict__ S, const float* __restrict__ G,
              const float* __restrict__ V1, const float* __restrict__ Vb2,
              float* __restrict__ Pbar, float* __restrict__ parts)
{
  __shared__ float TP[49 * 53];
  __shared__ float TG[49 * 53];
  const int tid = threadIdx.x;
  const int x = blockIdx.x, b = blockIdx.y;
  const int i = x / 27, j = x - i * 27;
  const float* Sp = S + (long)b*1323*1344 + (long)j*49*1344 + (long)i*49;
  for (int idx = tid; idx < 2401; idx += 64) {
    unsigned d = ((unsigned)idx * 1338u) >> 16;
    unsigned e = (unsigned)idx - d * 49u;
    TP[d*53 + e] = Sp[(long)d*1344 + e];
  }
  const float* Gp = G + ((long)b*27 + i) * 2401;
  for (int idx = tid; idx < 2401; idx += 64) {
    unsigned d = ((unsigned)idx * 1338u) >> 16;
    unsigned e = (unsigned)idx - d * 49u;
    TG[d*53 + e] = Gp[idx];
  }
  __syncthreads();
  if (tid < 49) {
    float* pr = &TP[tid * 53];
    float mx = -1e30f;
    for (int e = 0; e < 49; ++e) mx = fmaxf(mx, pr[e]);
    float sum = 0.f;
    for (int e = 0; e < 49; ++e) { float ex = __expf(pr[e] - mx); pr[e] = ex; sum += ex; }
    float inv = 1.f / sum;
    for (int e = 0; e < 49; ++e) pr[e] *= inv;
  }
  __syncthreads();
  float lin = 0.f, pvb = 0.f;
  if (tid < 49) {
    float pb = 0.f;
    for (int d = 0; d < 49; ++d) pb += TP[d*53 + tid];
    Pbar[(((long)b*27 + i)*27 + j)*49 + tid] = pb;
    long vo = ((long)b*27 + i)*49 + tid;
    lin = pb * V1[vo];
    pvb = pb * Vb2[vo];
  }
  float q2 = 0.f;
  if (tid < 49) {
    const float* pr = &TP[tid * 53];
#pragma unroll 1
    for (int e = 0; e < 49; e += 7) {
      float t0=0.f,t1=0.f,t2=0.f,t3=0.f,t4=0.f,t5=0.f,t6=0.f;
      for (int e2 = 0; e2 < 49; ++e2) {
        float pv = pr[e2];
        const float* g = &TG[e2*53 + e];
        t0 = fmaf(pv, g[0], t0); t1 = fmaf(pv, g[1], t1);
        t2 = fmaf(pv, g[2], t2); t3 = fmaf(pv, g[3], t3);
        t4 = fmaf(pv, g[4], t4); t5 = fmaf(pv, g[5], t5);
        t6 = fmaf(pv, g[6], t6);
      }
      q2 += t0*pr[e] + t1*pr[e+1] + t2*pr[e+2] + t3*pr[e+3]
          + t4*pr[e+4] + t5*pr[e+5] + t6*pr[e+6];
    }
  }
  float r1 = lin, r2 = q2 + 2.f * pvb;
#pragma unroll
  for (int off = 32; off; off >>= 1) { r1 += __shfl_down(r1, off); r2 += __shfl_down(r2, off); }
  if (tid == 0) {
    long o = ((long)b*729 + x) * 2;
    parts[o] = r1; parts[o + 1] = r2;
  }
}

// ============ per-edge BN stats over (b,d,c) ============
__global__ __launch_bounds__(256)
void edge_fin(const float* __restrict__ parts, const float* __restrict__ b2st,
              float* __restrict__ ems)
{
  int e = blockIdx.x * 256 + threadIdx.x;
  if (e < 729) {
    float B1 = b2st[0], nb2 = b2st[1];
    float s = 196.f * B1, q = 196.f * nb2;
#pragma unroll
    for (int b = 0; b < 4; ++b) {
      s += parts[((long)b * 729 + e) * 2 + 0];
      q += parts[((long)b * 729 + e) * 2 + 1];
    }
    const float inv = 1.f / 100352.f;
    float m = s * inv;
    float var = q * inv - m * m;
    ems[e*2]   = m;
    ems[e*2+1] = rsqrtf(var + EPS_);
  }
}

// ============ f_e = BN( Pbar@VW/49 + b2 ), emits fp32 + planes ============
__global__ __launch_bounds__(256)
void fe_build(const float* __restrict__ Pbar, const float* __restrict__ VW,
              const float* __restrict__ b2, const float* __restrict__ ems,
              const float* __restrict__ gw, const float* __restrict__ gb,
              float* __restrict__ fe, short* __restrict__ feh, short* __restrict__ fel)
{
  __shared__ float Pb[27 * 49];
  const int i = blockIdx.x, b = blockIdx.y;
  const int tid = threadIdx.x;
  const float* pp = Pbar + ((long)b*27 + i) * 27 * 49;
  for (int idx = tid; idx < 1323; idx += 256) Pb[idx] = pp[idx];
  __syncthreads();
  const float* vp = VW + ((long)b*1323 + (long)i*49) * 512;
#pragma unroll 1
  for (int half = 0; half < 2; ++half) {
    int c = half * 256 + tid;
    float acc[27];
#pragma unroll
    for (int j = 0; j < 27; ++j) acc[j] = 0.f;
    for (int e = 0; e < 49; ++e) {
      float v = vp[(long)e*512 + c];
#pragma unroll
      for (int j = 0; j < 27; ++j) acc[j] = fmaf(Pb[j*49 + e], v, acc[j]);
    }
    float bz = b2[c];
#pragma unroll
    for (int j = 0; j < 27; ++j) {
      int ij = i*27 + j;
      float m = ems[ij*2], rs = ems[ij*2+1];
      float h = acc[j] * (1.f/49.f) + bz;
      float v = fmaf((h - m) * rs, gw[ij], gb[ij]);
      long o = ((long)b*729 + ij)*512 + c;
      fe[o] = v;
      short hh, ll; split2(v, hh, ll);
      feh[o] = hh; fel[o] = ll;
    }
  }
}

// ============ GNN kernels ============
__global__ __launch_bounds__(256)
void gnn_edge_bn(const float* __restrict__ vi, const float* __restrict__ vj,
                 const float* __restrict__ el, const float* __restrict__ wv,
                 const float* __restrict__ bv, float* fe,
                 short* __restrict__ feh, short* __restrict__ fel)
{
  int ij = blockIdx.x; int i = ij / 27, j = ij - i * 27;
  int t = threadIdx.x;
  __shared__ float red[18];
  float mv[8]; float s = 0.f, q = 0.f;
#pragma unroll
  for (int p = 0; p < 8; ++p) {
    int idx = p * 256 + t; int b = idx >> 9, c = idx & 511;
    float v = vi[((long)b*27+i)*512 + c] + vj[((long)b*27+j)*512 + c]
            + el[((long)b*729+ij)*512 + c];
    mv[p] = v; s += v; q = fmaf(v, v, q);
  }
  int lane = t & 63, wid = t >> 6;
#pragma unroll
  for (int off = 32; off; off >>= 1) { s += __shfl_down(s, off); q += __shfl_down(q, off); }
  if (lane == 0) { red[wid] = s; red[4 + wid] = q; }
  __syncthreads();
  if (t == 0) {
    float S = red[0]+red[1]+red[2]+red[3], Q = red[4]+red[5]+red[6]+red[7];
    float m = S * (1.f / 2048.f);
    red[16] = m;
    red[17] = rsqrtf(Q * (1.f / 2048.f) - m * m + EPS_);
  }
  __syncthreads();
  float m = red[16], rs = red[17];
  float w = wv[ij], bb = bv[ij];
#pragma unroll
  for (int p = 0; p < 8; ++p) {
    int idx = p * 256 + t; int b = idx >> 9, c = idx & 511;
    long o = ((long)b*729+ij)*512 + c;
    float nv = fe[o] + fmaxf(fmaf((mv[p] - m) * rs, w, bb), 0.f);
    fe[o] = nv;
    short hh, ll; split2(nv, hh, ll);
    feh[o] = hh; fel[o] = ll;
  }
}

__global__ __launch_bounds__(256)
void gnn_agg(const float* __restrict__ fe, const float* __restrict__ ui,
             const float* __restrict__ uj, float* __restrict__ agg)
{
  int i = blockIdx.x, b = blockIdx.y;
  int t = threadIdx.x;
#pragma unroll
  for (int cq = 0; cq < 2; ++cq) {
    int c = cq * 256 + t;
    float sg[27];
    float mx = -1e30f;
#pragma unroll
    for (int j = 0; j < 27; ++j) {
      float x = fe[((long)b*729 + i*27 + j)*512 + c];
      float sgm = 1.f / (1.f + __expf(-x));
      sg[j] = sgm; mx = fmaxf(mx, sgm);
    }
    float sum = 0.f;
#pragma unroll
    for (int j = 0; j < 27; ++j) { float e2 = __expf(sg[j] - mx); sg[j] = e2; sum += e2; }
    float acc = 0.f;
#pragma unroll
    for (int j = 0; j < 27; ++j)
      acc = fmaf(sg[j], uj[((long)b*27+j)*512 + c], acc);
    agg[((long)b*27+i)*512 + c] = ui[((long)b*27+i)*512 + c] + acc / (sum * 27.f);
  }
}

__global__ __launch_bounds__(256)
void gnn_node_bn(const float* __restrict__ agg, const float* __restrict__ wv,
                 const float* __restrict__ bv, float* fv,
                 short* __restrict__ fvh, short* __restrict__ fvl)
{
  int i = blockIdx.x;
  int t = threadIdx.x;
  __shared__ float red[18];
  float mv[8]; float s = 0.f, q = 0.f;
#pragma unroll
  for (int p = 0; p < 8; ++p) {
    int idx = p * 256 + t; int b = idx >> 9, c = idx & 511;
    float v = agg[((long)b*27+i)*512 + c];
    mv[p] = v; s += v; q = fmaf(v, v, q);
  }
  int lane = t & 63, wid = t >> 6;
#pragma unroll
  for (int off = 32; off; off >>= 1) { s += __shfl_down(s, off); q += __shfl_down(q, off); }
  if (lane == 0) { red[wid] = s; red[4 + wid] = q; }
  __syncthreads();
  if (t == 0) {
    float S = red[0]+red[1]+red[2]+red[3], Q = red[4]+red[5]+red[6]+red[7];
    float m = S * (1.f / 2048.f);
    red[16] = m;
    red[17] = rsqrtf(Q * (1.f / 2048.f) - m * m + EPS_);
  }
  __syncthreads();
  float m = red[16], rs = red[17];
  float w = wv[i], bb = bv[i];
#pragma unroll
  for (int p = 0; p < 8; ++p) {
    int idx = p * 256 + t; int b = idx >> 9, c = idx & 511;
    long o = ((long)b*27+i)*512 + c;
    float nv = fv[o] + fmaxf(fmaf((mv[p] - m) * rs, w, bb), 0.f);
    fv[o] = nv;
    short hh, ll; split2(nv, hh, ll);
    fvh[o] = hh; fvl[o] = ll;
  }
}

__constant__ int SUB_IDX_c[14] = {0,0,1,1,2,2,4,4,7,7,8,8,11,11};

__global__ __launch_bounds__(64)
void sc_k(const float* __restrict__ fv, const float* __restrict__ mainsc,
          const float* __restrict__ subsc, float* __restrict__ out)
{
  int o = blockIdx.x, b = blockIdx.y;
  int lane = threadIdx.x;
  int r; const float* ap;
  if (o < 27) { r = o; ap = mainsc + (long)o * 512; }
  else        { int k = o - 27; r = SUB_IDX_c[k]; ap = subsc + (long)k * 512; }
  const float* fp = fv + ((long)b*27 + r) * 512;
  float sff = 0.f, saa = 0.f, sfa = 0.f;
  for (int c = lane; c < 512; c += 64) {
    float f = fp[c];
    float a = fmaxf(ap[c], 0.f);
    sff = fmaf(f, f, sff); saa = fmaf(a, a, saa); sfa = fmaf(f, a, sfa);
  }
#pragma unroll
  for (int off = 32; off; off >>= 1) {
    sff += __shfl_down(sff, off); saa += __shfl_down(saa, off); sfa += __shfl_down(sfa, off);
  }
  if (lane == 0)
    out[b * 41 + o] = sfa / (fmaxf(sqrtf(sff), 1e-12f) * fmaxf(sqrtf(saa), 1e-12f));
}

} // namespace

extern "C" void kernel_launch(void* const* d_in, const int* in_sizes, int n_in,
                              void* d_out, int out_size, void* d_ws, size_t ws_size,
                              hipStream_t stream)
{
  (void)in_sizes; (void)n_in; (void)out_size; (void)ws_size;
  const float* x       = (const float*)d_in[0];
  const float* nb_W    = (const float*)d_in[1];
  const float* nb_b    = (const float*)d_in[2];
  const float* nb_bnw  = (const float*)d_in[3];
  const float* nb_bnb  = (const float*)d_in[4];
  const float* fam_qW  = (const float*)d_in[5];
  const float* fam_qb  = (const float*)d_in[6];
  const float* fam_kW  = (const float*)d_in[7];
  const float* fam_kb  = (const float*)d_in[8];
  const float* fam_vW  = (const float*)d_in[9];
  const float* fam_vb  = (const float*)d_in[10];
  const float* arm_qW  = (const float*)d_in[11];
  const float* arm_qb  = (const float*)d_in[12];
  const float* arm_kW  = (const float*)d_in[13];
  const float* arm_kb  = (const float*)d_in[14];
  const float* arm_vW  = (const float*)d_in[15];
  const float* arm_vb  = (const float*)d_in[16];
  const float* ep_W    = (const float*)d_in[17];
  const float* ep_b    = (const float*)d_in[18];
  const float* gem_bnw = (const float*)d_in[19];
  const float* gem_bnb = (const float*)d_in[20];
  const float* gnn_uW  = (const float*)d_in[21];
  const float* gnn_vW  = (const float*)d_in[22];
  const float* gnn_aW  = (const float*)d_in[23];
  const float* gnn_bW  = (const float*)d_in[24];
  const float* gnn_eW  = (const float*)d_in[25];
  const float* gnn_bnvw = (const float*)d_in[26];
  const float* gnn_bnvb = (const float*)d_in[27];
  const float* gnn_bnew = (const float*)d_in[28];
  const float* gnn_bneb = (const float*)d_in[29];
  const float* main_sc  = (const float*)d_in[30];
  const float* sub_sc   = (const float*)d_in[31];
  float* out = (float*)d_out;

  // ---- workspace carve: fp32 region then bf16 plane region (~92 MB total) ----
  char* wp = (char*)d_ws;
  auto carveF = [&](long n) -> float* { float* p = (float*)wp; wp += ((n + 15) & ~15L) * 4; return p; };
  auto carveS = [&](long n) -> short* { short* p = (short*)wp; wp += ((n + 15) & ~15L) * 2; return p; };

  float* Hnb   = carveF((long)27*196*512);   // dead after nb_apply; VW aliases
  float* S     = carveF((long)4*1323*1344);  // dead after arm_post; el aliases
  float* fe    = carveF((long)4*729*512);
  float* kf    = carveF(196*256);
  float* vf    = carveF(196*512);
  float* qfam  = carveF((long)5292*256);
  float* nbm   = carveF(27*512);
  float* nbr   = carveF(27*512);
  float* Mpre  = carveF(512*512);
  float* bias2 = carveF(512);
  float* b2st  = carveF(16);
  float* parts = carveF(4*729*2);
  float* ems   = carveF(1460);
  float* G     = carveF((long)108*2401);
  float* V1    = carveF(108*49);
  float* Vb2   = carveF(108*49);
  float* Pbar  = carveF((long)4*27*27*49);
  float* fv    = carveF(108*512);
  float* vi    = carveF(108*512);
  float* vj    = carveF(108*512);
  float* uj    = carveF(108*512);
  float* ui    = carveF(108*512);
  float* agg   = carveF(108*512);
  float* VW = Hnb;   // alias (Hnb dead after nb_apply)
  float* el = S;     // alias (S dead after arm_post)

  short* xh    = carveS(100352);
  short* xl    = carveS(100352);
  short* wph   = carveS((long)26*131072);    // weight hi planes (26 chunks)
  short* wpl   = carveS((long)26*131072);
  short* Mpreh = carveS(262144);
  short* Mprel = carveS(262144);
  short* fuh   = carveS((long)5292*512);     // dead after FAM-q GEMM; feath aliases
  short* ful   = carveS((long)5292*512);
  short* Qah   = carveS((long)5292*256);     // dead after S-GEMM; feh aliases
  short* Qal   = carveS((long)5292*256);
  short* Kah   = carveS((long)4*1344*256);
  short* Kal   = carveS((long)4*1344*256);
  short* fvh   = carveS(108*512);
  short* fvl   = carveS(108*512);
  short* feath = fuh;   // alias: fu last read step 6; feat written step 7
  short* featl = ful;
  short* feh   = Qah;   // alias: Qa last read step 13; fe planes written step 17
  short* fel   = Qal;   // (1,492,992 shorts fits in Qah/Qal's 1,354,752+pad... use both halves)
  // NOTE: feh needs 1,492,992 shorts; Qah region is 1,354,752. Spill into Qal start
  // would corrupt fel. Instead place feh across Qah+Qal contiguously and fel across
  // Kah+Kal contiguously (each pair is contiguous by carve order and >= 2.7M shorts).
  fel = Kah;

  // weight plane offsets (chunks of 131072 shorts)
  short* famqWh = wph + 0L*131072;        short* famqWl = wpl + 0L*131072;
  short* famkWh = wph + 1L*131072;        short* famkWl = wpl + 1L*131072;
  short* armqWh = wph + 2L*131072;        short* armqWl = wpl + 2L*131072;
  short* armkWh = wph + 3L*131072;        short* armkWl = wpl + 3L*131072;
  short* famvWh = wph + 4L*131072;        short* famvWl = wpl + 4L*131072;
  short* uWh    = wph + 6L*131072;        short* uWl    = wpl + 6L*131072;
  short* vWh    = wph + 10L*131072;       short* vWl    = wpl + 10L*131072;
  short* aWh    = wph + 14L*131072;       short* aWl    = wpl + 14L*131072;
  short* bWh    = wph + 18L*131072;       short* bWl    = wpl + 18L*131072;
  short* eWh    = wph + 22L*131072;       short* eWl    = wpl + 22L*131072;

  // ---- conversions ----
  cvt1_k<<<dim3(98), 256, 0, stream>>>(x, xh, xl, 25088);
  P10 p10;
  p10.s[0] = fam_qW; p10.s[1] = fam_kW; p10.s[2] = arm_qW; p10.s[3] = arm_kW;
  p10.s[4] = fam_vW; p10.s[5] = gnn_uW; p10.s[6] = gnn_vW; p10.s[7] = gnn_aW;
  p10.s[8] = gnn_bW; p10.s[9] = gnn_eW;
  cvt_w_k<<<dim3(64, 26), 256, 0, stream>>>(p10, wph, wpl);

  // 1) node-block GEMMs (W converted on the fly from fp32 nb_W)
  gemm_bf3_k<1><<<dim3(8,4,27), 256, 0, stream>>>(xh, xl, nullptr, nullptr, nb_W,
      nb_b, Hnb, nullptr, nullptr, 196, 512, 512, 0, 262144, 512, 100352);
  // 2-3) BN stats + apply -> fu planes, fv (+planes)
  nb_stats<<<dim3(27,2), 256, 0, stream>>>(Hnb, nbm, nbr);
  nb_apply<<<dim3(27,4), 256, 0, stream>>>(Hnb, nbm, nbr, nb_bnw, nb_bnb,
      fuh, ful, fv, fvh, fvl);
  // 4-5) FAM k, v
  gemm_bf3_k<0><<<dim3(4,4), 256, 0, stream>>>(xh, xl, famkWh, famkWl, nullptr,
      fam_kb, kf, nullptr, nullptr, 196, 256, 512, 0,0,0,0);
  gemm_bf3_k<0><<<dim3(8,4), 256, 0, stream>>>(xh, xl, famvWh, famvWl, nullptr,
      fam_vb, vf, nullptr, nullptr, 196, 512, 512, 0,0,0,0);
  // 6) FAM q (last read of fu planes)
  gemm_bf3_k<0><<<dim3(4,83), 256, 0, stream>>>(fuh, ful, famqWh, famqWl, nullptr,
      fam_qb, qfam, nullptr, nullptr, 5292, 256, 512, 0,0,0,0);
  // 7) FAM cross-attention -> feat planes (overlays fu planes; batch-major)
  attn_fam<<<dim3(27,4), 512, 0, stream>>>(qfam, kf, vf, feath, featl);
  // 8) ARM Q (planes only)
  gemm_bf3_k<0><<<dim3(4,83), 256, 0, stream>>>(feath, featl, armqWh, armqWl, nullptr,
      arm_qb, nullptr, Qah, Qal, 5292, 256, 512, 0,0,0,0);
  // 9) ARM K (per-batch, row-padded to 1344; planes only)
  gemm_bf3_k<0><<<dim3(4,21,4), 256, 0, stream>>>(feath, featl, armkWh, armkWl, nullptr,
      arm_kb, nullptr, Kah, Kal, 1323, 256, 512, (long)1323*512, 0, 0, (long)1344*256);
  // 10) Mpre = ep_W @ arm_vW (fp32) + convert
  gemm_nn_k<<<dim3(8,8), 256, 0, stream>>>(ep_W, arm_vW, Mpre, 512, 512, 512);
  cvt1_k<<<dim3(256), 256, 0, stream>>>(Mpre, Mpreh, Mprel, 65536);
  // 11) bias2 + scalar sums
  bias2red_k<<<dim3(1), 512, 0, stream>>>(ep_W, arm_vb, ep_b, bias2, b2st);
  // 12) VW = feat @ Mpre^T (fp32 out, overlays Hnb)
  gemm_bf3_k<0><<<dim3(8,83), 256, 0, stream>>>(feath, featl, Mpreh, Mprel, nullptr,
      nullptr, VW, nullptr, nullptr, 5292, 512, 512, 0,0,0,0);
  // 13) S_all[b] = Qa_b @ Ka_b^T (last read of Qa/Ka planes)
  gemm_bf3_k<0><<<dim3(21,21,4), 256, 0, stream>>>(Qah, Qal, Kah, Kal, nullptr,
      nullptr, S, nullptr, nullptr, 1323, 1344, 256,
      (long)1323*256, (long)1344*256, 0, (long)1323*1344);
  // 14) G = VW VW^T per (b,i) + row sums
  gmat_k<<<dim3(27,4), 256, 0, stream>>>(VW, bias2, G, V1, Vb2);
  // 15) segmented softmax + Pbar + BN partials (last read of S)
  arm_post<<<dim3(729,4), 64, 0, stream>>>(S, G, V1, Vb2, Pbar, parts);
  // 16) per-edge BN stats
  edge_fin<<<dim3(3), 256, 0, stream>>>(parts, b2st, ems);
  // 17) f_e = BN(Pbar@VW/49 + b2) -> fp32 + planes (planes overlay Qa/Ka)
  fe_build<<<dim3(27,4), 256, 0, stream>>>(Pbar, VW, bias2, ems, gem_bnw, gem_bnb,
      fe, feh, fel);
  // 18) 2 GatedGNN layers
  for (int l = 0; l < 2; ++l) {
    long wo = (long)l * 262144;
    G4 g4;
    g4.wh[0] = aWh + wo; g4.wl[0] = aWl + wo; g4.c[0] = vi;
    g4.wh[1] = bWh + wo; g4.wl[1] = bWl + wo; g4.c[1] = vj;
    g4.wh[2] = vWh + wo; g4.wl[2] = vWl + wo; g4.c[2] = uj;
    g4.wh[3] = uWh + wo; g4.wl[3] = uWl + wo; g4.c[3] = ui;
    gemm4_bf3_k<<<dim3(8,2,4), 256, 0, stream>>>(fvh, fvl, g4, 108, 512, 512);
    gemm_bf3_k<0><<<dim3(8,46), 256, 0, stream>>>(feh, fel, eWh + wo, eWl + wo, nullptr,
        nullptr, el, nullptr, nullptr, 2916, 512, 512, 0,0,0,0);
    gnn_edge_bn<<<dim3(729), 256, 0, stream>>>(vi, vj, el,
        gnn_bnew + (long)l*729, gnn_bneb + (long)l*729, fe, feh, fel);
    gnn_agg<<<dim3(27,4), 256, 0, stream>>>(fe, ui, uj, agg);
    gnn_node_bn<<<dim3(27), 256, 0, stream>>>(agg,
        gnn_bnvw + (long)l*27, gnn_bnvb + (long)l*27, fv, fvh, fvl);
  }
  // 19) cosine-similarity outputs [4,41]
  sc_k<<<dim3(41,4), 64, 0, stream>>>(fv, main_sc, sub_sc, out);
}

// Round 6
// 685.503 us; speedup vs baseline: 1.7344x; 1.0004x over previous
//
#include <hip/hip_runtime.h>
#include <hip/hip_bf16.h>
#include <math.h>

// MEFL forward. B=4, D=49, C=512, N=27, C2=256.
// R6: arm_post rewritten — 128 threads, no G LDS-stage (global/L2 reads),
// q2 = <P^T P, G> strip-parallel across all lanes (float4 LDS reads).
// Everything else identical to R5 (bf16x3 MFMA GEMMs, 686 us baseline).

namespace {

constexpr float SCALE_ = 0.0625f;   // 256^-0.5
constexpr float EPS_   = 1e-5f;

typedef __attribute__((ext_vector_type(8))) short bf16x8;
typedef __attribute__((ext_vector_type(4))) short s16x4;
typedef __attribute__((ext_vector_type(4))) float f32x4;

__device__ __forceinline__ short f2bf(float f) {
  unsigned u = __float_as_uint(f);
  u += 0x7fffu + ((u >> 16) & 1u);
  return (short)(u >> 16);
}
__device__ __forceinline__ float bf2f(short h) {
  return __uint_as_float(((unsigned)(unsigned short)h) << 16);
}
__device__ __forceinline__ void split2(float f, short& h, short& l) {
  h = f2bf(f);
  l = f2bf(f - bf2f(h));
}

// ============ bf16x3 MFMA GEMM: C[M,N] = A[M,K] @ W[N,K]^T + bias ============
template<int CONVB>
__device__ __forceinline__
void gemm_bf3_core(const short* __restrict__ Ah, const short* __restrict__ Al,
                   const short* __restrict__ Wh, const short* __restrict__ Wl,
                   const float* __restrict__ Wf,
                   const float* __restrict__ bias, float* __restrict__ C,
                   short* __restrict__ Ch, short* __restrict__ Cl,
                   int M, int N, int K)
{
  __shared__ short sA[2][64][40];   // [hi/lo][row][k], 80B row stride (16B aligned)
  __shared__ short sB[2][64][40];
  const int tid  = threadIdx.x;
  const int n0   = blockIdx.x * 64, m0 = blockIdx.y * 64;
  const int wave = tid >> 6, lane = tid & 63;
  const int wr = (wave >> 1) * 32, wc = (wave & 1) * 32;
  const int lr = lane & 15, lk = (lane >> 4) * 8;
  const int sr = tid >> 2, sk = (tid & 3) * 8;
  const int arow = m0 + sr;

  f32x4 acc[2][2] = {};

  for (int k0 = 0; k0 < K; k0 += 32) {
    bf16x8 ah = {}, al = {};
    if (arow < M) {
      ah = *(const bf16x8*)(Ah + (long)arow * K + k0 + sk);
      al = *(const bf16x8*)(Al + (long)arow * K + k0 + sk);
    }
    bf16x8 bh, bl;
    if (CONVB) {
      f32x4 w0 = *(const f32x4*)(Wf + (long)(n0 + sr) * K + k0 + sk);
      f32x4 w1 = *(const f32x4*)(Wf + (long)(n0 + sr) * K + k0 + sk + 4);
#pragma unroll
      for (int j = 0; j < 4; ++j) {
        short h, l;
        split2(w0[j], h, l); bh[j] = h;     bl[j] = l;
        split2(w1[j], h, l); bh[4 + j] = h; bl[4 + j] = l;
      }
    } else {
      bh = *(const bf16x8*)(Wh + (long)(n0 + sr) * K + k0 + sk);
      bl = *(const bf16x8*)(Wl + (long)(n0 + sr) * K + k0 + sk);
    }
    __syncthreads();
    *(bf16x8*)&sA[0][sr][sk] = ah;
    *(bf16x8*)&sA[1][sr][sk] = al;
    *(bf16x8*)&sB[0][sr][sk] = bh;
    *(bf16x8*)&sB[1][sr][sk] = bl;
    __syncthreads();

    bf16x8 a0h = *(const bf16x8*)&sA[0][wr + lr][lk];
    bf16x8 a1h = *(const bf16x8*)&sA[0][wr + 16 + lr][lk];
    bf16x8 a0l = *(const bf16x8*)&sA[1][wr + lr][lk];
    bf16x8 a1l = *(const bf16x8*)&sA[1][wr + 16 + lr][lk];
    bf16x8 b0h = *(const bf16x8*)&sB[0][wc + lr][lk];
    bf16x8 b1h = *(const bf16x8*)&sB[0][wc + 16 + lr][lk];
    bf16x8 b0l = *(const bf16x8*)&sB[1][wc + lr][lk];
    bf16x8 b1l = *(const bf16x8*)&sB[1][wc + 16 + lr][lk];

    acc[0][0] = __builtin_amdgcn_mfma_f32_16x16x32_bf16(a0h, b0h, acc[0][0], 0, 0, 0);
    acc[0][1] = __builtin_amdgcn_mfma_f32_16x16x32_bf16(a0h, b1h, acc[0][1], 0, 0, 0);
    acc[1][0] = __builtin_amdgcn_mfma_f32_16x16x32_bf16(a1h, b0h, acc[1][0], 0, 0, 0);
    acc[1][1] = __builtin_amdgcn_mfma_f32_16x16x32_bf16(a1h, b1h, acc[1][1], 0, 0, 0);
    acc[0][0] = __builtin_amdgcn_mfma_f32_16x16x32_bf16(a0h, b0l, acc[0][0], 0, 0, 0);
    acc[0][1] = __builtin_amdgcn_mfma_f32_16x16x32_bf16(a0h, b1l, acc[0][1], 0, 0, 0);
    acc[1][0] = __builtin_amdgcn_mfma_f32_16x16x32_bf16(a1h, b0l, acc[1][0], 0, 0, 0);
    acc[1][1] = __builtin_amdgcn_mfma_f32_16x16x32_bf16(a1h, b1l, acc[1][1], 0, 0, 0);
    acc[0][0] = __builtin_amdgcn_mfma_f32_16x16x32_bf16(a0l, b0h, acc[0][0], 0, 0, 0);
    acc[0][1] = __builtin_amdgcn_mfma_f32_16x16x32_bf16(a0l, b1h, acc[0][1], 0, 0, 0);
    acc[1][0] = __builtin_amdgcn_mfma_f32_16x16x32_bf16(a1l, b0h, acc[1][0], 0, 0, 0);
    acc[1][1] = __builtin_amdgcn_mfma_f32_16x16x32_bf16(a1l, b1h, acc[1][1], 0, 0, 0);
  }

  const int rbase = m0 + wr + (lane >> 4) * 4;
  const int cb = n0 + wc + lr;
#pragma unroll
  for (int fj = 0; fj < 2; ++fj) {
    int col = cb + fj * 16;
    float bz = bias ? bias[col] : 0.f;
#pragma unroll
    for (int fi = 0; fi < 2; ++fi) {
#pragma unroll
      for (int r = 0; r < 4; ++r) {
        int row = rbase + fi * 16 + r;
        if (row < M) {
          float v = acc[fi][fj][r] + bz;
          long o = (long)row * N + col;
          if (C) C[o] = v;
          if (Ch) { short h, l; split2(v, h, l); Ch[o] = h; Cl[o] = l; }
        }
      }
    }
  }
}

template<int CONVB>
__global__ __launch_bounds__(256)
void gemm_bf3_k(const short* Ah, const short* Al, const short* Wh, const short* Wl,
                const float* Wf, const float* bias, float* C, short* Ch, short* Cl,
                int M, int N, int K, long aBS, long wBS, long bBS, long cBS)
{
  long z = blockIdx.z;
  gemm_bf3_core<CONVB>(Ah + z * aBS, Al + z * aBS,
                       Wh ? Wh + z * wBS : nullptr, Wl ? Wl + z * wBS : nullptr,
                       Wf ? Wf + z * wBS : nullptr,
                       bias ? bias + z * bBS : nullptr,
                       C ? C + z * cBS : nullptr,
                       Ch ? Ch + z * cBS : nullptr, Cl ? Cl + z * cBS : nullptr,
                       M, N, K);
}

struct G4 { const short* wh[4]; const short* wl[4]; float* c[4]; };

__global__ __launch_bounds__(256)
void gemm4_bf3_k(const short* Ah, const short* Al, G4 g, int M, int N, int K)
{
  int z = blockIdx.z;
  gemm_bf3_core<0>(Ah, Al, g.wh[z], g.wl[z], nullptr, nullptr, g.c[z],
                   nullptr, nullptr, M, N, K);
}

// ============ conversion kernels ============
__global__ __launch_bounds__(256)
void cvt1_k(const float* __restrict__ s, short* __restrict__ dh,
            short* __restrict__ dl, int n4)
{
  long i = (long)blockIdx.x * 256 + threadIdx.x;
  if (i >= n4) return;
  f32x4 v = *(const f32x4*)(s + i * 4);
  s16x4 h, l;
#pragma unroll
  for (int j = 0; j < 4; ++j) { short hh, ll; split2(v[j], hh, ll); h[j] = hh; l[j] = ll; }
  *(s16x4*)(dh + i * 4) = h;
  *(s16x4*)(dl + i * 4) = l;
}

struct P10 { const float* s[10]; };

// 26 chunks of 131072 elems: famq,famk,armq,armk @0-3; famv @4-5; gnn u,v,a,b,e @6..25
__global__ __launch_bounds__(256)
void cvt_w_k(P10 p, short* __restrict__ dh, short* __restrict__ dl)
{
  static const int tens[26] = {0,1,2,3,4,4,5,5,5,5,6,6,6,6,7,7,7,7,8,8,8,8,9,9,9,9};
  static const int coff[26] = {0,0,0,0,0,1,0,1,2,3,0,1,2,3,0,1,2,3,0,1,2,3,0,1,2,3};
  int c = blockIdx.y;
  const float* src = p.s[tens[c]] + (long)coff[c] * 131072;
  long dbase = (long)c * 131072;
  long i = ((long)blockIdx.x * 256 + threadIdx.x) * 8;
  f32x4 v0 = *(const f32x4*)(src + i);
  f32x4 v1 = *(const f32x4*)(src + i + 4);
  s16x4 h0, l0, h1, l1;
#pragma unroll
  for (int j = 0; j < 4; ++j) {
    short hh, ll;
    split2(v0[j], hh, ll); h0[j] = hh; l0[j] = ll;
    split2(v1[j], hh, ll); h1[j] = hh; l1[j] = ll;
  }
  *(s16x4*)(dh + dbase + i) = h0;     *(s16x4*)(dh + dbase + i + 4) = h1;
  *(s16x4*)(dl + dbase + i) = l0;     *(s16x4*)(dl + dbase + i + 4) = l1;
}

// ============ small NN GEMM (W is [K,N]) — only for Mpre = ep_W @ arm_vW ============
__global__ __launch_bounds__(256)
void gemm_nn_k(const float* __restrict__ A, const float* __restrict__ W,
               float* __restrict__ C, int M, int N, int K)
{
  __shared__ float As[32][68];
  __shared__ float Ws[32][68];
  const int tid = threadIdx.x;
  const int n0 = blockIdx.x * 64, m0 = blockIdx.y * 64;
  const int tx = tid & 15, ty = tid >> 4;
  float acc[4][4] = {};
  for (int k0 = 0; k0 < K; k0 += 32) {
#pragma unroll
    for (int p = 0; p < 2; ++p) {
      int idx = tid + p * 256;
      int row = idx >> 3, kq = idx & 7;
      float4 v = make_float4(0.f, 0.f, 0.f, 0.f);
      if (m0 + row < M)
        v = *(const float4*)(A + (long)(m0 + row) * K + k0 + kq * 4);
      As[kq*4+0][row] = v.x; As[kq*4+1][row] = v.y;
      As[kq*4+2][row] = v.z; As[kq*4+3][row] = v.w;
    }
#pragma unroll
    for (int p = 0; p < 2; ++p) {
      int idx = tid + p * 256;
      int row = idx >> 4, nq = idx & 15;
      float4 v = *(const float4*)(W + (long)(k0 + row) * N + n0 + nq * 4);
      *(float4*)&Ws[row][nq*4] = v;
    }
    __syncthreads();
#pragma unroll
    for (int k = 0; k < 32; ++k) {
      float4 a4 = *(const float4*)&As[k][ty*4];
      float4 b4 = *(const float4*)&Ws[k][tx*4];
      float av[4] = {a4.x, a4.y, a4.z, a4.w};
      float bv[4] = {b4.x, b4.y, b4.z, b4.w};
#pragma unroll
      for (int i2 = 0; i2 < 4; ++i2)
#pragma unroll
        for (int j2 = 0; j2 < 4; ++j2)
          acc[i2][j2] = fmaf(av[i2], bv[j2], acc[i2][j2]);
    }
    __syncthreads();
  }
#pragma unroll
  for (int i2 = 0; i2 < 4; ++i2) {
    int m = m0 + ty*4 + i2;
    if (m < M)
      *(float4*)(C + (long)m * N + n0 + tx*4) =
        make_float4(acc[i2][0], acc[i2][1], acc[i2][2], acc[i2][3]);
  }
}

// ============ node-block BN ============
__global__ __launch_bounds__(256)
void nb_stats(const float* __restrict__ H, float* __restrict__ mean, float* __restrict__ rs)
{
  int n = blockIdx.x;
  int c = blockIdx.y * 256 + threadIdx.x;
  const float* p = H + (long)n * 196 * 512 + c;
  float s = 0.f, q = 0.f;
  for (int r = 0; r < 196; ++r) { float v = p[(long)r * 512]; s += v; q = fmaf(v, v, q); }
  float m = s * (1.f / 196.f);
  float var = q * (1.f / 196.f) - m * m;
  mean[n * 512 + c] = m;
  rs[n * 512 + c] = rsqrtf(var + EPS_);
}

__global__ __launch_bounds__(256)
void nb_apply(const float* __restrict__ H, const float* __restrict__ mean,
              const float* __restrict__ rs, const float* __restrict__ bw,
              const float* __restrict__ bb,
              short* __restrict__ fuh, short* __restrict__ ful,
              float* __restrict__ fv, short* __restrict__ fvh, short* __restrict__ fvl)
{
  int n = blockIdx.x, b = blockIdx.y;
  int t = threadIdx.x;
#pragma unroll
  for (int cq = 0; cq < 2; ++cq) {
    int c = cq * 256 + t;
    float m = mean[n*512+c], r = rs[n*512+c];
    float w = bw[n*512+c], bias = bb[n*512+c];
    const float* hp = H + ((long)(n*4+b)*49) * 512 + c;
    long fo0 = ((long)(n*4+b)*49) * 512 + c;
    float s = 0.f;
    for (int d = 0; d < 49; ++d) {
      float v = hp[(long)d*512];
      float o = fmaxf(fmaf((v - m) * r, w, bias), 0.f);
      short hh, ll; split2(o, hh, ll);
      fuh[fo0 + (long)d*512] = hh;
      ful[fo0 + (long)d*512] = ll;
      s += o;
    }
    float fvv = s * (1.f / 49.f);
    long fo = ((long)b*27+n)*512 + c;
    fv[fo] = fvv;
    short hh, ll; split2(fvv, hh, ll);
    fvh[fo] = hh; fvl[fo] = ll;
  }
}

// ============ FAM cross-attention (emits feat hi/lo planes, batch-major) ============
__global__ __launch_bounds__(512)
void attn_fam(const float* __restrict__ Qg, const float* __restrict__ Kg,
              const float* __restrict__ Vg, short* __restrict__ feath,
              short* __restrict__ featl)
{
  __shared__ float Qs[52][68];
  __shared__ float Ks[52][68];
  __shared__ float Ss[49][56];
  __shared__ float Vs[49][68];

  const int tid = threadIdx.x;
  const int bx = blockIdx.x, b = blockIdx.y;   // bx = node n
  const int qblk = bx*4 + b;                    // qfam is n-major
  const long obase = ((long)b*1323 + (long)bx*49) * 512;  // feat batch-major
  const float* qp = Qg + (long)qblk * (49 * 256);
  const float* kp = Kg + (long)b * (49 * 256);
  const float* vp = Vg + (long)b * (49 * 512);

  const int tx = tid & 15;
  const int ty4 = tid >> 4;

  float sacc[2][4] = {};
  const int d0 = ty4 * 2;
  const int e0 = tx * 4;
  const int eh0 = (e0+0)&7, eh1 = (e0+1)&7, eh2 = (e0+2)&7, eh3 = (e0+3)&7;
  const int er0 = (e0+0) > 51 ? 51 : (e0+0);
  const int er1 = (e0+1) > 51 ? 51 : (e0+1);
  const int er2 = (e0+2) > 51 ? 51 : (e0+2);
  const int er3 = (e0+3) > 51 ? 51 : (e0+3);
  for (int kc = 0; kc < 256; kc += 64) {
    for (int idx = tid; idx < 49 * 16; idx += 512) {
      int row = idx >> 4, kq = idx & 15;
      *(float4*)&Qs[row][kq*4] = *(const float4*)(qp + (long)row*256 + kc + kq*4);
      *(float4*)&Ks[row][(kq ^ (row & 7)) * 4] = *(const float4*)(kp + (long)row*256 + kc + kq*4);
    }
    __syncthreads();
    if (d0 < 49) {
      const float* q0 = &Qs[d0][0];
      const float* q1 = &Qs[d0 + 1][0];
      const float* k0 = &Ks[er0][0];
      const float* k1 = &Ks[er1][0];
      const float* k2 = &Ks[er2][0];
      const float* k3 = &Ks[er3][0];
#pragma unroll 4
      for (int kq = 0; kq < 16; ++kq) {
        float4 a0 = *(const float4*)(q0 + kq*4);
        float4 a1 = *(const float4*)(q1 + kq*4);
        float4 b0 = *(const float4*)(k0 + ((kq ^ eh0) * 4));
        float4 b1 = *(const float4*)(k1 + ((kq ^ eh1) * 4));
        float4 b2 = *(const float4*)(k2 + ((kq ^ eh2) * 4));
        float4 b3 = *(const float4*)(k3 + ((kq ^ eh3) * 4));
        float av0[4] = {a0.x, a0.y, a0.z, a0.w};
        float av1[4] = {a1.x, a1.y, a1.z, a1.w};
        float bv[4][4] = {{b0.x,b0.y,b0.z,b0.w},{b1.x,b1.y,b1.z,b1.w},
                          {b2.x,b2.y,b2.z,b2.w},{b3.x,b3.y,b3.z,b3.w}};
#pragma unroll
        for (int j2 = 0; j2 < 4; ++j2) {
#pragma unroll
          for (int qq = 0; qq < 4; ++qq) {
            sacc[0][j2] = fmaf(av0[qq], bv[j2][qq], sacc[0][j2]);
            sacc[1][j2] = fmaf(av1[qq], bv[j2][qq], sacc[1][j2]);
          }
        }
      }
    }
    __syncthreads();
  }
  if (d0 < 49) {
#pragma unroll
    for (int i2 = 0; i2 < 2; ++i2) {
      int d = d0 + i2;
      if (d < 49) {
#pragma unroll
        for (int j2 = 0; j2 < 4; ++j2) {
          int e = e0 + j2;
          if (e < 49) Ss[d][e] = sacc[i2][j2] * SCALE_;
        }
      }
    }
  }
  __syncthreads();

  if (tid < 49) {
    float mx = -1e30f;
    for (int e = 0; e < 49; ++e) mx = fmaxf(mx, Ss[tid][e]);
    float sum = 0.f;
    for (int e = 0; e < 49; ++e) { float ex = __expf(Ss[tid][e] - mx); Ss[tid][e] = ex; sum += ex; }
    float inv = 1.f / sum;
    for (int e = 0; e < 49; ++e) Ss[tid][e] *= inv;
  }
  __syncthreads();

  const int td = ty4;
  const bool has2 = (td + 32) < 49;
  for (int cc = 0; cc < 512; cc += 64) {
    for (int idx = tid; idx < 49 * 16; idx += 512) {
      int row = idx >> 4, cq = idx & 15;
      *(float4*)&Vs[row][cq*4] = *(const float4*)(vp + (long)row*512 + cc + cq*4);
    }
    __syncthreads();
    float pa[2][4] = {};
#pragma unroll 7
    for (int e = 0; e < 49; ++e) {
      float4 v4 = *(const float4*)&Vs[e][tx*4];
      float p0 = Ss[td][e];
      float p1 = has2 ? Ss[td + 32][e] : 0.f;
      pa[0][0] = fmaf(p0, v4.x, pa[0][0]); pa[0][1] = fmaf(p0, v4.y, pa[0][1]);
      pa[0][2] = fmaf(p0, v4.z, pa[0][2]); pa[0][3] = fmaf(p0, v4.w, pa[0][3]);
      pa[1][0] = fmaf(p1, v4.x, pa[1][0]); pa[1][1] = fmaf(p1, v4.y, pa[1][1]);
      pa[1][2] = fmaf(p1, v4.z, pa[1][2]); pa[1][3] = fmaf(p1, v4.w, pa[1][3]);
    }
    __syncthreads();
    s16x4 hh, ll;
#pragma unroll
    for (int j = 0; j < 4; ++j) { short h, l; split2(pa[0][j], h, l); hh[j] = h; ll[j] = l; }
    *(s16x4*)(feath + obase + (long)td*512 + cc + tx*4) = hh;
    *(s16x4*)(featl + obase + (long)td*512 + cc + tx*4) = ll;
    if (has2) {
#pragma unroll
      for (int j = 0; j < 4; ++j) { short h, l; split2(pa[1][j], h, l); hh[j] = h; ll[j] = l; }
      *(s16x4*)(feath + obase + (long)(td+32)*512 + cc + tx*4) = hh;
      *(s16x4*)(featl + obase + (long)(td+32)*512 + cc + tx*4) = ll;
    }
  }
}

// ============ bias2 = ep_W @ arm_vb + ep_b, plus B1 = sum(b2), nb2 = sum(b2^2) ============
__global__ __launch_bounds__(512)
void bias2red_k(const float* __restrict__ epW, const float* __restrict__ vb,
                const float* __restrict__ epb, float* __restrict__ bias2,
                float* __restrict__ b2st)
{
  int c = threadIdx.x;
  float s = epb[c];
  const float* r = epW + (long)c * 512;
  for (int k = 0; k < 512; ++k) s = fmaf(r[k], vb[k], s);
  bias2[c] = s;
  __shared__ float red[16];
  float s1 = s, s2 = s * s;
#pragma unroll
  for (int off = 32; off; off >>= 1) { s1 += __shfl_down(s1, off); s2 += __shfl_down(s2, off); }
  int lane = c & 63, wid = c >> 6;
  if (lane == 0) { red[wid] = s1; red[8 + wid] = s2; }
  __syncthreads();
  if (c == 0) {
    float a = 0.f, qq = 0.f;
#pragma unroll
    for (int w = 0; w < 8; ++w) { a += red[w]; qq += red[8 + w]; }
    b2st[0] = a; b2st[1] = qq;
  }
}

// ============ G = VW VW^T per (b,i), plus row sums ============
__constant__ unsigned char TI_c[28] = {0,1,1,2,2,2,3,3,3,3,4,4,4,4,4,5,5,5,5,5,5,6,6,6,6,6,6,6};
__constant__ unsigned char TJ_c[28] = {0,0,1,0,1,2,0,1,2,3,0,1,2,3,4,0,1,2,3,4,5,0,1,2,3,4,5,6};

__global__ __launch_bounds__(256)
void gmat_k(const float* __restrict__ VW, const float* __restrict__ b2,
            float* __restrict__ G, float* __restrict__ V1, float* __restrict__ Vb2)
{
  __shared__ float Vs[49][260];
  const int i = blockIdx.x, b = blockIdx.y;
  const int tid = threadIdx.x;
  const int wave = tid >> 6, lane = tid & 63;
  const int di = lane >> 3, ej = lane & 7;
  const float* vp = VW + ((long)b*1323 + (long)i*49) * 512;
  float gacc[7];
#pragma unroll
  for (int t = 0; t < 7; ++t) gacc[t] = 0.f;
  float s1 = 0.f, s2 = 0.f;

  for (int half = 0; half < 2; ++half) {
    __syncthreads();
    for (int idx = tid; idx < 49 * 64; idx += 256) {
      int r = idx >> 6, q = idx & 63;
      *(float4*)&Vs[r][q*4] = *(const float4*)(vp + (long)r*512 + half*256 + q*4);
    }
    __syncthreads();
    int tt = 0;
    for (int t = wave; t < 28; t += 4, ++tt) {
      int d = TI_c[t]*8 + di, e = TJ_c[t]*8 + ej;
      int dc = d > 48 ? 48 : d, ec = e > 48 ? 48 : e;
      float g = gacc[tt];
      for (int q = 0; q < 64; ++q) {
        float4 a = *(const float4*)&Vs[dc][q*4];
        float4 bq = *(const float4*)&Vs[ec][q*4];
        g = fmaf(a.x, bq.x, fmaf(a.y, bq.y, fmaf(a.z, bq.z, fmaf(a.w, bq.w, g))));
      }
      gacc[tt] = g;
    }
    if (tid < 49) {
      for (int c = 0; c < 256; ++c) {
        float v = Vs[tid][c];
        s1 += v; s2 = fmaf(v, b2[half*256 + c], s2);
      }
    }
  }
  long gbase = ((long)b*27 + i) * 2401;
  int tt = 0;
  for (int t = wave; t < 28; t += 4, ++tt) {
    int ti = TI_c[t], tj = TJ_c[t];
    int d = ti*8 + di, e = tj*8 + ej;
    if (d < 49 && e < 49) {
      G[gbase + d*49 + e] = gacc[tt];
      if (ti != tj) G[gbase + e*49 + d] = gacc[tt];
    }
  }
  if (tid < 49) {
    long o = ((long)b*27 + i) * 49 + tid;
    V1[o] = s1; Vb2[o] = s2;
  }
}

// ============ per-edge: segmented softmax, Pbar, BN partial sums ============
// R6 rewrite: 128 threads; P staged in LDS (padded to 56, pad zeroed);
// G read straight from global (L2-shared across the 27 j-blocks per (b,i));
// q2 = <P^T P, G> via 343 strips (e, 8-wide e2 block) across all lanes.
__global__ __launch_bounds__(128)
void arm_post(const float* __restrict__ S, const float* __restrict__ G,
              const float* __restrict__ V1, const float* __restrict__ Vb2,
              float* __restrict__ Pbar, float* __restrict__ parts)
{
  __shared__ float TP[49 * 56];
  __shared__ float red[8];
  const int tid = threadIdx.x;
  const int x = blockIdx.x, b = blockIdx.y;
  const int i = x / 27, j = x - i * 27;
  const float* Sp = S + (long)b*1323*1344 + (long)j*49*1344 + (long)i*49;
  for (int idx = tid; idx < 2401; idx += 128) {
    unsigned d = ((unsigned)idx * 1338u) >> 16;
    unsigned e = (unsigned)idx - d * 49u;
    TP[d*56 + e] = Sp[(long)d*1344 + e];
  }
  // zero pad columns 49..55 (strips read float4 past col 48; zeros contribute 0)
  for (int idx = tid; idx < 343; idx += 128) {
    int d = idx / 7, e = 49 + idx - d * 7;
    TP[d*56 + e] = 0.f;
  }
  __syncthreads();

  // row softmax (rows 0..48)
  if (tid < 49) {
    float* pr = &TP[tid * 56];
    float mx = -1e30f;
    for (int e = 0; e < 49; ++e) mx = fmaxf(mx, pr[e]);
    float sum = 0.f;
    for (int e = 0; e < 49; ++e) { float ex = __expf(pr[e] - mx); pr[e] = ex; sum += ex; }
    float inv = 1.f / sum;
    for (int e = 0; e < 49; ++e) pr[e] *= inv;
  }
  __syncthreads();

  // Pbar (column sums) + linear BN terms
  float lin = 0.f, pvb = 0.f;
  if (tid < 49) {
    float pb = 0.f;
    for (int d = 0; d < 49; ++d) pb += TP[d*56 + tid];
    Pbar[(((long)b*27 + i)*27 + j)*49 + tid] = pb;
    long vo = ((long)b*27 + i)*49 + tid;
    lin = pb * V1[vo];
    pvb = pb * Vb2[vo];
  }

  // q2 = sum_{e,e2} M[e,e2] G[e,e2], M = P^T P; strips: (e, e2 in [8k, 8k+7])
  float q2 = 0.f;
  const float* Gp = G + ((long)b*27 + i) * 2401;
  for (int s = tid; s < 343; s += 128) {
    int e = s / 7;
    int k8 = (s - e * 7) * 8;
    float t[8];
#pragma unroll
    for (int k = 0; k < 8; ++k) t[k] = 0.f;
    for (int d = 0; d < 49; ++d) {
      float pe = TP[d*56 + e];
      f32x4 a = *(const f32x4*)&TP[d*56 + k8];
      f32x4 bq = *(const f32x4*)&TP[d*56 + k8 + 4];
      t[0] = fmaf(pe, a[0], t[0]); t[1] = fmaf(pe, a[1], t[1]);
      t[2] = fmaf(pe, a[2], t[2]); t[3] = fmaf(pe, a[3], t[3]);
      t[4] = fmaf(pe, bq[0], t[4]); t[5] = fmaf(pe, bq[1], t[5]);
      t[6] = fmaf(pe, bq[2], t[6]); t[7] = fmaf(pe, bq[3], t[7]);
    }
    const float* g = Gp + e * 49 + k8;
    int lim = 49 - k8;                 // >= 1
#pragma unroll
    for (int k = 0; k < 8; ++k)
      if (k < lim) q2 = fmaf(t[k], g[k], q2);
  }

  float r1 = lin, r2 = q2 + 2.f * pvb;
#pragma unroll
  for (int off = 32; off; off >>= 1) { r1 += __shfl_down(r1, off); r2 += __shfl_down(r2, off); }
  int lane = tid & 63, wid = tid >> 6;
  if (lane == 0) { red[wid] = r1; red[2 + wid] = r2; }
  __syncthreads();
  if (tid == 0) {
    long o = ((long)b*729 + x) * 2;
    parts[o]     = red[0] + red[1];
    parts[o + 1] = red[2] + red[3];
  }
}

// ============ per-edge BN stats over (b,d,c) ============
__global__ __launch_bounds__(256)
void edge_fin(const float* __restrict__ parts, const float* __restrict__ b2st,
              float* __restrict__ ems)
{
  int e = blockIdx.x * 256 + threadIdx.x;
  if (e < 729) {
    float B1 = b2st[0], nb2 = b2st[1];
    float s = 196.f * B1, q = 196.f * nb2;
#pragma unroll
    for (int b = 0; b < 4; ++b) {
      s += parts[((long)b * 729 + e) * 2 + 0];
      q += parts[((long)b * 729 + e) * 2 + 1];
    }
    const float inv = 1.f / 100352.f;
    float m = s * inv;
    float var = q * inv - m * m;
    ems[e*2]   = m;
    ems[e*2+1] = rsqrtf(var + EPS_);
  }
}

// ============ f_e = BN( Pbar@VW/49 + b2 ), emits fp32 + planes ============
__global__ __launch_bounds__(256)
void fe_build(const float* __restrict__ Pbar, const float* __restrict__ VW,
              const float* __restrict__ b2, const float* __restrict__ ems,
              const float* __restrict__ gw, const float* __restrict__ gb,
              float* __restrict__ fe, short* __restrict__ feh, short* __restrict__ fel)
{
  __shared__ float Pb[27 * 49];
  const int i = blockIdx.x, b = blockIdx.y;
  const int tid = threadIdx.x;
  const float* pp = Pbar + ((long)b*27 + i) * 27 * 49;
  for (int idx = tid; idx < 1323; idx += 256) Pb[idx] = pp[idx];
  __syncthreads();
  const float* vp = VW + ((long)b*1323 + (long)i*49) * 512;
#pragma unroll 1
  for (int half = 0; half < 2; ++half) {
    int c = half * 256 + tid;
    float acc[27];
#pragma unroll
    for (int j = 0; j < 27; ++j) acc[j] = 0.f;
    for (int e = 0; e < 49; ++e) {
      float v = vp[(long)e*512 + c];
#pragma unroll
      for (int j = 0; j < 27; ++j) acc[j] = fmaf(Pb[j*49 + e], v, acc[j]);
    }
    float bz = b2[c];
#pragma unroll
    for (int j = 0; j < 27; ++j) {
      int ij = i*27 + j;
      float m = ems[ij*2], rs = ems[ij*2+1];
      float h = acc[j] * (1.f/49.f) + bz;
      float v = fmaf((h - m) * rs, gw[ij], gb[ij]);
      long o = ((long)b*729 + ij)*512 + c;
      fe[o] = v;
      short hh, ll; split2(v, hh, ll);
      feh[o] = hh; fel[o] = ll;
    }
  }
}

// ============ GNN kernels ============
__global__ __launch_bounds__(256)
void gnn_edge_bn(const float* __restrict__ vi, const float* __restrict__ vj,
                 const float* __restrict__ el, const float* __restrict__ wv,
                 const float* __restrict__ bv, float* fe,
                 short* __restrict__ feh, short* __restrict__ fel)
{
  int ij = blockIdx.x; int i = ij / 27, j = ij - i * 27;
  int t = threadIdx.x;
  __shared__ float red[18];
  float mv[8]; float s = 0.f, q = 0.f;
#pragma unroll
  for (int p = 0; p < 8; ++p) {
    int idx = p * 256 + t; int b = idx >> 9, c = idx & 511;
    float v = vi[((long)b*27+i)*512 + c] + vj[((long)b*27+j)*512 + c]
            + el[((long)b*729+ij)*512 + c];
    mv[p] = v; s += v; q = fmaf(v, v, q);
  }
  int lane = t & 63, wid = t >> 6;
#pragma unroll
  for (int off = 32; off; off >>= 1) { s += __shfl_down(s, off); q += __shfl_down(q, off); }
  if (lane == 0) { red[wid] = s; red[4 + wid] = q; }
  __syncthreads();
  if (t == 0) {
    float S = red[0]+red[1]+red[2]+red[3], Q = red[4]+red[5]+red[6]+red[7];
    float m = S * (1.f / 2048.f);
    red[16] = m;
    red[17] = rsqrtf(Q * (1.f / 2048.f) - m * m + EPS_);
  }
  __syncthreads();
  float m = red[16], rs = red[17];
  float w = wv[ij], bb = bv[ij];
#pragma unroll
  for (int p = 0; p < 8; ++p) {
    int idx = p * 256 + t; int b = idx >> 9, c = idx & 511;
    long o = ((long)b*729+ij)*512 + c;
    float nv = fe[o] + fmaxf(fmaf((mv[p] - m) * rs, w, bb), 0.f);
    fe[o] = nv;
    short hh, ll; split2(nv, hh, ll);
    feh[o] = hh; fel[o] = ll;
  }
}

__global__ __launch_bounds__(256)
void gnn_agg(const float* __restrict__ fe, const float* __restrict__ ui,
             const float* __restrict__ uj, float* __restrict__ agg)
{
  int i = blockIdx.x, b = blockIdx.y;
  int t = threadIdx.x;
#pragma unroll
  for (int cq = 0; cq < 2; ++cq) {
    int c = cq * 256 + t;
    float sg[27];
    float mx = -1e30f;
#pragma unroll
    for (int j = 0; j < 27; ++j) {
      float x = fe[((long)b*729 + i*27 + j)*512 + c];
      float sgm = 1.f / (1.f + __expf(-x));
      sg[j] = sgm; mx = fmaxf(mx, sgm);
    }
    float sum = 0.f;
#pragma unroll
    for (int j = 0; j < 27; ++j) { float e2 = __expf(sg[j] - mx); sg[j] = e2; sum += e2; }
    float acc = 0.f;
#pragma unroll
    for (int j = 0; j < 27; ++j)
      acc = fmaf(sg[j], uj[((long)b*27+j)*512 + c], acc);
    agg[((long)b*27+i)*512 + c] = ui[((long)b*27+i)*512 + c] + acc / (sum * 27.f);
  }
}

__global__ __launch_bounds__(256)
void gnn_node_bn(const float* __restrict__ agg, const float* __restrict__ wv,
                 const float* __restrict__ bv, float* fv,
                 short* __restrict__ fvh, short* __restrict__ fvl)
{
  int i = blockIdx.x;
  int t = threadIdx.x;
  __shared__ float red[18];
  float mv[8]; float s = 0.f, q = 0.f;
#pragma unroll
  for (int p = 0; p < 8; ++p) {
    int idx = p * 256 + t; int b = idx >> 9, c = idx & 511;
    float v = agg[((long)b*27+i)*512 + c];
    mv[p] = v; s += v; q = fmaf(v, v, q);
  }
  int lane = t & 63, wid = t >> 6;
#pragma unroll
  for (int off = 32; off; off >>= 1) { s += __shfl_down(s, off); q += __shfl_down(q, off); }
  if (lane == 0) { red[wid] = s; red[4 + wid] = q; }
  __syncthreads();
  if (t == 0) {
    float S = red[0]+red[1]+red[2]+red[3], Q = red[4]+red[5]+red[6]+red[7];
    float m = S * (1.f / 2048.f);
    red[16] = m;
    red[17] = rsqrtf(Q * (1.f / 2048.f) - m * m + EPS_);
  }
  __syncthreads();
  float m = red[16], rs = red[17];
  float w = wv[i], bb = bv[i];
#pragma unroll
  for (int p = 0; p < 8; ++p) {
    int idx = p * 256 + t; int b = idx >> 9, c = idx & 511;
    long o = ((long)b*27+i)*512 + c;
    float nv = fv[o] + fmaxf(fmaf((mv[p] - m) * rs, w, bb), 0.f);
    fv[o] = nv;
    short hh, ll; split2(nv, hh, ll);
    fvh[o] = hh; fvl[o] = ll;
  }
}

__constant__ int SUB_IDX_c[14] = {0,0,1,1,2,2,4,4,7,7,8,8,11,11};

__global__ __launch_bounds__(64)
void sc_k(const float* __restrict__ fv, const float* __restrict__ mainsc,
          const float* __restrict__ subsc, float* __restrict__ out)
{
  int o = blockIdx.x, b = blockIdx.y;
  int lane = threadIdx.x;
  int r; const float* ap;
  if (o < 27) { r = o; ap = mainsc + (long)o * 512; }
  else        { int k = o - 27; r = SUB_IDX_c[k]; ap = subsc + (long)k * 512; }
  const float* fp = fv + ((long)b*27 + r) * 512;
  float sff = 0.f, saa = 0.f, sfa = 0.f;
  for (int c = lane; c < 512; c += 64) {
    float f = fp[c];
    float a = fmaxf(ap[c], 0.f);
    sff = fmaf(f, f, sff); saa = fmaf(a, a, saa); sfa = fmaf(f, a, sfa);
  }
#pragma unroll
  for (int off = 32; off; off >>= 1) {
    sff += __shfl_down(sff, off); saa += __shfl_down(saa, off); sfa += __shfl_down(sfa, off);
  }
  if (lane == 0)
    out[b * 41 + o] = sfa / (fmaxf(sqrtf(sff), 1e-12f) * fmaxf(sqrtf(saa), 1e-12f));
}

} // namespace

extern "C" void kernel_launch(void* const* d_in, const int* in_sizes, int n_in,
                              void* d_out, int out_size, void* d_ws, size_t ws_size,
                              hipStream_t stream)
{
  (void)in_sizes; (void)n_in; (void)out_size; (void)ws_size;
  const float* x       = (const float*)d_in[0];
  const float* nb_W    = (const float*)d_in[1];
  const float* nb_b    = (const float*)d_in[2];
  const float* nb_bnw  = (const float*)d_in[3];
  const float* nb_bnb  = (const float*)d_in[4];
  const float* fam_qW  = (const float*)d_in[5];
  const float* fam_qb  = (const float*)d_in[6];
  const float* fam_kW  = (const float*)d_in[7];
  const float* fam_kb  = (const float*)d_in[8];
  const float* fam_vW  = (const float*)d_in[9];
  const float* fam_vb  = (const float*)d_in[10];
  const float* arm_qW  = (const float*)d_in[11];
  const float* arm_qb  = (const float*)d_in[12];
  const float* arm_kW  = (const float*)d_in[13];
  const float* arm_kb  = (const float*)d_in[14];
  const float* arm_vW  = (const float*)d_in[15];
  const float* arm_vb  = (const float*)d_in[16];
  const float* ep_W    = (const float*)d_in[17];
  const float* ep_b    = (const float*)d_in[18];
  const float* gem_bnw = (const float*)d_in[19];
  const float* gem_bnb = (const float*)d_in[20];
  const float* gnn_uW  = (const float*)d_in[21];
  const float* gnn_vW  = (const float*)d_in[22];
  const float* gnn_aW  = (const float*)d_in[23];
  const float* gnn_bW  = (const float*)d_in[24];
  const float* gnn_eW  = (const float*)d_in[25];
  const float* gnn_bnvw = (const float*)d_in[26];
  const float* gnn_bnvb = (const float*)d_in[27];
  const float* gnn_bnew = (const float*)d_in[28];
  const float* gnn_bneb = (const float*)d_in[29];
  const float* main_sc  = (const float*)d_in[30];
  const float* sub_sc   = (const float*)d_in[31];
  float* out = (float*)d_out;

  // ---- workspace carve: fp32 region then bf16 plane region (~92 MB total) ----
  char* wp = (char*)d_ws;
  auto carveF = [&](long n) -> float* { float* p = (float*)wp; wp += ((n + 15) & ~15L) * 4; return p; };
  auto carveS = [&](long n) -> short* { short* p = (short*)wp; wp += ((n + 15) & ~15L) * 2; return p; };

  float* Hnb   = carveF((long)27*196*512);   // dead after nb_apply; VW aliases
  float* S     = carveF((long)4*1323*1344);  // dead after arm_post; el aliases
  float* fe    = carveF((long)4*729*512);
  float* kf    = carveF(196*256);
  float* vf    = carveF(196*512);
  float* qfam  = carveF((long)5292*256);
  float* nbm   = carveF(27*512);
  float* nbr   = carveF(27*512);
  float* Mpre  = carveF(512*512);
  float* bias2 = carveF(512);
  float* b2st  = carveF(16);
  float* parts = carveF(4*729*2);
  float* ems   = carveF(1460);
  float* G     = carveF((long)108*2401);
  float* V1    = carveF(108*49);
  float* Vb2   = carveF(108*49);
  float* Pbar  = carveF((long)4*27*27*49);
  float* fv    = carveF(108*512);
  float* vi    = carveF(108*512);
  float* vj    = carveF(108*512);
  float* uj    = carveF(108*512);
  float* ui    = carveF(108*512);
  float* agg   = carveF(108*512);
  float* VW = Hnb;   // alias (Hnb dead after nb_apply)
  float* el = S;     // alias (S dead after arm_post)

  short* xh    = carveS(100352);
  short* xl    = carveS(100352);
  short* wph   = carveS((long)26*131072);    // weight hi planes (26 chunks)
  short* wpl   = carveS((long)26*131072);
  short* Mpreh = carveS(262144);
  short* Mprel = carveS(262144);
  short* fuh   = carveS((long)5292*512);     // dead after FAM-q GEMM; feath aliases
  short* ful   = carveS((long)5292*512);
  short* Qah   = carveS((long)5292*256);     // Qah+Qal contiguous: feh alias
  short* Qal   = carveS((long)5292*256);
  short* Kah   = carveS((long)4*1344*256);   // Kah+Kal contiguous: fel alias
  short* Kal   = carveS((long)4*1344*256);
  short* fvh   = carveS(108*512);
  short* fvl   = carveS(108*512);
  short* feath = fuh;   // alias: fu last read step 6; feat written step 7
  short* featl = ful;
  short* feh   = Qah;   // alias: Qa/Ka last read step 13; fe planes written step 17
  short* fel   = Kah;   // (feh spans Qah+Qal region, fel spans Kah+Kal region)

  // weight plane offsets (chunks of 131072 shorts)
  short* famqWh = wph + 0L*131072;        short* famqWl = wpl + 0L*131072;
  short* famkWh = wph + 1L*131072;        short* famkWl = wpl + 1L*131072;
  short* armqWh = wph + 2L*131072;        short* armqWl = wpl + 2L*131072;
  short* armkWh = wph + 3L*131072;        short* armkWl = wpl + 3L*131072;
  short* famvWh = wph + 4L*131072;        short* famvWl = wpl + 4L*131072;
  short* uWh    = wph + 6L*131072;        short* uWl    = wpl + 6L*131072;
  short* vWh    = wph + 10L*131072;       short* vWl    = wpl + 10L*131072;
  short* aWh    = wph + 14L*131072;       short* aWl    = wpl + 14L*131072;
  short* bWh    = wph + 18L*131072;       short* bWl    = wpl + 18L*131072;
  short* eWh    = wph + 22L*131072;       short* eWl    = wpl + 22L*131072;

  // ---- conversions ----
  cvt1_k<<<dim3(98), 256, 0, stream>>>(x, xh, xl, 25088);
  P10 p10;
  p10.s[0] = fam_qW; p10.s[1] = fam_kW; p10.s[2] = arm_qW; p10.s[3] = arm_kW;
  p10.s[4] = fam_vW; p10.s[5] = gnn_uW; p10.s[6] = gnn_vW; p10.s[7] = gnn_aW;
  p10.s[8] = gnn_bW; p10.s[9] = gnn_eW;
  cvt_w_k<<<dim3(64, 26), 256, 0, stream>>>(p10, wph, wpl);

  // 1) node-block GEMMs (W converted on the fly from fp32 nb_W)
  gemm_bf3_k<1><<<dim3(8,4,27), 256, 0, stream>>>(xh, xl, nullptr, nullptr, nb_W,
      nb_b, Hnb, nullptr, nullptr, 196, 512, 512, 0, 262144, 512, 100352);
  // 2-3) BN stats + apply -> fu planes, fv (+planes)
  nb_stats<<<dim3(27,2), 256, 0, stream>>>(Hnb, nbm, nbr);
  nb_apply<<<dim3(27,4), 256, 0, stream>>>(Hnb, nbm, nbr, nb_bnw, nb_bnb,
      fuh, ful, fv, fvh, fvl);
  // 4-5) FAM k, v
  gemm_bf3_k<0><<<dim3(4,4), 256, 0, stream>>>(xh, xl, famkWh, famkWl, nullptr,
      fam_kb, kf, nullptr, nullptr, 196, 256, 512, 0,0,0,0);
  gemm_bf3_k<0><<<dim3(8,4), 256, 0, stream>>>(xh, xl, famvWh, famvWl, nullptr,
      fam_vb, vf, nullptr, nullptr, 196, 512, 512, 0,0,0,0);
  // 6) FAM q (last read of fu planes)
  gemm_bf3_k<0><<<dim3(4,83), 256, 0, stream>>>(fuh, ful, famqWh, famqWl, nullptr,
      fam_qb, qfam, nullptr, nullptr, 5292, 256, 512, 0,0,0,0);
  // 7) FAM cross-attention -> feat planes (overlays fu planes; batch-major)
  attn_fam<<<dim3(27,4), 512, 0, stream>>>(qfam, kf, vf, feath, featl);
  // 8) ARM Q (planes only)
  gemm_bf3_k<0><<<dim3(4,83), 256, 0, stream>>>(feath, featl, armqWh, armqWl, nullptr,
      arm_qb, nullptr, Qah, Qal, 5292, 256, 512, 0,0,0,0);
  // 9) ARM K (per-batch, row-padded to 1344; planes only)
  gemm_bf3_k<0><<<dim3(4,21,4), 256, 0, stream>>>(feath, featl, armkWh, armkWl, nullptr,
      arm_kb, nullptr, Kah, Kal, 1323, 256, 512, (long)1323*512, 0, 0, (long)1344*256);
  // 10) Mpre = ep_W @ arm_vW (fp32) + convert
  gemm_nn_k<<<dim3(8,8), 256, 0, stream>>>(ep_W, arm_vW, Mpre, 512, 512, 512);
  cvt1_k<<<dim3(256), 256, 0, stream>>>(Mpre, Mpreh, Mprel, 65536);
  // 11) bias2 + scalar sums
  bias2red_k<<<dim3(1), 512, 0, stream>>>(ep_W, arm_vb, ep_b, bias2, b2st);
  // 12) VW = feat @ Mpre^T (fp32 out, overlays Hnb)
  gemm_bf3_k<0><<<dim3(8,83), 256, 0, stream>>>(feath, featl, Mpreh, Mprel, nullptr,
      nullptr, VW, nullptr, nullptr, 5292, 512, 512, 0,0,0,0);
  // 13) S_all[b] = Qa_b @ Ka_b^T (last read of Qa/Ka planes)
  gemm_bf3_k<0><<<dim3(21,21,4), 256, 0, stream>>>(Qah, Qal, Kah, Kal, nullptr,
      nullptr, S, nullptr, nullptr, 1323, 1344, 256,
      (long)1323*256, (long)1344*256, 0, (long)1323*1344);
  // 14) G = VW VW^T per (b,i) + row sums
  gmat_k<<<dim3(27,4), 256, 0, stream>>>(VW, bias2, G, V1, Vb2);
  // 15) segmented softmax + Pbar + BN partials (last read of S)
  arm_post<<<dim3(729,4), 128, 0, stream>>>(S, G, V1, Vb2, Pbar, parts);
  // 16) per-edge BN stats
  edge_fin<<<dim3(3), 256, 0, stream>>>(parts, b2st, ems);
  // 17) f_e = BN(Pbar@VW/49 + b2) -> fp32 + planes (planes overlay Qa/Ka)
  fe_build<<<dim3(27,4), 256, 0, stream>>>(Pbar, VW, bias2, ems, gem_bnw, gem_bnb,
      fe, feh, fel);
  // 18) 2 GatedGNN layers
  for (int l = 0; l < 2; ++l) {
    long wo = (long)l * 262144;
    G4 g4;
    g4.wh[0] = aWh + wo; g4.wl[0] = aWl + wo; g4.c[0] = vi;
    g4.wh[1] = bWh + wo; g4.wl[1] = bWl + wo; g4.c[1] = vj;
    g4.wh[2] = vWh + wo; g4.wl[2] = vWl + wo; g4.c[2] = uj;
    g4.wh[3] = uWh + wo; g4.wl[3] = uWl + wo; g4.c[3] = ui;
    gemm4_bf3_k<<<dim3(8,2,4), 256, 0, stream>>>(fvh, fvl, g4, 108, 512, 512);
    gemm_bf3_k<0><<<dim3(8,46), 256, 0, stream>>>(feh, fel, eWh + wo, eWl + wo, nullptr,
        nullptr, el, nullptr, nullptr, 2916, 512, 512, 0,0,0,0);
    gnn_edge_bn<<<dim3(729), 256, 0, stream>>>(vi, vj, el,
        gnn_bnew + (long)l*729, gnn_bneb + (long)l*729, fe, feh, fel);
    gnn_agg<<<dim3(27,4), 256, 0, stream>>>(fe, ui, uj, agg);
    gnn_node_bn<<<dim3(27), 256, 0, stream>>>(agg,
        gnn_bnvw + (long)l*27, gnn_bnvb + (long)l*27, fv, fvh, fvl);
  }
  // 19) cosine-similarity outputs [4,41]
  sc_k<<<dim3(41,4), 64, 0, stream>>>(fv, main_sc, sub_sc, out);
}

// Round 7
// 655.298 us; speedup vs baseline: 1.8144x; 1.0461x over previous
//
#include <hip/hip_runtime.h>
#include <hip/hip_bf16.h>
#include <math.h>

// MEFL forward. B=4, D=49, C=512, N=27, C2=256.
// R7: arm_post strip map transposed (e fast -> broadcast float4 reads, conflict-free
// scalar reads) + unroll 7 to cap VGPR. Everything else identical to R6/R5
// (bf16x3 MFMA GEMMs, 686 us baseline).

namespace {

constexpr float SCALE_ = 0.0625f;   // 256^-0.5
constexpr float EPS_   = 1e-5f;

typedef __attribute__((ext_vector_type(8))) short bf16x8;
typedef __attribute__((ext_vector_type(4))) short s16x4;
typedef __attribute__((ext_vector_type(4))) float f32x4;

__device__ __forceinline__ short f2bf(float f) {
  unsigned u = __float_as_uint(f);
  u += 0x7fffu + ((u >> 16) & 1u);
  return (short)(u >> 16);
}
__device__ __forceinline__ float bf2f(short h) {
  return __uint_as_float(((unsigned)(unsigned short)h) << 16);
}
__device__ __forceinline__ void split2(float f, short& h, short& l) {
  h = f2bf(f);
  l = f2bf(f - bf2f(h));
}

// ============ bf16x3 MFMA GEMM: C[M,N] = A[M,K] @ W[N,K]^T + bias ============
template<int CONVB>
__device__ __forceinline__
void gemm_bf3_core(const short* __restrict__ Ah, const short* __restrict__ Al,
                   const short* __restrict__ Wh, const short* __restrict__ Wl,
                   const float* __restrict__ Wf,
                   const float* __restrict__ bias, float* __restrict__ C,
                   short* __restrict__ Ch, short* __restrict__ Cl,
                   int M, int N, int K)
{
  __shared__ short sA[2][64][40];   // [hi/lo][row][k], 80B row stride (16B aligned)
  __shared__ short sB[2][64][40];
  const int tid  = threadIdx.x;
  const int n0   = blockIdx.x * 64, m0 = blockIdx.y * 64;
  const int wave = tid >> 6, lane = tid & 63;
  const int wr = (wave >> 1) * 32, wc = (wave & 1) * 32;
  const int lr = lane & 15, lk = (lane >> 4) * 8;
  const int sr = tid >> 2, sk = (tid & 3) * 8;
  const int arow = m0 + sr;

  f32x4 acc[2][2] = {};

  for (int k0 = 0; k0 < K; k0 += 32) {
    bf16x8 ah = {}, al = {};
    if (arow < M) {
      ah = *(const bf16x8*)(Ah + (long)arow * K + k0 + sk);
      al = *(const bf16x8*)(Al + (long)arow * K + k0 + sk);
    }
    bf16x8 bh, bl;
    if (CONVB) {
      f32x4 w0 = *(const f32x4*)(Wf + (long)(n0 + sr) * K + k0 + sk);
      f32x4 w1 = *(const f32x4*)(Wf + (long)(n0 + sr) * K + k0 + sk + 4);
#pragma unroll
      for (int j = 0; j < 4; ++j) {
        short h, l;
        split2(w0[j], h, l); bh[j] = h;     bl[j] = l;
        split2(w1[j], h, l); bh[4 + j] = h; bl[4 + j] = l;
      }
    } else {
      bh = *(const bf16x8*)(Wh + (long)(n0 + sr) * K + k0 + sk);
      bl = *(const bf16x8*)(Wl + (long)(n0 + sr) * K + k0 + sk);
    }
    __syncthreads();
    *(bf16x8*)&sA[0][sr][sk] = ah;
    *(bf16x8*)&sA[1][sr][sk] = al;
    *(bf16x8*)&sB[0][sr][sk] = bh;
    *(bf16x8*)&sB[1][sr][sk] = bl;
    __syncthreads();

    bf16x8 a0h = *(const bf16x8*)&sA[0][wr + lr][lk];
    bf16x8 a1h = *(const bf16x8*)&sA[0][wr + 16 + lr][lk];
    bf16x8 a0l = *(const bf16x8*)&sA[1][wr + lr][lk];
    bf16x8 a1l = *(const bf16x8*)&sA[1][wr + 16 + lr][lk];
    bf16x8 b0h = *(const bf16x8*)&sB[0][wc + lr][lk];
    bf16x8 b1h = *(const bf16x8*)&sB[0][wc + 16 + lr][lk];
    bf16x8 b0l = *(const bf16x8*)&sB[1][wc + lr][lk];
    bf16x8 b1l = *(const bf16x8*)&sB[1][wc + 16 + lr][lk];

    acc[0][0] = __builtin_amdgcn_mfma_f32_16x16x32_bf16(a0h, b0h, acc[0][0], 0, 0, 0);
    acc[0][1] = __builtin_amdgcn_mfma_f32_16x16x32_bf16(a0h, b1h, acc[0][1], 0, 0, 0);
    acc[1][0] = __builtin_amdgcn_mfma_f32_16x16x32_bf16(a1h, b0h, acc[1][0], 0, 0, 0);
    acc[1][1] = __builtin_amdgcn_mfma_f32_16x16x32_bf16(a1h, b1h, acc[1][1], 0, 0, 0);
    acc[0][0] = __builtin_amdgcn_mfma_f32_16x16x32_bf16(a0h, b0l, acc[0][0], 0, 0, 0);
    acc[0][1] = __builtin_amdgcn_mfma_f32_16x16x32_bf16(a0h, b1l, acc[0][1], 0, 0, 0);
    acc[1][0] = __builtin_amdgcn_mfma_f32_16x16x32_bf16(a1h, b0l, acc[1][0], 0, 0, 0);
    acc[1][1] = __builtin_amdgcn_mfma_f32_16x16x32_bf16(a1h, b1l, acc[1][1], 0, 0, 0);
    acc[0][0] = __builtin_amdgcn_mfma_f32_16x16x32_bf16(a0l, b0h, acc[0][0], 0, 0, 0);
    acc[0][1] = __builtin_amdgcn_mfma_f32_16x16x32_bf16(a0l, b1h, acc[0][1], 0, 0, 0);
    acc[1][0] = __builtin_amdgcn_mfma_f32_16x16x32_bf16(a1l, b0h, acc[1][0], 0, 0, 0);
    acc[1][1] = __builtin_amdgcn_mfma_f32_16x16x32_bf16(a1l, b1h, acc[1][1], 0, 0, 0);
  }

  const int rbase = m0 + wr + (lane >> 4) * 4;
  const int cb = n0 + wc + lr;
#pragma unroll
  for (int fj = 0; fj < 2; ++fj) {
    int col = cb + fj * 16;
    float bz = bias ? bias[col] : 0.f;
#pragma unroll
    for (int fi = 0; fi < 2; ++fi) {
#pragma unroll
      for (int r = 0; r < 4; ++r) {
        int row = rbase + fi * 16 + r;
        if (row < M) {
          float v = acc[fi][fj][r] + bz;
          long o = (long)row * N + col;
          if (C) C[o] = v;
          if (Ch) { short h, l; split2(v, h, l); Ch[o] = h; Cl[o] = l; }
        }
      }
    }
  }
}

template<int CONVB>
__global__ __launch_bounds__(256)
void gemm_bf3_k(const short* Ah, const short* Al, const short* Wh, const short* Wl,
                const float* Wf, const float* bias, float* C, short* Ch, short* Cl,
                int M, int N, int K, long aBS, long wBS, long bBS, long cBS)
{
  long z = blockIdx.z;
  gemm_bf3_core<CONVB>(Ah + z * aBS, Al + z * aBS,
                       Wh ? Wh + z * wBS : nullptr, Wl ? Wl + z * wBS : nullptr,
                       Wf ? Wf + z * wBS : nullptr,
                       bias ? bias + z * bBS : nullptr,
                       C ? C + z * cBS : nullptr,
                       Ch ? Ch + z * cBS : nullptr, Cl ? Cl + z * cBS : nullptr,
                       M, N, K);
}

struct G4 { const short* wh[4]; const short* wl[4]; float* c[4]; };

__global__ __launch_bounds__(256)
void gemm4_bf3_k(const short* Ah, const short* Al, G4 g, int M, int N, int K)
{
  int z = blockIdx.z;
  gemm_bf3_core<0>(Ah, Al, g.wh[z], g.wl[z], nullptr, nullptr, g.c[z],
                   nullptr, nullptr, M, N, K);
}

// ============ conversion kernels ============
__global__ __launch_bounds__(256)
void cvt1_k(const float* __restrict__ s, short* __restrict__ dh,
            short* __restrict__ dl, int n4)
{
  long i = (long)blockIdx.x * 256 + threadIdx.x;
  if (i >= n4) return;
  f32x4 v = *(const f32x4*)(s + i * 4);
  s16x4 h, l;
#pragma unroll
  for (int j = 0; j < 4; ++j) { short hh, ll; split2(v[j], hh, ll); h[j] = hh; l[j] = ll; }
  *(s16x4*)(dh + i * 4) = h;
  *(s16x4*)(dl + i * 4) = l;
}

struct P10 { const float* s[10]; };

// 26 chunks of 131072 elems: famq,famk,armq,armk @0-3; famv @4-5; gnn u,v,a,b,e @6..25
__global__ __launch_bounds__(256)
void cvt_w_k(P10 p, short* __restrict__ dh, short* __restrict__ dl)
{
  static const int tens[26] = {0,1,2,3,4,4,5,5,5,5,6,6,6,6,7,7,7,7,8,8,8,8,9,9,9,9};
  static const int coff[26] = {0,0,0,0,0,1,0,1,2,3,0,1,2,3,0,1,2,3,0,1,2,3,0,1,2,3};
  int c = blockIdx.y;
  const float* src = p.s[tens[c]] + (long)coff[c] * 131072;
  long dbase = (long)c * 131072;
  long i = ((long)blockIdx.x * 256 + threadIdx.x) * 8;
  f32x4 v0 = *(const f32x4*)(src + i);
  f32x4 v1 = *(const f32x4*)(src + i + 4);
  s16x4 h0, l0, h1, l1;
#pragma unroll
  for (int j = 0; j < 4; ++j) {
    short hh, ll;
    split2(v0[j], hh, ll); h0[j] = hh; l0[j] = ll;
    split2(v1[j], hh, ll); h1[j] = hh; l1[j] = ll;
  }
  *(s16x4*)(dh + dbase + i) = h0;     *(s16x4*)(dh + dbase + i + 4) = h1;
  *(s16x4*)(dl + dbase + i) = l0;     *(s16x4*)(dl + dbase + i + 4) = l1;
}

// ============ small NN GEMM (W is [K,N]) — only for Mpre = ep_W @ arm_vW ============
__global__ __launch_bounds__(256)
void gemm_nn_k(const float* __restrict__ A, const float* __restrict__ W,
               float* __restrict__ C, int M, int N, int K)
{
  __shared__ float As[32][68];
  __shared__ float Ws[32][68];
  const int tid = threadIdx.x;
  const int n0 = blockIdx.x * 64, m0 = blockIdx.y * 64;
  const int tx = tid & 15, ty = tid >> 4;
  float acc[4][4] = {};
  for (int k0 = 0; k0 < K; k0 += 32) {
#pragma unroll
    for (int p = 0; p < 2; ++p) {
      int idx = tid + p * 256;
      int row = idx >> 3, kq = idx & 7;
      float4 v = make_float4(0.f, 0.f, 0.f, 0.f);
      if (m0 + row < M)
        v = *(const float4*)(A + (long)(m0 + row) * K + k0 + kq * 4);
      As[kq*4+0][row] = v.x; As[kq*4+1][row] = v.y;
      As[kq*4+2][row] = v.z; As[kq*4+3][row] = v.w;
    }
#pragma unroll
    for (int p = 0; p < 2; ++p) {
      int idx = tid + p * 256;
      int row = idx >> 4, nq = idx & 15;
      float4 v = *(const float4*)(W + (long)(k0 + row) * N + n0 + nq * 4);
      *(float4*)&Ws[row][nq*4] = v;
    }
    __syncthreads();
#pragma unroll
    for (int k = 0; k < 32; ++k) {
      float4 a4 = *(const float4*)&As[k][ty*4];
      float4 b4 = *(const float4*)&Ws[k][tx*4];
      float av[4] = {a4.x, a4.y, a4.z, a4.w};
      float bv[4] = {b4.x, b4.y, b4.z, b4.w};
#pragma unroll
      for (int i2 = 0; i2 < 4; ++i2)
#pragma unroll
        for (int j2 = 0; j2 < 4; ++j2)
          acc[i2][j2] = fmaf(av[i2], bv[j2], acc[i2][j2]);
    }
    __syncthreads();
  }
#pragma unroll
  for (int i2 = 0; i2 < 4; ++i2) {
    int m = m0 + ty*4 + i2;
    if (m < M)
      *(float4*)(C + (long)m * N + n0 + tx*4) =
        make_float4(acc[i2][0], acc[i2][1], acc[i2][2], acc[i2][3]);
  }
}

// ============ node-block BN ============
__global__ __launch_bounds__(256)
void nb_stats(const float* __restrict__ H, float* __restrict__ mean, float* __restrict__ rs)
{
  int n = blockIdx.x;
  int c = blockIdx.y * 256 + threadIdx.x;
  const float* p = H + (long)n * 196 * 512 + c;
  float s = 0.f, q = 0.f;
  for (int r = 0; r < 196; ++r) { float v = p[(long)r * 512]; s += v; q = fmaf(v, v, q); }
  float m = s * (1.f / 196.f);
  float var = q * (1.f / 196.f) - m * m;
  mean[n * 512 + c] = m;
  rs[n * 512 + c] = rsqrtf(var + EPS_);
}

__global__ __launch_bounds__(256)
void nb_apply(const float* __restrict__ H, const float* __restrict__ mean,
              const float* __restrict__ rs, const float* __restrict__ bw,
              const float* __restrict__ bb,
              short* __restrict__ fuh, short* __restrict__ ful,
              float* __restrict__ fv, short* __restrict__ fvh, short* __restrict__ fvl)
{
  int n = blockIdx.x, b = blockIdx.y;
  int t = threadIdx.x;
#pragma unroll
  for (int cq = 0; cq < 2; ++cq) {
    int c = cq * 256 + t;
    float m = mean[n*512+c], r = rs[n*512+c];
    float w = bw[n*512+c], bias = bb[n*512+c];
    const float* hp = H + ((long)(n*4+b)*49) * 512 + c;
    long fo0 = ((long)(n*4+b)*49) * 512 + c;
    float s = 0.f;
    for (int d = 0; d < 49; ++d) {
      float v = hp[(long)d*512];
      float o = fmaxf(fmaf((v - m) * r, w, bias), 0.f);
      short hh, ll; split2(o, hh, ll);
      fuh[fo0 + (long)d*512] = hh;
      ful[fo0 + (long)d*512] = ll;
      s += o;
    }
    float fvv = s * (1.f / 49.f);
    long fo = ((long)b*27+n)*512 + c;
    fv[fo] = fvv;
    short hh, ll; split2(fvv, hh, ll);
    fvh[fo] = hh; fvl[fo] = ll;
  }
}

// ============ FAM cross-attention (emits feat hi/lo planes, batch-major) ============
__global__ __launch_bounds__(512)
void attn_fam(const float* __restrict__ Qg, const float* __restrict__ Kg,
              const float* __restrict__ Vg, short* __restrict__ feath,
              short* __restrict__ featl)
{
  __shared__ float Qs[52][68];
  __shared__ float Ks[52][68];
  __shared__ float Ss[49][56];
  __shared__ float Vs[49][68];

  const int tid = threadIdx.x;
  const int bx = blockIdx.x, b = blockIdx.y;   // bx = node n
  const int qblk = bx*4 + b;                    // qfam is n-major
  const long obase = ((long)b*1323 + (long)bx*49) * 512;  // feat batch-major
  const float* qp = Qg + (long)qblk * (49 * 256);
  const float* kp = Kg + (long)b * (49 * 256);
  const float* vp = Vg + (long)b * (49 * 512);

  const int tx = tid & 15;
  const int ty4 = tid >> 4;

  float sacc[2][4] = {};
  const int d0 = ty4 * 2;
  const int e0 = tx * 4;
  const int eh0 = (e0+0)&7, eh1 = (e0+1)&7, eh2 = (e0+2)&7, eh3 = (e0+3)&7;
  const int er0 = (e0+0) > 51 ? 51 : (e0+0);
  const int er1 = (e0+1) > 51 ? 51 : (e0+1);
  const int er2 = (e0+2) > 51 ? 51 : (e0+2);
  const int er3 = (e0+3) > 51 ? 51 : (e0+3);
  for (int kc = 0; kc < 256; kc += 64) {
    for (int idx = tid; idx < 49 * 16; idx += 512) {
      int row = idx >> 4, kq = idx & 15;
      *(float4*)&Qs[row][kq*4] = *(const float4*)(qp + (long)row*256 + kc + kq*4);
      *(float4*)&Ks[row][(kq ^ (row & 7)) * 4] = *(const float4*)(kp + (long)row*256 + kc + kq*4);
    }
    __syncthreads();
    if (d0 < 49) {
      const float* q0 = &Qs[d0][0];
      const float* q1 = &Qs[d0 + 1][0];
      const float* k0 = &Ks[er0][0];
      const float* k1 = &Ks[er1][0];
      const float* k2 = &Ks[er2][0];
      const float* k3 = &Ks[er3][0];
#pragma unroll 4
      for (int kq = 0; kq < 16; ++kq) {
        float4 a0 = *(const float4*)(q0 + kq*4);
        float4 a1 = *(const float4*)(q1 + kq*4);
        float4 b0 = *(const float4*)(k0 + ((kq ^ eh0) * 4));
        float4 b1 = *(const float4*)(k1 + ((kq ^ eh1) * 4));
        float4 b2 = *(const float4*)(k2 + ((kq ^ eh2) * 4));
        float4 b3 = *(const float4*)(k3 + ((kq ^ eh3) * 4));
        float av0[4] = {a0.x, a0.y, a0.z, a0.w};
        float av1[4] = {a1.x, a1.y, a1.z, a1.w};
        float bv[4][4] = {{b0.x,b0.y,b0.z,b0.w},{b1.x,b1.y,b1.z,b1.w},
                          {b2.x,b2.y,b2.z,b2.w},{b3.x,b3.y,b3.z,b3.w}};
#pragma unroll
        for (int j2 = 0; j2 < 4; ++j2) {
#pragma unroll
          for (int qq = 0; qq < 4; ++qq) {
            sacc[0][j2] = fmaf(av0[qq], bv[j2][qq], sacc[0][j2]);
            sacc[1][j2] = fmaf(av1[qq], bv[j2][qq], sacc[1][j2]);
          }
        }
      }
    }
    __syncthreads();
  }
  if (d0 < 49) {
#pragma unroll
    for (int i2 = 0; i2 < 2; ++i2) {
      int d = d0 + i2;
      if (d < 49) {
#pragma unroll
        for (int j2 = 0; j2 < 4; ++j2) {
          int e = e0 + j2;
          if (e < 49) Ss[d][e] = sacc[i2][j2] * SCALE_;
        }
      }
    }
  }
  __syncthreads();

  if (tid < 49) {
    float mx = -1e30f;
    for (int e = 0; e < 49; ++e) mx = fmaxf(mx, Ss[tid][e]);
    float sum = 0.f;
    for (int e = 0; e < 49; ++e) { float ex = __expf(Ss[tid][e] - mx); Ss[tid][e] = ex; sum += ex; }
    float inv = 1.f / sum;
    for (int e = 0; e < 49; ++e) Ss[tid][e] *= inv;
  }
  __syncthreads();

  const int td = ty4;
  const bool has2 = (td + 32) < 49;
  for (int cc = 0; cc < 512; cc += 64) {
    for (int idx = tid; idx < 49 * 16; idx += 512) {
      int row = idx >> 4, cq = idx & 15;
      *(float4*)&Vs[row][cq*4] = *(const float4*)(vp + (long)row*512 + cc + cq*4);
    }
    __syncthreads();
    float pa[2][4] = {};
#pragma unroll 7
    for (int e = 0; e < 49; ++e) {
      float4 v4 = *(const float4*)&Vs[e][tx*4];
      float p0 = Ss[td][e];
      float p1 = has2 ? Ss[td + 32][e] : 0.f;
      pa[0][0] = fmaf(p0, v4.x, pa[0][0]); pa[0][1] = fmaf(p0, v4.y, pa[0][1]);
      pa[0][2] = fmaf(p0, v4.z, pa[0][2]); pa[0][3] = fmaf(p0, v4.w, pa[0][3]);
      pa[1][0] = fmaf(p1, v4.x, pa[1][0]); pa[1][1] = fmaf(p1, v4.y, pa[1][1]);
      pa[1][2] = fmaf(p1, v4.z, pa[1][2]); pa[1][3] = fmaf(p1, v4.w, pa[1][3]);
    }
    __syncthreads();
    s16x4 hh, ll;
#pragma unroll
    for (int j = 0; j < 4; ++j) { short h, l; split2(pa[0][j], h, l); hh[j] = h; ll[j] = l; }
    *(s16x4*)(feath + obase + (long)td*512 + cc + tx*4) = hh;
    *(s16x4*)(featl + obase + (long)td*512 + cc + tx*4) = ll;
    if (has2) {
#pragma unroll
      for (int j = 0; j < 4; ++j) { short h, l; split2(pa[1][j], h, l); hh[j] = h; ll[j] = l; }
      *(s16x4*)(feath + obase + (long)(td+32)*512 + cc + tx*4) = hh;
      *(s16x4*)(featl + obase + (long)(td+32)*512 + cc + tx*4) = ll;
    }
  }
}

// ============ bias2 = ep_W @ arm_vb + ep_b, plus B1 = sum(b2), nb2 = sum(b2^2) ============
__global__ __launch_bounds__(512)
void bias2red_k(const float* __restrict__ epW, const float* __restrict__ vb,
                const float* __restrict__ epb, float* __restrict__ bias2,
                float* __restrict__ b2st)
{
  int c = threadIdx.x;
  float s = epb[c];
  const float* r = epW + (long)c * 512;
  for (int k = 0; k < 512; ++k) s = fmaf(r[k], vb[k], s);
  bias2[c] = s;
  __shared__ float red[16];
  float s1 = s, s2 = s * s;
#pragma unroll
  for (int off = 32; off; off >>= 1) { s1 += __shfl_down(s1, off); s2 += __shfl_down(s2, off); }
  int lane = c & 63, wid = c >> 6;
  if (lane == 0) { red[wid] = s1; red[8 + wid] = s2; }
  __syncthreads();
  if (c == 0) {
    float a = 0.f, qq = 0.f;
#pragma unroll
    for (int w = 0; w < 8; ++w) { a += red[w]; qq += red[8 + w]; }
    b2st[0] = a; b2st[1] = qq;
  }
}

// ============ G = VW VW^T per (b,i), plus row sums ============
__constant__ unsigned char TI_c[28] = {0,1,1,2,2,2,3,3,3,3,4,4,4,4,4,5,5,5,5,5,5,6,6,6,6,6,6,6};
__constant__ unsigned char TJ_c[28] = {0,0,1,0,1,2,0,1,2,3,0,1,2,3,4,0,1,2,3,4,5,0,1,2,3,4,5,6};

__global__ __launch_bounds__(256)
void gmat_k(const float* __restrict__ VW, const float* __restrict__ b2,
            float* __restrict__ G, float* __restrict__ V1, float* __restrict__ Vb2)
{
  __shared__ float Vs[49][260];
  const int i = blockIdx.x, b = blockIdx.y;
  const int tid = threadIdx.x;
  const int wave = tid >> 6, lane = tid & 63;
  const int di = lane >> 3, ej = lane & 7;
  const float* vp = VW + ((long)b*1323 + (long)i*49) * 512;
  float gacc[7];
#pragma unroll
  for (int t = 0; t < 7; ++t) gacc[t] = 0.f;
  float s1 = 0.f, s2 = 0.f;

  for (int half = 0; half < 2; ++half) {
    __syncthreads();
    for (int idx = tid; idx < 49 * 64; idx += 256) {
      int r = idx >> 6, q = idx & 63;
      *(float4*)&Vs[r][q*4] = *(const float4*)(vp + (long)r*512 + half*256 + q*4);
    }
    __syncthreads();
    int tt = 0;
    for (int t = wave; t < 28; t += 4, ++tt) {
      int d = TI_c[t]*8 + di, e = TJ_c[t]*8 + ej;
      int dc = d > 48 ? 48 : d, ec = e > 48 ? 48 : e;
      float g = gacc[tt];
      for (int q = 0; q < 64; ++q) {
        float4 a = *(const float4*)&Vs[dc][q*4];
        float4 bq = *(const float4*)&Vs[ec][q*4];
        g = fmaf(a.x, bq.x, fmaf(a.y, bq.y, fmaf(a.z, bq.z, fmaf(a.w, bq.w, g))));
      }
      gacc[tt] = g;
    }
    if (tid < 49) {
      for (int c = 0; c < 256; ++c) {
        float v = Vs[tid][c];
        s1 += v; s2 = fmaf(v, b2[half*256 + c], s2);
      }
    }
  }
  long gbase = ((long)b*27 + i) * 2401;
  int tt = 0;
  for (int t = wave; t < 28; t += 4, ++tt) {
    int ti = TI_c[t], tj = TJ_c[t];
    int d = ti*8 + di, e = tj*8 + ej;
    if (d < 49 && e < 49) {
      G[gbase + d*49 + e] = gacc[tt];
      if (ti != tj) G[gbase + e*49 + d] = gacc[tt];
    }
  }
  if (tid < 49) {
    long o = ((long)b*27 + i) * 49 + tid;
    V1[o] = s1; Vb2[o] = s2;
  }
}

// ============ per-edge: segmented softmax, Pbar, BN partial sums ============
// R7: strip map transposed — s = k*49 + e with e FAST. Lanes within a 49-group
// share k8 -> float4 TP reads are wave-uniform broadcasts; scalar TP reads have
// lane-consecutive e (conflict-free). unroll 7 caps VGPR.
__global__ __launch_bounds__(128)
void arm_post(const float* __restrict__ S, const float* __restrict__ G,
              const float* __restrict__ V1, const float* __restrict__ Vb2,
              float* __restrict__ Pbar, float* __restrict__ parts)
{
  __shared__ float TP[49 * 56];
  __shared__ float red[8];
  const int tid = threadIdx.x;
  const int x = blockIdx.x, b = blockIdx.y;
  const int i = x / 27, j = x - i * 27;
  const float* Sp = S + (long)b*1323*1344 + (long)j*49*1344 + (long)i*49;
  for (int idx = tid; idx < 2401; idx += 128) {
    unsigned d = ((unsigned)idx * 1338u) >> 16;
    unsigned e = (unsigned)idx - d * 49u;
    TP[d*56 + e] = Sp[(long)d*1344 + e];
  }
  // zero pad columns 49..55 (strips read float4 past col 48; zeros contribute 0)
  for (int idx = tid; idx < 343; idx += 128) {
    int d = idx / 7, e = 49 + idx - d * 7;
    TP[d*56 + e] = 0.f;
  }
  __syncthreads();

  // row softmax (rows 0..48)
  if (tid < 49) {
    float* pr = &TP[tid * 56];
    float mx = -1e30f;
    for (int e = 0; e < 49; ++e) mx = fmaxf(mx, pr[e]);
    float sum = 0.f;
    for (int e = 0; e < 49; ++e) { float ex = __expf(pr[e] - mx); pr[e] = ex; sum += ex; }
    float inv = 1.f / sum;
    for (int e = 0; e < 49; ++e) pr[e] *= inv;
  }
  __syncthreads();

  // Pbar (column sums) + linear BN terms
  float lin = 0.f, pvb = 0.f;
  if (tid < 49) {
    float pb = 0.f;
    for (int d = 0; d < 49; ++d) pb += TP[d*56 + tid];
    Pbar[(((long)b*27 + i)*27 + j)*49 + tid] = pb;
    long vo = ((long)b*27 + i)*49 + tid;
    lin = pb * V1[vo];
    pvb = pb * Vb2[vo];
  }

  // q2 = sum_{e,e2} M[e,e2] G[e,e2], M = P^T P.
  // strips: s = k*49 + e, e fast. k8 = k*8 selects e2 block [k8, k8+7].
  float q2 = 0.f;
  const float* Gp = G + ((long)b*27 + i) * 2401;
  for (int s = tid; s < 343; s += 128) {
    int k = s / 49;
    int e = s - k * 49;
    int k8 = k * 8;
    float t[8];
#pragma unroll
    for (int kk = 0; kk < 8; ++kk) t[kk] = 0.f;
#pragma unroll 7
    for (int d = 0; d < 49; ++d) {
      float pe = TP[d*56 + e];                         // lane-consecutive e
      f32x4 a  = *(const f32x4*)&TP[d*56 + k8];        // uniform in e-group: broadcast
      f32x4 bq = *(const f32x4*)&TP[d*56 + k8 + 4];
      t[0] = fmaf(pe, a[0], t[0]); t[1] = fmaf(pe, a[1], t[1]);
      t[2] = fmaf(pe, a[2], t[2]); t[3] = fmaf(pe, a[3], t[3]);
      t[4] = fmaf(pe, bq[0], t[4]); t[5] = fmaf(pe, bq[1], t[5]);
      t[6] = fmaf(pe, bq[2], t[6]); t[7] = fmaf(pe, bq[3], t[7]);
    }
    const float* g = Gp + e * 49 + k8;
    int lim = 49 - k8;                 // >= 1
#pragma unroll
    for (int kk = 0; kk < 8; ++kk)
      if (kk < lim) q2 = fmaf(t[kk], g[kk], q2);
  }

  float r1 = lin, r2 = q2 + 2.f * pvb;
#pragma unroll
  for (int off = 32; off; off >>= 1) { r1 += __shfl_down(r1, off); r2 += __shfl_down(r2, off); }
  int lane = tid & 63, wid = tid >> 6;
  if (lane == 0) { red[wid] = r1; red[2 + wid] = r2; }
  __syncthreads();
  if (tid == 0) {
    long o = ((long)b*729 + x) * 2;
    parts[o]     = red[0] + red[1];
    parts[o + 1] = red[2] + red[3];
  }
}

// ============ per-edge BN stats over (b,d,c) ============
__global__ __launch_bounds__(256)
void edge_fin(const float* __restrict__ parts, const float* __restrict__ b2st,
              float* __restrict__ ems)
{
  int e = blockIdx.x * 256 + threadIdx.x;
  if (e < 729) {
    float B1 = b2st[0], nb2 = b2st[1];
    float s = 196.f * B1, q = 196.f * nb2;
#pragma unroll
    for (int b = 0; b < 4; ++b) {
      s += parts[((long)b * 729 + e) * 2 + 0];
      q += parts[((long)b * 729 + e) * 2 + 1];
    }
    const float inv = 1.f / 100352.f;
    float m = s * inv;
    float var = q * inv - m * m;
    ems[e*2]   = m;
    ems[e*2+1] = rsqrtf(var + EPS_);
  }
}

// ============ f_e = BN( Pbar@VW/49 + b2 ), emits fp32 + planes ============
__global__ __launch_bounds__(256)
void fe_build(const float* __restrict__ Pbar, const float* __restrict__ VW,
              const float* __restrict__ b2, const float* __restrict__ ems,
              const float* __restrict__ gw, const float* __restrict__ gb,
              float* __restrict__ fe, short* __restrict__ feh, short* __restrict__ fel)
{
  __shared__ float Pb[27 * 49];
  const int i = blockIdx.x, b = blockIdx.y;
  const int tid = threadIdx.x;
  const float* pp = Pbar + ((long)b*27 + i) * 27 * 49;
  for (int idx = tid; idx < 1323; idx += 256) Pb[idx] = pp[idx];
  __syncthreads();
  const float* vp = VW + ((long)b*1323 + (long)i*49) * 512;
#pragma unroll 1
  for (int half = 0; half < 2; ++half) {
    int c = half * 256 + tid;
    float acc[27];
#pragma unroll
    for (int j = 0; j < 27; ++j) acc[j] = 0.f;
    for (int e = 0; e < 49; ++e) {
      float v = vp[(long)e*512 + c];
#pragma unroll
      for (int j = 0; j < 27; ++j) acc[j] = fmaf(Pb[j*49 + e], v, acc[j]);
    }
    float bz = b2[c];
#pragma unroll
    for (int j = 0; j < 27; ++j) {
      int ij = i*27 + j;
      float m = ems[ij*2], rs = ems[ij*2+1];
      float h = acc[j] * (1.f/49.f) + bz;
      float v = fmaf((h - m) * rs, gw[ij], gb[ij]);
      long o = ((long)b*729 + ij)*512 + c;
      fe[o] = v;
      short hh, ll; split2(v, hh, ll);
      feh[o] = hh; fel[o] = ll;
    }
  }
}

// ============ GNN kernels ============
__global__ __launch_bounds__(256)
void gnn_edge_bn(const float* __restrict__ vi, const float* __restrict__ vj,
                 const float* __restrict__ el, const float* __restrict__ wv,
                 const float* __restrict__ bv, float* fe,
                 short* __restrict__ feh, short* __restrict__ fel)
{
  int ij = blockIdx.x; int i = ij / 27, j = ij - i * 27;
  int t = threadIdx.x;
  __shared__ float red[18];
  float mv[8]; float s = 0.f, q = 0.f;
#pragma unroll
  for (int p = 0; p < 8; ++p) {
    int idx = p * 256 + t; int b = idx >> 9, c = idx & 511;
    float v = vi[((long)b*27+i)*512 + c] + vj[((long)b*27+j)*512 + c]
            + el[((long)b*729+ij)*512 + c];
    mv[p] = v; s += v; q = fmaf(v, v, q);
  }
  int lane = t & 63, wid = t >> 6;
#pragma unroll
  for (int off = 32; off; off >>= 1) { s += __shfl_down(s, off); q += __shfl_down(q, off); }
  if (lane == 0) { red[wid] = s; red[4 + wid] = q; }
  __syncthreads();
  if (t == 0) {
    float S = red[0]+red[1]+red[2]+red[3], Q = red[4]+red[5]+red[6]+red[7];
    float m = S * (1.f / 2048.f);
    red[16] = m;
    red[17] = rsqrtf(Q * (1.f / 2048.f) - m * m + EPS_);
  }
  __syncthreads();
  float m = red[16], rs = red[17];
  float w = wv[ij], bb = bv[ij];
#pragma unroll
  for (int p = 0; p < 8; ++p) {
    int idx = p * 256 + t; int b = idx >> 9, c = idx & 511;
    long o = ((long)b*729+ij)*512 + c;
    float nv = fe[o] + fmaxf(fmaf((mv[p] - m) * rs, w, bb), 0.f);
    fe[o] = nv;
    short hh, ll; split2(nv, hh, ll);
    feh[o] = hh; fel[o] = ll;
  }
}

__global__ __launch_bounds__(256)
void gnn_agg(const float* __restrict__ fe, const float* __restrict__ ui,
             const float* __restrict__ uj, float* __restrict__ agg)
{
  int i = blockIdx.x, b = blockIdx.y;
  int t = threadIdx.x;
#pragma unroll
  for (int cq = 0; cq < 2; ++cq) {
    int c = cq * 256 + t;
    float sg[27];
    float mx = -1e30f;
#pragma unroll
    for (int j = 0; j < 27; ++j) {
      float x = fe[((long)b*729 + i*27 + j)*512 + c];
      float sgm = 1.f / (1.f + __expf(-x));
      sg[j] = sgm; mx = fmaxf(mx, sgm);
    }
    float sum = 0.f;
#pragma unroll
    for (int j = 0; j < 27; ++j) { float e2 = __expf(sg[j] - mx); sg[j] = e2; sum += e2; }
    float acc = 0.f;
#pragma unroll
    for (int j = 0; j < 27; ++j)
      acc = fmaf(sg[j], uj[((long)b*27+j)*512 + c], acc);
    agg[((long)b*27+i)*512 + c] = ui[((long)b*27+i)*512 + c] + acc / (sum * 27.f);
  }
}

__global__ __launch_bounds__(256)
void gnn_node_bn(const float* __restrict__ agg, const float* __restrict__ wv,
                 const float* __restrict__ bv, float* fv,
                 short* __restrict__ fvh, short* __restrict__ fvl)
{
  int i = blockIdx.x;
  int t = threadIdx.x;
  __shared__ float red[18];
  float mv[8]; float s = 0.f, q = 0.f;
#pragma unroll
  for (int p = 0; p < 8; ++p) {
    int idx = p * 256 + t; int b = idx >> 9, c = idx & 511;
    float v = agg[((long)b*27+i)*512 + c];
    mv[p] = v; s += v; q = fmaf(v, v, q);
  }
  int lane = t & 63, wid = t >> 6;
#pragma unroll
  for (int off = 32; off; off >>= 1) { s += __shfl_down(s, off); q += __shfl_down(q, off); }
  if (lane == 0) { red[wid] = s; red[4 + wid] = q; }
  __syncthreads();
  if (t == 0) {
    float S = red[0]+red[1]+red[2]+red[3], Q = red[4]+red[5]+red[6]+red[7];
    float m = S * (1.f / 2048.f);
    red[16] = m;
    red[17] = rsqrtf(Q * (1.f / 2048.f) - m * m + EPS_);
  }
  __syncthreads();
  float m = red[16], rs = red[17];
  float w = wv[i], bb = bv[i];
#pragma unroll
  for (int p = 0; p < 8; ++p) {
    int idx = p * 256 + t; int b = idx >> 9, c = idx & 511;
    long o = ((long)b*27+i)*512 + c;
    float nv = fv[o] + fmaxf(fmaf((mv[p] - m) * rs, w, bb), 0.f);
    fv[o] = nv;
    short hh, ll; split2(nv, hh, ll);
    fvh[o] = hh; fvl[o] = ll;
  }
}

__constant__ int SUB_IDX_c[14] = {0,0,1,1,2,2,4,4,7,7,8,8,11,11};

__global__ __launch_bounds__(64)
void sc_k(const float* __restrict__ fv, const float* __restrict__ mainsc,
          const float* __restrict__ subsc, float* __restrict__ out)
{
  int o = blockIdx.x, b = blockIdx.y;
  int lane = threadIdx.x;
  int r; const float* ap;
  if (o < 27) { r = o; ap = mainsc + (long)o * 512; }
  else        { int k = o - 27; r = SUB_IDX_c[k]; ap = subsc + (long)k * 512; }
  const float* fp = fv + ((long)b*27 + r) * 512;
  float sff = 0.f, saa = 0.f, sfa = 0.f;
  for (int c = lane; c < 512; c += 64) {
    float f = fp[c];
    float a = fmaxf(ap[c], 0.f);
    sff = fmaf(f, f, sff); saa = fmaf(a, a, saa); sfa = fmaf(f, a, sfa);
  }
#pragma unroll
  for (int off = 32; off; off >>= 1) {
    sff += __shfl_down(sff, off); saa += __shfl_down(saa, off); sfa += __shfl_down(sfa, off);
  }
  if (lane == 0)
    out[b * 41 + o] = sfa / (fmaxf(sqrtf(sff), 1e-12f) * fmaxf(sqrtf(saa), 1e-12f));
}

} // namespace

extern "C" void kernel_launch(void* const* d_in, const int* in_sizes, int n_in,
                              void* d_out, int out_size, void* d_ws, size_t ws_size,
                              hipStream_t stream)
{
  (void)in_sizes; (void)n_in; (void)out_size; (void)ws_size;
  const float* x       = (const float*)d_in[0];
  const float* nb_W    = (const float*)d_in[1];
  const float* nb_b    = (const float*)d_in[2];
  const float* nb_bnw  = (const float*)d_in[3];
  const float* nb_bnb  = (const float*)d_in[4];
  const float* fam_qW  = (const float*)d_in[5];
  const float* fam_qb  = (const float*)d_in[6];
  const float* fam_kW  = (const float*)d_in[7];
  const float* fam_kb  = (const float*)d_in[8];
  const float* fam_vW  = (const float*)d_in[9];
  const float* fam_vb  = (const float*)d_in[10];
  const float* arm_qW  = (const float*)d_in[11];
  const float* arm_qb  = (const float*)d_in[12];
  const float* arm_kW  = (const float*)d_in[13];
  const float* arm_kb  = (const float*)d_in[14];
  const float* arm_vW  = (const float*)d_in[15];
  const float* arm_vb  = (const float*)d_in[16];
  const float* ep_W    = (const float*)d_in[17];
  const float* ep_b    = (const float*)d_in[18];
  const float* gem_bnw = (const float*)d_in[19];
  const float* gem_bnb = (const float*)d_in[20];
  const float* gnn_uW  = (const float*)d_in[21];
  const float* gnn_vW  = (const float*)d_in[22];
  const float* gnn_aW  = (const float*)d_in[23];
  const float* gnn_bW  = (const float*)d_in[24];
  const float* gnn_eW  = (const float*)d_in[25];
  const float* gnn_bnvw = (const float*)d_in[26];
  const float* gnn_bnvb = (const float*)d_in[27];
  const float* gnn_bnew = (const float*)d_in[28];
  const float* gnn_bneb = (const float*)d_in[29];
  const float* main_sc  = (const float*)d_in[30];
  const float* sub_sc   = (const float*)d_in[31];
  float* out = (float*)d_out;

  // ---- workspace carve: fp32 region then bf16 plane region (~92 MB total) ----
  char* wp = (char*)d_ws;
  auto carveF = [&](long n) -> float* { float* p = (float*)wp; wp += ((n + 15) & ~15L) * 4; return p; };
  auto carveS = [&](long n) -> short* { short* p = (short*)wp; wp += ((n + 15) & ~15L) * 2; return p; };

  float* Hnb   = carveF((long)27*196*512);   // dead after nb_apply; VW aliases
  float* S     = carveF((long)4*1323*1344);  // dead after arm_post; el aliases
  float* fe    = carveF((long)4*729*512);
  float* kf    = carveF(196*256);
  float* vf    = carveF(196*512);
  float* qfam  = carveF((long)5292*256);
  float* nbm   = carveF(27*512);
  float* nbr   = carveF(27*512);
  float* Mpre  = carveF(512*512);
  float* bias2 = carveF(512);
  float* b2st  = carveF(16);
  float* parts = carveF(4*729*2);
  float* ems   = carveF(1460);
  float* G     = carveF((long)108*2401);
  float* V1    = carveF(108*49);
  float* Vb2   = carveF(108*49);
  float* Pbar  = carveF((long)4*27*27*49);
  float* fv    = carveF(108*512);
  float* vi    = carveF(108*512);
  float* vj    = carveF(108*512);
  float* uj    = carveF(108*512);
  float* ui    = carveF(108*512);
  float* agg   = carveF(108*512);
  float* VW = Hnb;   // alias (Hnb dead after nb_apply)
  float* el = S;     // alias (S dead after arm_post)

  short* xh    = carveS(100352);
  short* xl    = carveS(100352);
  short* wph   = carveS((long)26*131072);    // weight hi planes (26 chunks)
  short* wpl   = carveS((long)26*131072);
  short* Mpreh = carveS(262144);
  short* Mprel = carveS(262144);
  short* fuh   = carveS((long)5292*512);     // dead after FAM-q GEMM; feath aliases
  short* ful   = carveS((long)5292*512);
  short* Qah   = carveS((long)5292*256);     // Qah+Qal contiguous: feh alias
  short* Qal   = carveS((long)5292*256);
  short* Kah   = carveS((long)4*1344*256);   // Kah+Kal contiguous: fel alias
  short* Kal   = carveS((long)4*1344*256);
  short* fvh   = carveS(108*512);
  short* fvl   = carveS(108*512);
  short* feath = fuh;   // alias: fu last read step 6; feat written step 7
  short* featl = ful;
  short* feh   = Qah;   // alias: Qa/Ka last read step 13; fe planes written step 17
  short* fel   = Kah;   // (feh spans Qah+Qal region, fel spans Kah+Kal region)

  // weight plane offsets (chunks of 131072 shorts)
  short* famqWh = wph + 0L*131072;        short* famqWl = wpl + 0L*131072;
  short* famkWh = wph + 1L*131072;        short* famkWl = wpl + 1L*131072;
  short* armqWh = wph + 2L*131072;        short* armqWl = wpl + 2L*131072;
  short* armkWh = wph + 3L*131072;        short* armkWl = wpl + 3L*131072;
  short* famvWh = wph + 4L*131072;        short* famvWl = wpl + 4L*131072;
  short* uWh    = wph + 6L*131072;        short* uWl    = wpl + 6L*131072;
  short* vWh    = wph + 10L*131072;       short* vWl    = wpl + 10L*131072;
  short* aWh    = wph + 14L*131072;       short* aWl    = wpl + 14L*131072;
  short* bWh    = wph + 18L*131072;       short* bWl    = wpl + 18L*131072;
  short* eWh    = wph + 22L*131072;       short* eWl    = wpl + 22L*131072;

  // ---- conversions ----
  cvt1_k<<<dim3(98), 256, 0, stream>>>(x, xh, xl, 25088);
  P10 p10;
  p10.s[0] = fam_qW; p10.s[1] = fam_kW; p10.s[2] = arm_qW; p10.s[3] = arm_kW;
  p10.s[4] = fam_vW; p10.s[5] = gnn_uW; p10.s[6] = gnn_vW; p10.s[7] = gnn_aW;
  p10.s[8] = gnn_bW; p10.s[9] = gnn_eW;
  cvt_w_k<<<dim3(64, 26), 256, 0, stream>>>(p10, wph, wpl);

  // 1) node-block GEMMs (W converted on the fly from fp32 nb_W)
  gemm_bf3_k<1><<<dim3(8,4,27), 256, 0, stream>>>(xh, xl, nullptr, nullptr, nb_W,
      nb_b, Hnb, nullptr, nullptr, 196, 512, 512, 0, 262144, 512, 100352);
  // 2-3) BN stats + apply -> fu planes, fv (+planes)
  nb_stats<<<dim3(27,2), 256, 0, stream>>>(Hnb, nbm, nbr);
  nb_apply<<<dim3(27,4), 256, 0, stream>>>(Hnb, nbm, nbr, nb_bnw, nb_bnb,
      fuh, ful, fv, fvh, fvl);
  // 4-5) FAM k, v
  gemm_bf3_k<0><<<dim3(4,4), 256, 0, stream>>>(xh, xl, famkWh, famkWl, nullptr,
      fam_kb, kf, nullptr, nullptr, 196, 256, 512, 0,0,0,0);
  gemm_bf3_k<0><<<dim3(8,4), 256, 0, stream>>>(xh, xl, famvWh, famvWl, nullptr,
      fam_vb, vf, nullptr, nullptr, 196, 512, 512, 0,0,0,0);
  // 6) FAM q (last read of fu planes)
  gemm_bf3_k<0><<<dim3(4,83), 256, 0, stream>>>(fuh, ful, famqWh, famqWl, nullptr,
      fam_qb, qfam, nullptr, nullptr, 5292, 256, 512, 0,0,0,0);
  // 7) FAM cross-attention -> feat planes (overlays fu planes; batch-major)
  attn_fam<<<dim3(27,4), 512, 0, stream>>>(qfam, kf, vf, feath, featl);
  // 8) ARM Q (planes only)
  gemm_bf3_k<0><<<dim3(4,83), 256, 0, stream>>>(feath, featl, armqWh, armqWl, nullptr,
      arm_qb, nullptr, Qah, Qal, 5292, 256, 512, 0,0,0,0);
  // 9) ARM K (per-batch, row-padded to 1344; planes only)
  gemm_bf3_k<0><<<dim3(4,21,4), 256, 0, stream>>>(feath, featl, armkWh, armkWl, nullptr,
      arm_kb, nullptr, Kah, Kal, 1323, 256, 512, (long)1323*512, 0, 0, (long)1344*256);
  // 10) Mpre = ep_W @ arm_vW (fp32) + convert
  gemm_nn_k<<<dim3(8,8), 256, 0, stream>>>(ep_W, arm_vW, Mpre, 512, 512, 512);
  cvt1_k<<<dim3(256), 256, 0, stream>>>(Mpre, Mpreh, Mprel, 65536);
  // 11) bias2 + scalar sums
  bias2red_k<<<dim3(1), 512, 0, stream>>>(ep_W, arm_vb, ep_b, bias2, b2st);
  // 12) VW = feat @ Mpre^T (fp32 out, overlays Hnb)
  gemm_bf3_k<0><<<dim3(8,83), 256, 0, stream>>>(feath, featl, Mpreh, Mprel, nullptr,
      nullptr, VW, nullptr, nullptr, 5292, 512, 512, 0,0,0,0);
  // 13) S_all[b] = Qa_b @ Ka_b^T (last read of Qa/Ka planes)
  gemm_bf3_k<0><<<dim3(21,21,4), 256, 0, stream>>>(Qah, Qal, Kah, Kal, nullptr,
      nullptr, S, nullptr, nullptr, 1323, 1344, 256,
      (long)1323*256, (long)1344*256, 0, (long)1323*1344);
  // 14) G = VW VW^T per (b,i) + row sums
  gmat_k<<<dim3(27,4), 256, 0, stream>>>(VW, bias2, G, V1, Vb2);
  // 15) segmented softmax + Pbar + BN partials (last read of S)
  arm_post<<<dim3(729,4), 128, 0, stream>>>(S, G, V1, Vb2, Pbar, parts);
  // 16) per-edge BN stats
  edge_fin<<<dim3(3), 256, 0, stream>>>(parts, b2st, ems);
  // 17) f_e = BN(Pbar@VW/49 + b2) -> fp32 + planes (planes overlay Qa/Ka)
  fe_build<<<dim3(27,4), 256, 0, stream>>>(Pbar, VW, bias2, ems, gem_bnw, gem_bnb,
      fe, feh, fel);
  // 18) 2 GatedGNN layers
  for (int l = 0; l < 2; ++l) {
    long wo = (long)l * 262144;
    G4 g4;
    g4.wh[0] = aWh + wo; g4.wl[0] = aWl + wo; g4.c[0] = vi;
    g4.wh[1] = bWh + wo; g4.wl[1] = bWl + wo; g4.c[1] = vj;
    g4.wh[2] = vWh + wo; g4.wl[2] = vWl + wo; g4.c[2] = uj;
    g4.wh[3] = uWh + wo; g4.wl[3] = uWl + wo; g4.c[3] = ui;
    gemm4_bf3_k<<<dim3(8,2,4), 256, 0, stream>>>(fvh, fvl, g4, 108, 512, 512);
    gemm_bf3_k<0><<<dim3(8,46), 256, 0, stream>>>(feh, fel, eWh + wo, eWl + wo, nullptr,
        nullptr, el, nullptr, nullptr, 2916, 512, 512, 0,0,0,0);
    gnn_edge_bn<<<dim3(729), 256, 0, stream>>>(vi, vj, el,
        gnn_bnew + (long)l*729, gnn_bneb + (long)l*729, fe, feh, fel);
    gnn_agg<<<dim3(27,4), 256, 0, stream>>>(fe, ui, uj, agg);
    gnn_node_bn<<<dim3(27), 256, 0, stream>>>(agg,
        gnn_bnvw + (long)l*27, gnn_bnvb + (long)l*27, fv, fvh, fvl);
  }
  // 19) cosine-similarity outputs [4,41]
  sc_k<<<dim3(41,4), 64, 0, stream>>>(fv, main_sc, sub_sc, out);
}

// Round 8
// 645.510 us; speedup vs baseline: 1.8419x; 1.0152x over previous
//
#include <hip/hip_runtime.h>
#include <hip/hip_bf16.h>
#include <math.h>

// MEFL forward. B=4, D=49, C=512, N=27, C2=256.
// R8: attn_fam (55us, 108-block latency-bound) deleted; FAM = S-GEMM (z=4) +
// row-parallel softmax (5292 rows) + PV-GEMM (z=4) on the bf16x3 MFMA core.
// fu now emitted batch-major so FAM-q planes are batch-contiguous.
// Everything else identical to R7 (655 us baseline).

namespace {

constexpr float SCALE_ = 0.0625f;   // 256^-0.5
constexpr float EPS_   = 1e-5f;

typedef __attribute__((ext_vector_type(8))) short bf16x8;
typedef __attribute__((ext_vector_type(4))) short s16x4;
typedef __attribute__((ext_vector_type(4))) float f32x4;

__device__ __forceinline__ short f2bf(float f) {
  unsigned u = __float_as_uint(f);
  u += 0x7fffu + ((u >> 16) & 1u);
  return (short)(u >> 16);
}
__device__ __forceinline__ float bf2f(short h) {
  return __uint_as_float(((unsigned)(unsigned short)h) << 16);
}
__device__ __forceinline__ void split2(float f, short& h, short& l) {
  h = f2bf(f);
  l = f2bf(f - bf2f(h));
}

// ============ bf16x3 MFMA GEMM: C[M,N] = A[M,K] @ W[N,K]^T + bias ============
template<int CONVB>
__device__ __forceinline__
void gemm_bf3_core(const short* __restrict__ Ah, const short* __restrict__ Al,
                   const short* __restrict__ Wh, const short* __restrict__ Wl,
                   const float* __restrict__ Wf,
                   const float* __restrict__ bias, float* __restrict__ C,
                   short* __restrict__ Ch, short* __restrict__ Cl,
                   int M, int N, int K)
{
  __shared__ short sA[2][64][40];   // [hi/lo][row][k], 80B row stride (16B aligned)
  __shared__ short sB[2][64][40];
  const int tid  = threadIdx.x;
  const int n0   = blockIdx.x * 64, m0 = blockIdx.y * 64;
  const int wave = tid >> 6, lane = tid & 63;
  const int wr = (wave >> 1) * 32, wc = (wave & 1) * 32;
  const int lr = lane & 15, lk = (lane >> 4) * 8;
  const int sr = tid >> 2, sk = (tid & 3) * 8;
  const int arow = m0 + sr;

  f32x4 acc[2][2] = {};

  for (int k0 = 0; k0 < K; k0 += 32) {
    bf16x8 ah = {}, al = {};
    if (arow < M) {
      ah = *(const bf16x8*)(Ah + (long)arow * K + k0 + sk);
      al = *(const bf16x8*)(Al + (long)arow * K + k0 + sk);
    }
    bf16x8 bh, bl;
    if (CONVB) {
      f32x4 w0 = *(const f32x4*)(Wf + (long)(n0 + sr) * K + k0 + sk);
      f32x4 w1 = *(const f32x4*)(Wf + (long)(n0 + sr) * K + k0 + sk + 4);
#pragma unroll
      for (int j = 0; j < 4; ++j) {
        short h, l;
        split2(w0[j], h, l); bh[j] = h;     bl[j] = l;
        split2(w1[j], h, l); bh[4 + j] = h; bl[4 + j] = l;
      }
    } else {
      bh = *(const bf16x8*)(Wh + (long)(n0 + sr) * K + k0 + sk);
      bl = *(const bf16x8*)(Wl + (long)(n0 + sr) * K + k0 + sk);
    }
    __syncthreads();
    *(bf16x8*)&sA[0][sr][sk] = ah;
    *(bf16x8*)&sA[1][sr][sk] = al;
    *(bf16x8*)&sB[0][sr][sk] = bh;
    *(bf16x8*)&sB[1][sr][sk] = bl;
    __syncthreads();

    bf16x8 a0h = *(const bf16x8*)&sA[0][wr + lr][lk];
    bf16x8 a1h = *(const bf16x8*)&sA[0][wr + 16 + lr][lk];
    bf16x8 a0l = *(const bf16x8*)&sA[1][wr + lr][lk];
    bf16x8 a1l = *(const bf16x8*)&sA[1][wr + 16 + lr][lk];
    bf16x8 b0h = *(const bf16x8*)&sB[0][wc + lr][lk];
    bf16x8 b1h = *(const bf16x8*)&sB[0][wc + 16 + lr][lk];
    bf16x8 b0l = *(const bf16x8*)&sB[1][wc + lr][lk];
    bf16x8 b1l = *(const bf16x8*)&sB[1][wc + 16 + lr][lk];

    acc[0][0] = __builtin_amdgcn_mfma_f32_16x16x32_bf16(a0h, b0h, acc[0][0], 0, 0, 0);
    acc[0][1] = __builtin_amdgcn_mfma_f32_16x16x32_bf16(a0h, b1h, acc[0][1], 0, 0, 0);
    acc[1][0] = __builtin_amdgcn_mfma_f32_16x16x32_bf16(a1h, b0h, acc[1][0], 0, 0, 0);
    acc[1][1] = __builtin_amdgcn_mfma_f32_16x16x32_bf16(a1h, b1h, acc[1][1], 0, 0, 0);
    acc[0][0] = __builtin_amdgcn_mfma_f32_16x16x32_bf16(a0h, b0l, acc[0][0], 0, 0, 0);
    acc[0][1] = __builtin_amdgcn_mfma_f32_16x16x32_bf16(a0h, b1l, acc[0][1], 0, 0, 0);
    acc[1][0] = __builtin_amdgcn_mfma_f32_16x16x32_bf16(a1h, b0l, acc[1][0], 0, 0, 0);
    acc[1][1] = __builtin_amdgcn_mfma_f32_16x16x32_bf16(a1h, b1l, acc[1][1], 0, 0, 0);
    acc[0][0] = __builtin_amdgcn_mfma_f32_16x16x32_bf16(a0l, b0h, acc[0][0], 0, 0, 0);
    acc[0][1] = __builtin_amdgcn_mfma_f32_16x16x32_bf16(a0l, b1h, acc[0][1], 0, 0, 0);
    acc[1][0] = __builtin_amdgcn_mfma_f32_16x16x32_bf16(a1l, b0h, acc[1][0], 0, 0, 0);
    acc[1][1] = __builtin_amdgcn_mfma_f32_16x16x32_bf16(a1l, b1h, acc[1][1], 0, 0, 0);
  }

  const int rbase = m0 + wr + (lane >> 4) * 4;
  const int cb = n0 + wc + lr;
#pragma unroll
  for (int fj = 0; fj < 2; ++fj) {
    int col = cb + fj * 16;
    float bz = bias ? bias[col] : 0.f;
#pragma unroll
    for (int fi = 0; fi < 2; ++fi) {
#pragma unroll
      for (int r = 0; r < 4; ++r) {
        int row = rbase + fi * 16 + r;
        if (row < M) {
          float v = acc[fi][fj][r] + bz;
          long o = (long)row * N + col;
          if (C) C[o] = v;
          if (Ch) { short h, l; split2(v, h, l); Ch[o] = h; Cl[o] = l; }
        }
      }
    }
  }
}

template<int CONVB>
__global__ __launch_bounds__(256)
void gemm_bf3_k(const short* Ah, const short* Al, const short* Wh, const short* Wl,
                const float* Wf, const float* bias, float* C, short* Ch, short* Cl,
                int M, int N, int K, long aBS, long wBS, long bBS, long cBS)
{
  long z = blockIdx.z;
  gemm_bf3_core<CONVB>(Ah + z * aBS, Al + z * aBS,
                       Wh ? Wh + z * wBS : nullptr, Wl ? Wl + z * wBS : nullptr,
                       Wf ? Wf + z * wBS : nullptr,
                       bias ? bias + z * bBS : nullptr,
                       C ? C + z * cBS : nullptr,
                       Ch ? Ch + z * cBS : nullptr, Cl ? Cl + z * cBS : nullptr,
                       M, N, K);
}

struct G4 { const short* wh[4]; const short* wl[4]; float* c[4]; };

__global__ __launch_bounds__(256)
void gemm4_bf3_k(const short* Ah, const short* Al, G4 g, int M, int N, int K)
{
  int z = blockIdx.z;
  gemm_bf3_core<0>(Ah, Al, g.wh[z], g.wl[z], nullptr, nullptr, g.c[z],
                   nullptr, nullptr, M, N, K);
}

// ============ conversion kernels ============
__global__ __launch_bounds__(256)
void cvt1_k(const float* __restrict__ s, short* __restrict__ dh,
            short* __restrict__ dl, int n4)
{
  long i = (long)blockIdx.x * 256 + threadIdx.x;
  if (i >= n4) return;
  f32x4 v = *(const f32x4*)(s + i * 4);
  s16x4 h, l;
#pragma unroll
  for (int j = 0; j < 4; ++j) { short hh, ll; split2(v[j], hh, ll); h[j] = hh; l[j] = ll; }
  *(s16x4*)(dh + i * 4) = h;
  *(s16x4*)(dl + i * 4) = l;
}

struct P10 { const float* s[10]; };

// 26 chunks of 131072 elems: famq,famk,armq,armk @0-3; famv @4-5; gnn u,v,a,b,e @6..25
__global__ __launch_bounds__(256)
void cvt_w_k(P10 p, short* __restrict__ dh, short* __restrict__ dl)
{
  static const int tens[26] = {0,1,2,3,4,4,5,5,5,5,6,6,6,6,7,7,7,7,8,8,8,8,9,9,9,9};
  static const int coff[26] = {0,0,0,0,0,1,0,1,2,3,0,1,2,3,0,1,2,3,0,1,2,3,0,1,2,3};
  int c = blockIdx.y;
  const float* src = p.s[tens[c]] + (long)coff[c] * 131072;
  long dbase = (long)c * 131072;
  long i = ((long)blockIdx.x * 256 + threadIdx.x) * 8;
  f32x4 v0 = *(const f32x4*)(src + i);
  f32x4 v1 = *(const f32x4*)(src + i + 4);
  s16x4 h0, l0, h1, l1;
#pragma unroll
  for (int j = 0; j < 4; ++j) {
    short hh, ll;
    split2(v0[j], hh, ll); h0[j] = hh; l0[j] = ll;
    split2(v1[j], hh, ll); h1[j] = hh; l1[j] = ll;
  }
  *(s16x4*)(dh + dbase + i) = h0;     *(s16x4*)(dh + dbase + i + 4) = h1;
  *(s16x4*)(dl + dbase + i) = l0;     *(s16x4*)(dl + dbase + i + 4) = l1;
}

// ============ small NN GEMM (W is [K,N]) — only for Mpre = ep_W @ arm_vW ============
__global__ __launch_bounds__(256)
void gemm_nn_k(const float* __restrict__ A, const float* __restrict__ W,
               float* __restrict__ C, int M, int N, int K)
{
  __shared__ float As[32][68];
  __shared__ float Ws[32][68];
  const int tid = threadIdx.x;
  const int n0 = blockIdx.x * 64, m0 = blockIdx.y * 64;
  const int tx = tid & 15, ty = tid >> 4;
  float acc[4][4] = {};
  for (int k0 = 0; k0 < K; k0 += 32) {
#pragma unroll
    for (int p = 0; p < 2; ++p) {
      int idx = tid + p * 256;
      int row = idx >> 3, kq = idx & 7;
      float4 v = make_float4(0.f, 0.f, 0.f, 0.f);
      if (m0 + row < M)
        v = *(const float4*)(A + (long)(m0 + row) * K + k0 + kq * 4);
      As[kq*4+0][row] = v.x; As[kq*4+1][row] = v.y;
      As[kq*4+2][row] = v.z; As[kq*4+3][row] = v.w;
    }
#pragma unroll
    for (int p = 0; p < 2; ++p) {
      int idx = tid + p * 256;
      int row = idx >> 4, nq = idx & 15;
      float4 v = *(const float4*)(W + (long)(k0 + row) * N + n0 + nq * 4);
      *(float4*)&Ws[row][nq*4] = v;
    }
    __syncthreads();
#pragma unroll
    for (int k = 0; k < 32; ++k) {
      float4 a4 = *(const float4*)&As[k][ty*4];
      float4 b4 = *(const float4*)&Ws[k][tx*4];
      float av[4] = {a4.x, a4.y, a4.z, a4.w};
      float bv[4] = {b4.x, b4.y, b4.z, b4.w};
#pragma unroll
      for (int i2 = 0; i2 < 4; ++i2)
#pragma unroll
        for (int j2 = 0; j2 < 4; ++j2)
          acc[i2][j2] = fmaf(av[i2], bv[j2], acc[i2][j2]);
    }
    __syncthreads();
  }
#pragma unroll
  for (int i2 = 0; i2 < 4; ++i2) {
    int m = m0 + ty*4 + i2;
    if (m < M)
      *(float4*)(C + (long)m * N + n0 + tx*4) =
        make_float4(acc[i2][0], acc[i2][1], acc[i2][2], acc[i2][3]);
  }
}

// ============ node-block BN ============
__global__ __launch_bounds__(256)
void nb_stats(const float* __restrict__ H, float* __restrict__ mean, float* __restrict__ rs)
{
  int n = blockIdx.x;
  int c = blockIdx.y * 256 + threadIdx.x;
  const float* p = H + (long)n * 196 * 512 + c;
  float s = 0.f, q = 0.f;
  for (int r = 0; r < 196; ++r) { float v = p[(long)r * 512]; s += v; q = fmaf(v, v, q); }
  float m = s * (1.f / 196.f);
  float var = q * (1.f / 196.f) - m * m;
  mean[n * 512 + c] = m;
  rs[n * 512 + c] = rsqrtf(var + EPS_);
}

// fu planes now written BATCH-MAJOR: [b][n*49+d][512]
__global__ __launch_bounds__(256)
void nb_apply(const float* __restrict__ H, const float* __restrict__ mean,
              const float* __restrict__ rs, const float* __restrict__ bw,
              const float* __restrict__ bb,
              short* __restrict__ fuh, short* __restrict__ ful,
              float* __restrict__ fv, short* __restrict__ fvh, short* __restrict__ fvl)
{
  int n = blockIdx.x, b = blockIdx.y;
  int t = threadIdx.x;
#pragma unroll
  for (int cq = 0; cq < 2; ++cq) {
    int c = cq * 256 + t;
    float m = mean[n*512+c], r = rs[n*512+c];
    float w = bw[n*512+c], bias = bb[n*512+c];
    const float* hp = H + ((long)(n*4+b)*49) * 512 + c;
    long fo0 = ((long)b*1323 + (long)n*49) * 512 + c;   // batch-major
    float s = 0.f;
    for (int d = 0; d < 49; ++d) {
      float v = hp[(long)d*512];
      float o = fmaxf(fmaf((v - m) * r, w, bias), 0.f);
      short hh, ll; split2(o, hh, ll);
      fuh[fo0 + (long)d*512] = hh;
      ful[fo0 + (long)d*512] = ll;
      s += o;
    }
    float fvv = s * (1.f / 49.f);
    long fo = ((long)b*27+n)*512 + c;
    fv[fo] = fvv;
    short hh, ll; split2(fvv, hh, ll);
    fvh[fo] = hh; fvl[fo] = ll;
  }
}

// ============ FAM softmax: row-parallel, one 64-lane group per row ============
// Sf [4*1323][64] fp32 (cols>=49 garbage); writes P planes with zero pad cols.
__global__ __launch_bounds__(256)
void sm_fam_k(const float* __restrict__ Sf, short* __restrict__ Ph,
              short* __restrict__ Pl)
{
  int row = blockIdx.x * 4 + (threadIdx.x >> 6);
  int e = threadIdx.x & 63;
  float v = (e < 49) ? Sf[(long)row * 64 + e] * SCALE_ : -1e30f;
  float mx = v;
#pragma unroll
  for (int off = 32; off; off >>= 1) mx = fmaxf(mx, __shfl_xor(mx, off));
  float ex = (e < 49) ? __expf(v - mx) : 0.f;
  float sum = ex;
#pragma unroll
  for (int off = 32; off; off >>= 1) sum += __shfl_xor(sum, off);
  float p = ex / sum;
  short h, l; split2(p, h, l);
  Ph[(long)row * 64 + e] = h;
  Pl[(long)row * 64 + e] = l;
}

// ============ V transpose+convert: vf [4][49][512] fp32 -> VT planes [4][512][64] ============
__global__ __launch_bounds__(256)
void vt_cvt_k(const float* __restrict__ vf, short* __restrict__ VTh,
              short* __restrict__ VTl)
{
  int b = blockIdx.x;
  int n = blockIdx.y * 256 + threadIdx.x;
  long obase = ((long)b * 512 + n) * 64;
#pragma unroll 7
  for (int k = 0; k < 64; ++k) {
    float v = (k < 49) ? vf[((long)b * 49 + k) * 512 + n] : 0.f;
    short h, l; split2(v, h, l);
    VTh[obase + k] = h;
    VTl[obase + k] = l;
  }
}

// ============ bias2 = ep_W @ arm_vb + ep_b, plus B1 = sum(b2), nb2 = sum(b2^2) ============
__global__ __launch_bounds__(512)
void bias2red_k(const float* __restrict__ epW, const float* __restrict__ vb,
                const float* __restrict__ epb, float* __restrict__ bias2,
                float* __restrict__ b2st)
{
  int c = threadIdx.x;
  float s = epb[c];
  const float* r = epW + (long)c * 512;
  for (int k = 0; k < 512; ++k) s = fmaf(r[k], vb[k], s);
  bias2[c] = s;
  __shared__ float red[16];
  float s1 = s, s2 = s * s;
#pragma unroll
  for (int off = 32; off; off >>= 1) { s1 += __shfl_down(s1, off); s2 += __shfl_down(s2, off); }
  int lane = c & 63, wid = c >> 6;
  if (lane == 0) { red[wid] = s1; red[8 + wid] = s2; }
  __syncthreads();
  if (c == 0) {
    float a = 0.f, qq = 0.f;
#pragma unroll
    for (int w = 0; w < 8; ++w) { a += red[w]; qq += red[8 + w]; }
    b2st[0] = a; b2st[1] = qq;
  }
}

// ============ G = VW VW^T per (b,i), plus row sums ============
__constant__ unsigned char TI_c[28] = {0,1,1,2,2,2,3,3,3,3,4,4,4,4,4,5,5,5,5,5,5,6,6,6,6,6,6,6};
__constant__ unsigned char TJ_c[28] = {0,0,1,0,1,2,0,1,2,3,0,1,2,3,4,0,1,2,3,4,5,0,1,2,3,4,5,6};

__global__ __launch_bounds__(256)
void gmat_k(const float* __restrict__ VW, const float* __restrict__ b2,
            float* __restrict__ G, float* __restrict__ V1, float* __restrict__ Vb2)
{
  __shared__ float Vs[49][260];
  const int i = blockIdx.x, b = blockIdx.y;
  const int tid = threadIdx.x;
  const int wave = tid >> 6, lane = tid & 63;
  const int di = lane >> 3, ej = lane & 7;
  const float* vp = VW + ((long)b*1323 + (long)i*49) * 512;
  float gacc[7];
#pragma unroll
  for (int t = 0; t < 7; ++t) gacc[t] = 0.f;
  float s1 = 0.f, s2 = 0.f;

  for (int half = 0; half < 2; ++half) {
    __syncthreads();
    for (int idx = tid; idx < 49 * 64; idx += 256) {
      int r = idx >> 6, q = idx & 63;
      *(float4*)&Vs[r][q*4] = *(const float4*)(vp + (long)r*512 + half*256 + q*4);
    }
    __syncthreads();
    int tt = 0;
    for (int t = wave; t < 28; t += 4, ++tt) {
      int d = TI_c[t]*8 + di, e = TJ_c[t]*8 + ej;
      int dc = d > 48 ? 48 : d, ec = e > 48 ? 48 : e;
      float g = gacc[tt];
      for (int q = 0; q < 64; ++q) {
        float4 a = *(const float4*)&Vs[dc][q*4];
        float4 bq = *(const float4*)&Vs[ec][q*4];
        g = fmaf(a.x, bq.x, fmaf(a.y, bq.y, fmaf(a.z, bq.z, fmaf(a.w, bq.w, g))));
      }
      gacc[tt] = g;
    }
    if (tid < 49) {
      for (int c = 0; c < 256; ++c) {
        float v = Vs[tid][c];
        s1 += v; s2 = fmaf(v, b2[half*256 + c], s2);
      }
    }
  }
  long gbase = ((long)b*27 + i) * 2401;
  int tt = 0;
  for (int t = wave; t < 28; t += 4, ++tt) {
    int ti = TI_c[t], tj = TJ_c[t];
    int d = ti*8 + di, e = tj*8 + ej;
    if (d < 49 && e < 49) {
      G[gbase + d*49 + e] = gacc[tt];
      if (ti != tj) G[gbase + e*49 + d] = gacc[tt];
    }
  }
  if (tid < 49) {
    long o = ((long)b*27 + i) * 49 + tid;
    V1[o] = s1; Vb2[o] = s2;
  }
}

// ============ per-edge: segmented softmax, Pbar, BN partial sums ============
__global__ __launch_bounds__(128)
void arm_post(const float* __restrict__ S, const float* __restrict__ G,
              const float* __restrict__ V1, const float* __restrict__ Vb2,
              float* __restrict__ Pbar, float* __restrict__ parts)
{
  __shared__ float TP[49 * 56];
  __shared__ float red[8];
  const int tid = threadIdx.x;
  const int x = blockIdx.x, b = blockIdx.y;
  const int i = x / 27, j = x - i * 27;
  const float* Sp = S + (long)b*1323*1344 + (long)j*49*1344 + (long)i*49;
  for (int idx = tid; idx < 2401; idx += 128) {
    unsigned d = ((unsigned)idx * 1338u) >> 16;
    unsigned e = (unsigned)idx - d * 49u;
    TP[d*56 + e] = Sp[(long)d*1344 + e];
  }
  for (int idx = tid; idx < 343; idx += 128) {
    int d = idx / 7, e = 49 + idx - d * 7;
    TP[d*56 + e] = 0.f;
  }
  __syncthreads();

  if (tid < 49) {
    float* pr = &TP[tid * 56];
    float mx = -1e30f;
    for (int e = 0; e < 49; ++e) mx = fmaxf(mx, pr[e]);
    float sum = 0.f;
    for (int e = 0; e < 49; ++e) { float ex = __expf(pr[e] - mx); pr[e] = ex; sum += ex; }
    float inv = 1.f / sum;
    for (int e = 0; e < 49; ++e) pr[e] *= inv;
  }
  __syncthreads();

  float lin = 0.f, pvb = 0.f;
  if (tid < 49) {
    float pb = 0.f;
    for (int d = 0; d < 49; ++d) pb += TP[d*56 + tid];
    Pbar[(((long)b*27 + i)*27 + j)*49 + tid] = pb;
    long vo = ((long)b*27 + i)*49 + tid;
    lin = pb * V1[vo];
    pvb = pb * Vb2[vo];
  }

  float q2 = 0.f;
  const float* Gp = G + ((long)b*27 + i) * 2401;
  for (int s = tid; s < 343; s += 128) {
    int k = s / 49;
    int e = s - k * 49;
    int k8 = k * 8;
    float t[8];
#pragma unroll
    for (int kk = 0; kk < 8; ++kk) t[kk] = 0.f;
#pragma unroll 7
    for (int d = 0; d < 49; ++d) {
      float pe = TP[d*56 + e];
      f32x4 a  = *(const f32x4*)&TP[d*56 + k8];
      f32x4 bq = *(const f32x4*)&TP[d*56 + k8 + 4];
      t[0] = fmaf(pe, a[0], t[0]); t[1] = fmaf(pe, a[1], t[1]);
      t[2] = fmaf(pe, a[2], t[2]); t[3] = fmaf(pe, a[3], t[3]);
      t[4] = fmaf(pe, bq[0], t[4]); t[5] = fmaf(pe, bq[1], t[5]);
      t[6] = fmaf(pe, bq[2], t[6]); t[7] = fmaf(pe, bq[3], t[7]);
    }
    const float* g = Gp + e * 49 + k8;
    int lim = 49 - k8;
#pragma unroll
    for (int kk = 0; kk < 8; ++kk)
      if (kk < lim) q2 = fmaf(t[kk], g[kk], q2);
  }

  float r1 = lin, r2 = q2 + 2.f * pvb;
#pragma unroll
  for (int off = 32; off; off >>= 1) { r1 += __shfl_down(r1, off); r2 += __shfl_down(r2, off); }
  int lane = tid & 63, wid = tid >> 6;
  if (lane == 0) { red[wid] = r1; red[2 + wid] = r2; }
  __syncthreads();
  if (tid == 0) {
    long o = ((long)b*729 + x) * 2;
    parts[o]     = red[0] + red[1];
    parts[o + 1] = red[2] + red[3];
  }
}

// ============ per-edge BN stats over (b,d,c) ============
__global__ __launch_bounds__(256)
void edge_fin(const float* __restrict__ parts, const float* __restrict__ b2st,
              float* __restrict__ ems)
{
  int e = blockIdx.x * 256 + threadIdx.x;
  if (e < 729) {
    float B1 = b2st[0], nb2 = b2st[1];
    float s = 196.f * B1, q = 196.f * nb2;
#pragma unroll
    for (int b = 0; b < 4; ++b) {
      s += parts[((long)b * 729 + e) * 2 + 0];
      q += parts[((long)b * 729 + e) * 2 + 1];
    }
    const float inv = 1.f / 100352.f;
    float m = s * inv;
    float var = q * inv - m * m;
    ems[e*2]   = m;
    ems[e*2+1] = rsqrtf(var + EPS_);
  }
}

// ============ f_e = BN( Pbar@VW/49 + b2 ), emits fp32 + planes ============
__global__ __launch_bounds__(256)
void fe_build(const float* __restrict__ Pbar, const float* __restrict__ VW,
              const float* __restrict__ b2, const float* __restrict__ ems,
              const float* __restrict__ gw, const float* __restrict__ gb,
              float* __restrict__ fe, short* __restrict__ feh, short* __restrict__ fel)
{
  __shared__ float Pb[27 * 49];
  const int i = blockIdx.x, b = blockIdx.y;
  const int tid = threadIdx.x;
  const float* pp = Pbar + ((long)b*27 + i) * 27 * 49;
  for (int idx = tid; idx < 1323; idx += 256) Pb[idx] = pp[idx];
  __syncthreads();
  const float* vp = VW + ((long)b*1323 + (long)i*49) * 512;
#pragma unroll 1
  for (int half = 0; half < 2; ++half) {
    int c = half * 256 + tid;
    float acc[27];
#pragma unroll
    for (int j = 0; j < 27; ++j) acc[j] = 0.f;
    for (int e = 0; e < 49; ++e) {
      float v = vp[(long)e*512 + c];
#pragma unroll
      for (int j = 0; j < 27; ++j) acc[j] = fmaf(Pb[j*49 + e], v, acc[j]);
    }
    float bz = b2[c];
#pragma unroll
    for (int j = 0; j < 27; ++j) {
      int ij = i*27 + j;
      float m = ems[ij*2], rs = ems[ij*2+1];
      float h = acc[j] * (1.f/49.f) + bz;
      float v = fmaf((h - m) * rs, gw[ij], gb[ij]);
      long o = ((long)b*729 + ij)*512 + c;
      fe[o] = v;
      short hh, ll; split2(v, hh, ll);
      feh[o] = hh; fel[o] = ll;
    }
  }
}

// ============ GNN kernels ============
__global__ __launch_bounds__(256)
void gnn_edge_bn(const float* __restrict__ vi, const float* __restrict__ vj,
                 const float* __restrict__ el, const float* __restrict__ wv,
                 const float* __restrict__ bv, float* fe,
                 short* __restrict__ feh, short* __restrict__ fel)
{
  int ij = blockIdx.x; int i = ij / 27, j = ij - i * 27;
  int t = threadIdx.x;
  __shared__ float red[18];
  float mv[8]; float s = 0.f, q = 0.f;
#pragma unroll
  for (int p = 0; p < 8; ++p) {
    int idx = p * 256 + t; int b = idx >> 9, c = idx & 511;
    float v = vi[((long)b*27+i)*512 + c] + vj[((long)b*27+j)*512 + c]
            + el[((long)b*729+ij)*512 + c];
    mv[p] = v; s += v; q = fmaf(v, v, q);
  }
  int lane = t & 63, wid = t >> 6;
#pragma unroll
  for (int off = 32; off; off >>= 1) { s += __shfl_down(s, off); q += __shfl_down(q, off); }
  if (lane == 0) { red[wid] = s; red[4 + wid] = q; }
  __syncthreads();
  if (t == 0) {
    float S = red[0]+red[1]+red[2]+red[3], Q = red[4]+red[5]+red[6]+red[7];
    float m = S * (1.f / 2048.f);
    red[16] = m;
    red[17] = rsqrtf(Q * (1.f / 2048.f) - m * m + EPS_);
  }
  __syncthreads();
  float m = red[16], rs = red[17];
  float w = wv[ij], bb = bv[ij];
#pragma unroll
  for (int p = 0; p < 8; ++p) {
    int idx = p * 256 + t; int b = idx >> 9, c = idx & 511;
    long o = ((long)b*729+ij)*512 + c;
    float nv = fe[o] + fmaxf(fmaf((mv[p] - m) * rs, w, bb), 0.f);
    fe[o] = nv;
    short hh, ll; split2(nv, hh, ll);
    feh[o] = hh; fel[o] = ll;
  }
}

__global__ __launch_bounds__(256)
void gnn_agg(const float* __restrict__ fe, const float* __restrict__ ui,
             const float* __restrict__ uj, float* __restrict__ agg)
{
  int i = blockIdx.x, b = blockIdx.y;
  int t = threadIdx.x;
#pragma unroll
  for (int cq = 0; cq < 2; ++cq) {
    int c = cq * 256 + t;
    float sg[27];
    float mx = -1e30f;
#pragma unroll
    for (int j = 0; j < 27; ++j) {
      float x = fe[((long)b*729 + i*27 + j)*512 + c];
      float sgm = 1.f / (1.f + __expf(-x));
      sg[j] = sgm; mx = fmaxf(mx, sgm);
    }
    float sum = 0.f;
#pragma unroll
    for (int j = 0; j < 27; ++j) { float e2 = __expf(sg[j] - mx); sg[j] = e2; sum += e2; }
    float acc = 0.f;
#pragma unroll
    for (int j = 0; j < 27; ++j)
      acc = fmaf(sg[j], uj[((long)b*27+j)*512 + c], acc);
    agg[((long)b*27+i)*512 + c] = ui[((long)b*27+i)*512 + c] + acc / (sum * 27.f);
  }
}

__global__ __launch_bounds__(256)
void gnn_node_bn(const float* __restrict__ agg, const float* __restrict__ wv,
                 const float* __restrict__ bv, float* fv,
                 short* __restrict__ fvh, short* __restrict__ fvl)
{
  int i = blockIdx.x;
  int t = threadIdx.x;
  __shared__ float red[18];
  float mv[8]; float s = 0.f, q = 0.f;
#pragma unroll
  for (int p = 0; p < 8; ++p) {
    int idx = p * 256 + t; int b = idx >> 9, c = idx & 511;
    float v = agg[((long)b*27+i)*512 + c];
    mv[p] = v; s += v; q = fmaf(v, v, q);
  }
  int lane = t & 63, wid = t >> 6;
#pragma unroll
  for (int off = 32; off; off >>= 1) { s += __shfl_down(s, off); q += __shfl_down(q, off); }
  if (lane == 0) { red[wid] = s; red[4 + wid] = q; }
  __syncthreads();
  if (t == 0) {
    float S = red[0]+red[1]+red[2]+red[3], Q = red[4]+red[5]+red[6]+red[7];
    float m = S * (1.f / 2048.f);
    red[16] = m;
    red[17] = rsqrtf(Q * (1.f / 2048.f) - m * m + EPS_);
  }
  __syncthreads();
  float m = red[16], rs = red[17];
  float w = wv[i], bb = bv[i];
#pragma unroll
  for (int p = 0; p < 8; ++p) {
    int idx = p * 256 + t; int b = idx >> 9, c = idx & 511;
    long o = ((long)b*27+i)*512 + c;
    float nv = fv[o] + fmaxf(fmaf((mv[p] - m) * rs, w, bb), 0.f);
    fv[o] = nv;
    short hh, ll; split2(nv, hh, ll);
    fvh[o] = hh; fvl[o] = ll;
  }
}

__constant__ int SUB_IDX_c[14] = {0,0,1,1,2,2,4,4,7,7,8,8,11,11};

__global__ __launch_bounds__(64)
void sc_k(const float* __restrict__ fv, const float* __restrict__ mainsc,
          const float* __restrict__ subsc, float* __restrict__ out)
{
  int o = blockIdx.x, b = blockIdx.y;
  int lane = threadIdx.x;
  int r; const float* ap;
  if (o < 27) { r = o; ap = mainsc + (long)o * 512; }
  else        { int k = o - 27; r = SUB_IDX_c[k]; ap = subsc + (long)k * 512; }
  const float* fp = fv + ((long)b*27 + r) * 512;
  float sff = 0.f, saa = 0.f, sfa = 0.f;
  for (int c = lane; c < 512; c += 64) {
    float f = fp[c];
    float a = fmaxf(ap[c], 0.f);
    sff = fmaf(f, f, sff); saa = fmaf(a, a, saa); sfa = fmaf(f, a, sfa);
  }
#pragma unroll
  for (int off = 32; off; off >>= 1) {
    sff += __shfl_down(sff, off); saa += __shfl_down(saa, off); sfa += __shfl_down(sfa, off);
  }
  if (lane == 0)
    out[b * 41 + o] = sfa / (fmaxf(sqrtf(sff), 1e-12f) * fmaxf(sqrtf(saa), 1e-12f));
}

} // namespace

extern "C" void kernel_launch(void* const* d_in, const int* in_sizes, int n_in,
                              void* d_out, int out_size, void* d_ws, size_t ws_size,
                              hipStream_t stream)
{
  (void)in_sizes; (void)n_in; (void)out_size; (void)ws_size;
  const float* x       = (const float*)d_in[0];
  const float* nb_W    = (const float*)d_in[1];
  const float* nb_b    = (const float*)d_in[2];
  const float* nb_bnw  = (const float*)d_in[3];
  const float* nb_bnb  = (const float*)d_in[4];
  const float* fam_qW  = (const float*)d_in[5];
  const float* fam_qb  = (const float*)d_in[6];
  const float* fam_kW  = (const float*)d_in[7];
  const float* fam_kb  = (const float*)d_in[8];
  const float* fam_vW  = (const float*)d_in[9];
  const float* fam_vb  = (const float*)d_in[10];
  const float* arm_qW  = (const float*)d_in[11];
  const float* arm_qb  = (const float*)d_in[12];
  const float* arm_kW  = (const float*)d_in[13];
  const float* arm_kb  = (const float*)d_in[14];
  const float* arm_vW  = (const float*)d_in[15];
  const float* arm_vb  = (const float*)d_in[16];
  const float* ep_W    = (const float*)d_in[17];
  const float* ep_b    = (const float*)d_in[18];
  const float* gem_bnw = (const float*)d_in[19];
  const float* gem_bnb = (const float*)d_in[20];
  const float* gnn_uW  = (const float*)d_in[21];
  const float* gnn_vW  = (const float*)d_in[22];
  const float* gnn_aW  = (const float*)d_in[23];
  const float* gnn_bW  = (const float*)d_in[24];
  const float* gnn_eW  = (const float*)d_in[25];
  const float* gnn_bnvw = (const float*)d_in[26];
  const float* gnn_bnvb = (const float*)d_in[27];
  const float* gnn_bnew = (const float*)d_in[28];
  const float* gnn_bneb = (const float*)d_in[29];
  const float* main_sc  = (const float*)d_in[30];
  const float* sub_sc   = (const float*)d_in[31];
  float* out = (float*)d_out;

  // ---- workspace carve: fp32 region then bf16 plane region (~93 MB total) ----
  char* wp = (char*)d_ws;
  auto carveF = [&](long n) -> float* { float* p = (float*)wp; wp += ((n + 15) & ~15L) * 4; return p; };
  auto carveS = [&](long n) -> short* { short* p = (short*)wp; wp += ((n + 15) & ~15L) * 2; return p; };

  float* Hnb   = carveF((long)27*196*512);   // dead after nb_apply; VW aliases
  float* S     = carveF((long)4*1323*1344);  // dead after arm_post; el aliases
  float* fe    = carveF((long)4*729*512);
  float* kf    = carveF(196*256);            // unused (kept for layout stability)
  float* vf    = carveF(196*512);
  float* qfam  = carveF((long)5292*256);     // reused as S_fam [5292][64] fp32
  float* nbm   = carveF(27*512);
  float* nbr   = carveF(27*512);
  float* Mpre  = carveF(512*512);
  float* bias2 = carveF(512);
  float* b2st  = carveF(16);
  float* parts = carveF(4*729*2);
  float* ems   = carveF(1460);
  float* G     = carveF((long)108*2401);
  float* V1    = carveF(108*49);
  float* Vb2   = carveF(108*49);
  float* Pbar  = carveF((long)4*27*27*49);
  float* fv    = carveF(108*512);
  float* vi    = carveF(108*512);
  float* vj    = carveF(108*512);
  float* uj    = carveF(108*512);
  float* ui    = carveF(108*512);
  float* agg   = carveF(108*512);
  float* VW = Hnb;     // alias (Hnb dead after nb_apply)
  float* el = S;       // alias (S dead after arm_post)
  float* Sfam = qfam;  // alias (qfam fp32 no longer produced)
  (void)kf;

  short* xh    = carveS(100352);
  short* xl    = carveS(100352);
  short* wph   = carveS((long)26*131072);    // weight hi planes (26 chunks)
  short* wpl   = carveS((long)26*131072);
  short* Mpreh = carveS(262144);
  short* Mprel = carveS(262144);
  short* fuh   = carveS((long)5292*512);     // dead after FAM-q GEMM; feath aliases
  short* ful   = carveS((long)5292*512);
  short* Qah   = carveS((long)5292*256);     // FAM-q planes, then ARM Q; feh alias later
  short* Qal   = carveS((long)5292*256);
  short* Kah   = carveS((long)4*1344*256);   // FAM P planes, then ARM K; fel alias later
  short* Kal   = carveS((long)4*1344*256);
  short* fvh   = carveS(108*512);
  short* fvl   = carveS(108*512);
  short* kfh   = carveS(212*256);            // FAM k planes (+16 rows slack for N=64 spill)
  short* kfl   = carveS(212*256);
  short* vth   = carveS((long)4*512*64);     // V^T planes [4][512][64]
  short* vtl   = carveS((long)4*512*64);
  short* feath = fuh;   // alias: fu last read by FAM-q GEMM; feat written by PV GEMM
  short* featl = ful;
  short* Pfh   = Kah;   // alias: P planes dead before ARM K write (step 9)
  short* Pfl   = Kal;
  short* feh   = Qah;   // alias: Qa/Ka last read step 13; fe planes written step 17
  short* fel   = Kah;   // (feh spans Qah+Qal region, fel spans Kah+Kal region)

  // weight plane offsets (chunks of 131072 shorts)
  short* famqWh = wph + 0L*131072;        short* famqWl = wpl + 0L*131072;
  short* famkWh = wph + 1L*131072;        short* famkWl = wpl + 1L*131072;
  short* armqWh = wph + 2L*131072;        short* armqWl = wpl + 2L*131072;
  short* armkWh = wph + 3L*131072;        short* armkWl = wpl + 3L*131072;
  short* famvWh = wph + 4L*131072;        short* famvWl = wpl + 4L*131072;
  short* uWh    = wph + 6L*131072;        short* uWl    = wpl + 6L*131072;
  short* vWh    = wph + 10L*131072;       short* vWl    = wpl + 10L*131072;
  short* aWh    = wph + 14L*131072;       short* aWl    = wpl + 14L*131072;
  short* bWh    = wph + 18L*131072;       short* bWl    = wpl + 18L*131072;
  short* eWh    = wph + 22L*131072;       short* eWl    = wpl + 22L*131072;

  // ---- conversions ----
  cvt1_k<<<dim3(98), 256, 0, stream>>>(x, xh, xl, 25088);
  P10 p10;
  p10.s[0] = fam_qW; p10.s[1] = fam_kW; p10.s[2] = arm_qW; p10.s[3] = arm_kW;
  p10.s[4] = fam_vW; p10.s[5] = gnn_uW; p10.s[6] = gnn_vW; p10.s[7] = gnn_aW;
  p10.s[8] = gnn_bW; p10.s[9] = gnn_eW;
  cvt_w_k<<<dim3(64, 26), 256, 0, stream>>>(p10, wph, wpl);

  // 1) node-block GEMMs (W converted on the fly from fp32 nb_W)
  gemm_bf3_k<1><<<dim3(8,4,27), 256, 0, stream>>>(xh, xl, nullptr, nullptr, nb_W,
      nb_b, Hnb, nullptr, nullptr, 196, 512, 512, 0, 262144, 512, 100352);
  // 2-3) BN stats + apply -> fu planes (batch-major), fv (+planes)
  nb_stats<<<dim3(27,2), 256, 0, stream>>>(Hnb, nbm, nbr);
  nb_apply<<<dim3(27,4), 256, 0, stream>>>(Hnb, nbm, nbr, nb_bnw, nb_bnb,
      fuh, ful, fv, fvh, fvl);
  // 4) FAM k -> planes [196][256]
  gemm_bf3_k<0><<<dim3(4,4), 256, 0, stream>>>(xh, xl, famkWh, famkWl, nullptr,
      fam_kb, nullptr, kfh, kfl, 196, 256, 512, 0,0,0,0);
  // 5) FAM v (fp32, feeds transpose)
  gemm_bf3_k<0><<<dim3(8,4), 256, 0, stream>>>(xh, xl, famvWh, famvWl, nullptr,
      fam_vb, vf, nullptr, nullptr, 196, 512, 512, 0,0,0,0);
  // 5b) V^T planes [4][512][64]
  vt_cvt_k<<<dim3(4,2), 256, 0, stream>>>(vf, vth, vtl);
  // 6) FAM q -> planes (batch-major rows; last read of fu planes)
  gemm_bf3_k<0><<<dim3(4,83), 256, 0, stream>>>(fuh, ful, famqWh, famqWl, nullptr,
      fam_qb, nullptr, Qah, Qal, 5292, 256, 512, 0,0,0,0);
  // 7a) S_fam[b] = Qf_b @ kf_b^T  [1323 x 64], cols>=49 garbage (masked in softmax)
  gemm_bf3_k<0><<<dim3(1,21,4), 256, 0, stream>>>(Qah, Qal, kfh, kfl, nullptr,
      nullptr, Sfam, nullptr, nullptr, 1323, 64, 256,
      (long)1323*256, (long)49*256, 0, (long)1323*64);
  // 7b) row softmax -> P planes (pad cols zeroed)
  sm_fam_k<<<dim3(1323), 256, 0, stream>>>(Sfam, Pfh, Pfl);
  // 7c) feat = P @ V  -> feat planes (batch-major), K=64
  gemm_bf3_k<0><<<dim3(8,21,4), 256, 0, stream>>>(Pfh, Pfl, vth, vtl, nullptr,
      nullptr, nullptr, feath, featl, 1323, 512, 64,
      (long)1323*64, (long)512*64, 0, (long)1323*512);
  // 8) ARM Q (planes only; overwrites FAM-q planes region)
  gemm_bf3_k<0><<<dim3(4,83), 256, 0, stream>>>(feath, featl, armqWh, armqWl, nullptr,
      arm_qb, nullptr, Qah, Qal, 5292, 256, 512, 0,0,0,0);
  // 9) ARM K (per-batch, row-padded to 1344; overwrites P planes region)
  gemm_bf3_k<0><<<dim3(4,21,4), 256, 0, stream>>>(feath, featl, armkWh, armkWl, nullptr,
      arm_kb, nullptr, Kah, Kal, 1323, 256, 512, (long)1323*512, 0, 0, (long)1344*256);
  // 10) Mpre = ep_W @ arm_vW (fp32) + convert
  gemm_nn_k<<<dim3(8,8), 256, 0, stream>>>(ep_W, arm_vW, Mpre, 512, 512, 512);
  cvt1_k<<<dim3(256), 256, 0, stream>>>(Mpre, Mpreh, Mprel, 65536);
  // 11) bias2 + scalar sums
  bias2red_k<<<dim3(1), 512, 0, stream>>>(ep_W, arm_vb, ep_b, bias2, b2st);
  // 12) VW = feat @ Mpre^T (fp32 out, overlays Hnb)
  gemm_bf3_k<0><<<dim3(8,83), 256, 0, stream>>>(feath, featl, Mpreh, Mprel, nullptr,
      nullptr, VW, nullptr, nullptr, 5292, 512, 512, 0,0,0,0);
  // 13) S_all[b] = Qa_b @ Ka_b^T (last read of Qa/Ka planes)
  gemm_bf3_k<0><<<dim3(21,21,4), 256, 0, stream>>>(Qah, Qal, Kah, Kal, nullptr,
      nullptr, S, nullptr, nullptr, 1323, 1344, 256,
      (long)1323*256, (long)1344*256, 0, (long)1323*1344);
  // 14) G = VW VW^T per (b,i) + row sums
  gmat_k<<<dim3(27,4), 256, 0, stream>>>(VW, bias2, G, V1, Vb2);
  // 15) segmented softmax + Pbar + BN partials (last read of S)
  arm_post<<<dim3(729,4), 128, 0, stream>>>(S, G, V1, Vb2, Pbar, parts);
  // 16) per-edge BN stats
  edge_fin<<<dim3(3), 256, 0, stream>>>(parts, b2st, ems);
  // 17) f_e = BN(Pbar@VW/49 + b2) -> fp32 + planes (planes overlay Qa/Ka)
  fe_build<<<dim3(27,4), 256, 0, stream>>>(Pbar, VW, bias2, ems, gem_bnw, gem_bnb,
      fe, feh, fel);
  // 18) 2 GatedGNN layers
  for (int l = 0; l < 2; ++l) {
    long wo = (long)l * 262144;
    G4 g4;
    g4.wh[0] = aWh + wo; g4.wl[0] = aWl + wo; g4.c[0] = vi;
    g4.wh[1] = bWh + wo; g4.wl[1] = bWl + wo; g4.c[1] = vj;
    g4.wh[2] = vWh + wo; g4.wl[2] = vWl + wo; g4.c[2] = uj;
    g4.wh[3] = uWh + wo; g4.wl[3] = uWl + wo; g4.c[3] = ui;
    gemm4_bf3_k<<<dim3(8,2,4), 256, 0, stream>>>(fvh, fvl, g4, 108, 512, 512);
    gemm_bf3_k<0><<<dim3(8,46), 256, 0, stream>>>(feh, fel, eWh + wo, eWl + wo, nullptr,
        nullptr, el, nullptr, nullptr, 2916, 512, 512, 0,0,0,0);
    gnn_edge_bn<<<dim3(729), 256, 0, stream>>>(vi, vj, el,
        gnn_bnew + (long)l*729, gnn_bneb + (long)l*729, fe, feh, fel);
    gnn_agg<<<dim3(27,4), 256, 0, stream>>>(fe, ui, uj, agg);
    gnn_node_bn<<<dim3(27), 256, 0, stream>>>(agg,
        gnn_bnvw + (long)l*27, gnn_bnvb + (long)l*27, fv, fvh, fvl);
  }
  // 19) cosine-similarity outputs [4,41]
  sc_k<<<dim3(41,4), 64, 0, stream>>>(fv, main_sc, sub_sc, out);
}